// Round 12
// baseline (170.260 us; speedup 1.0000x reference)
//
#include <hip/hip_runtime.h>
#include <hip/hip_bf16.h>

#define LL 768
#define TOPK 128

// workspace layout (floats)
#define WS_SEQ  0                        // 768*256
#define WS_NODE (WS_SEQ + LL*256)        // 768*32
#define WS_NBR  (WS_NODE + LL*32)        // 768*128 ints
#define WS_CSEE (WS_NBR + LL*TOPK)       // 32

// bf16 pair pack/unpack (RNE)
__device__ __forceinline__ unsigned bfpack(float a, float b) {
  unsigned ua = __float_as_uint(a);
  ua = (ua + 0x7fffu + ((ua >> 16) & 1u)) >> 16;
  unsigned ub = __float_as_uint(b);
  ub = (ub + 0x7fffu + ((ub >> 16) & 1u)) & 0xffff0000u;
  return ua | ub;
}
__device__ __forceinline__ float bflo(unsigned v) { return __uint_as_float(v << 16); }
__device__ __forceinline__ float bfhi(unsigned v) { return __uint_as_float(v & 0xffff0000u); }

__device__ __forceinline__ float block_sum_256(float v, float* red, int t) {
#pragma unroll
  for (int o = 32; o > 0; o >>= 1) v += __shfl_xor(v, o, 64);
  __syncthreads();
  if ((t & 63) == 0) red[t >> 6] = v;
  __syncthreads();
  return red[0] + red[1] + red[2] + red[3];
}

// ---------------- Kernel ABP: A (blocks 0..767), B (768..1535), P (1536) ----
__global__ __launch_bounds__(256) void kernABP(
    const float* __restrict__ msa, const float* __restrict__ state,
    const float* __restrict__ W_en, const float* __restrict__ b_en,
    const float* __restrict__ Wn1, const float* __restrict__ bn1,
    const float* __restrict__ Wn2, const float* __restrict__ bn2,
    const float* __restrict__ xyz, const float* __restrict__ W_ee,
    float* __restrict__ seq_ln, float* __restrict__ nodeo,
    int* __restrict__ nbr, float* __restrict__ colsum_ee)
{
  const int bid = blockIdx.x, t = threadIdx.x;
  __shared__ float x[256];
  __shared__ float red[4];
  __shared__ float sn[16], n0[32], tn[32], hh[64], n1v[32];
  __shared__ float partA[8][33];
  __shared__ unsigned hist[256];
  __shared__ int selBin, below;
  __shared__ unsigned wcL[4], wcE[4];

  if (bid < LL) {
    // ================= A: seq LN, state LN, node MLP + LN =================
    const int i = bid;
    float v = msa[i*256 + t];
    float mean = block_sum_256(v, red, t) * (1.f/256.f);
    float d = v - mean;
    float var = block_sum_256(d*d, red, t) * (1.f/256.f);
    float xn = d / sqrtf(var + 1e-5f);
    x[t] = xn;
    seq_ln[i*256 + t] = xn;

    if (t < 16) {
      float m2 = 0.f;
      for (int k = 0; k < 16; ++k) m2 += state[i*16 + k];
      m2 *= (1.f/16.f);
      float v2 = 0.f;
      for (int k = 0; k < 16; ++k) { float dd = state[i*16 + k] - m2; v2 += dd*dd; }
      v2 *= (1.f/16.f);
      sn[t] = (state[i*16 + t] - m2) / sqrtf(v2 + 1e-5f);
    }
    __syncthreads();

    {  // k-split matvec over ALL 256 threads
      const int g = t >> 5, c = t & 31;
      float p = 0.f;
      for (int k = g*32; k < g*32 + 32; ++k) p = fmaf(x[k], W_en[k*32 + c], p);
      if (g == 7)
        for (int k = 0; k < 16; ++k) p = fmaf(sn[k], W_en[(256+k)*32 + c], p);
      partA[g][c] = p;
    }
    __syncthreads();
    if (t < 32) {
      float a = b_en[t];
#pragma unroll
      for (int g = 0; g < 8; ++g) a += partA[g][t];
      n0[t] = a;
    }
    __syncthreads();
    if (t < 32) {
      float m = 0.f;
      for (int k = 0; k < 32; ++k) m += n0[k];
      m *= (1.f/32.f);
      float vv = 0.f;
      for (int k = 0; k < 32; ++k) { float dd = n0[k] - m; vv += dd*dd; }
      vv *= (1.f/32.f);
      tn[t] = (n0[t] - m) / sqrtf(vv + 1e-5f);
    }
    __syncthreads();
    if (t < 64) {
      float a = bn1[t];
      for (int k = 0; k < 32; ++k) a = fmaf(tn[k], Wn1[k*64 + t], a);
      hh[t] = fmaxf(a, 0.f);
    }
    __syncthreads();
    if (t < 32) {
      float a = n0[t] + bn2[t];
      for (int k = 0; k < 64; ++k) a = fmaf(hh[k], Wn2[k*32 + t], a);
      n1v[t] = a;
    }
    __syncthreads();
    if (t < 32) {
      float m = 0.f;
      for (int k = 0; k < 32; ++k) m += n1v[k];
      m *= (1.f/32.f);
      float vv = 0.f;
      for (int k = 0; k < 32; ++k) { float dd = n1v[k] - m; vv += dd*dd; }
      vv *= (1.f/32.f);
      nodeo[i*32 + t] = (n1v[t] - m) / sqrtf(vv + 1e-5f);
    }
    return;
  }

  if (bid < 2*LL) {
    // ================= B: top-128 nearest via 4-pass radix select ==========
    const int i = bid - LL;
    const int lane = t & 63, wv = t >> 6;

    const float cix = xyz[i*9+3], ciy = xyz[i*9+4], ciz = xyz[i*9+5];
    unsigned key[3];
#pragma unroll
    for (int r = 0; r < 3; ++r) {
      const int j = r*256 + t;
      float dx = __fadd_rn(cix, -xyz[j*9+3]);
      float dy = __fadd_rn(ciy, -xyz[j*9+4]);
      float dz = __fadd_rn(ciz, -xyz[j*9+5]);
      float Dv = sqrtf(__fadd_rn(__fadd_rn(__fadd_rn(__fmul_rn(dx,dx),
                         __fmul_rn(dy,dy)), __fmul_rn(dz,dz)), 1e-8f));
      key[r] = __float_as_uint(Dv);
    }

    unsigned prefix = 0;
    int rank = 127, cntLess = 0;
#pragma unroll
    for (int pass = 0; pass < 4; ++pass) {
      const int shift = 24 - pass*8;
      const unsigned hiMask = (pass == 0) ? 0u : (0xFFFFFFFFu << (shift + 8));
      hist[t] = 0;
      __syncthreads();
#pragma unroll
      for (int r = 0; r < 3; ++r)
        if ((key[r] & hiMask) == (prefix & hiMask))
          atomicAdd(&hist[(key[r] >> shift) & 0xffu], 1u);
      __syncthreads();
      if (t < 64) {
        unsigned s0 = hist[t*4], s1 = hist[t*4+1], s2 = hist[t*4+2], s3 = hist[t*4+3];
        int tot = (int)(s0 + s1 + s2 + s3);
        int inc = tot;
#pragma unroll
        for (int o = 1; o < 64; o <<= 1) {
          int v = __shfl_up(inc, o);
          if (t >= o) inc += v;
        }
        int excl = inc - tot;
        if (rank >= excl && rank < inc) {
          int c = excl, bsel = t*4;
          if (rank >= c + (int)s0) { c += (int)s0; bsel = t*4+1;
            if (rank >= c + (int)s1) { c += (int)s1; bsel = t*4+2;
              if (rank >= c + (int)s2) { c += (int)s2; bsel = t*4+3; } } }
          selBin = bsel; below = c;
        }
      }
      __syncthreads();
      prefix |= ((unsigned)selBin) << shift;
      rank -= below;
      cntLess += below;
      __syncthreads();
    }
    const unsigned thr = prefix;

    const unsigned long long lmask = (1ull << lane) - 1ull;
    unsigned baseLt = 0, baseEq = (unsigned)cntLess;
#pragma unroll
    for (int r = 0; r < 3; ++r) {
      const int j = r*256 + t;
      const bool pl = key[r] < thr;
      const bool pe = key[r] == thr;
      unsigned long long balL = __ballot(pl);
      unsigned long long balE = __ballot(pe);
      unsigned preL = (unsigned)__popcll(balL & lmask);
      unsigned preE = (unsigned)__popcll(balE & lmask);
      if (lane == 0) { wcL[wv] = (unsigned)__popcll(balL); wcE[wv] = (unsigned)__popcll(balE); }
      __syncthreads();
      unsigned wbL = 0, wbE = 0, totL = 0, totE = 0;
#pragma unroll
      for (int w = 0; w < 4; ++w) {
        if (w < wv) { wbL += wcL[w]; wbE += wcE[w]; }
        totL += wcL[w]; totE += wcE[w];
      }
      if (pl) nbr[i*TOPK + baseLt + wbL + preL] = j;
      if (pe) {
        unsigned pos = baseEq + wbE + preE;
        if (pos < TOPK) nbr[i*TOPK + pos] = j;
      }
      baseLt += totL; baseEq += totE;
      __syncthreads();
    }
    return;
  }

  // ================= P: column sums of W_ee pair-part ======================
  {
    const int c = t & 31, sg = t >> 5;
    float s = 0.f;
    for (int k = sg*16; k < sg*16 + 16; ++k) s += W_ee[k*32 + c];
    partA[sg][c] = s;
    __syncthreads();
    if (t < 32) {
      float tot = 0.f;
#pragma unroll
      for (int g = 0; g < 8; ++g) tot += partA[g][t];
      colsum_ee[t] = tot;
    }
  }
}

// ---------------- Kernel CD (FUSED C1+C2+D), 4 blocks/CU --------------------
__global__ __launch_bounds__(256, 4) void kernCD(
    const float* __restrict__ pair, const float* __restrict__ xyz,
    const int* __restrict__ idx, const unsigned char* __restrict__ rmask,
    const float* __restrict__ W_ee, const float* __restrict__ b_ee,
    const float* __restrict__ colsum_ee,
    const float* __restrict__ We1, const float* __restrict__ be1,
    const float* __restrict__ We2, const float* __restrict__ be2,
    const float* __restrict__ Wm1, const float* __restrict__ bm1,
    const float* __restrict__ Wm2, const float* __restrict__ bm2,
    const float* __restrict__ Wl0, const float* __restrict__ bl0,
    const float* __restrict__ node, const int* __restrict__ nbr,
    const float* __restrict__ seq_ln,
    const float* __restrict__ Ws0, const float* __restrict__ bs0,
    const float* __restrict__ Wsi, const float* __restrict__ bsi,
    const float* __restrict__ Wp1, const float* __restrict__ bp1,
    const float* __restrict__ Wp2, const float* __restrict__ bp2,
    const float* __restrict__ Wp3, const float* __restrict__ bp3,
    const float* __restrict__ Wp4, const float* __restrict__ bp4,
    const float* __restrict__ Wout, const float* __restrict__ bout,
    float* __restrict__ out)
{
  const int i = blockIdx.x, t = threadIdx.x;
  const int lane = t & 63;
  const int wv = __builtin_amdgcn_readfirstlane(t >> 6);   // uniform 0..3
  __shared__ unsigned Ab[128][17];     // e0 -> ed -> e2 -> ed2 (bf16 pairs)
  __shared__ unsigned U[128*33];       // pairB[64][65] / Bb[128][33] / D bufs
  __shared__ unsigned nd[128][17];     // node rows (bf16 pairs)
  __shared__ int   jl[128];
  __shared__ float Dvv[128], xsepv[128];
  __shared__ float relv[128][3];
  __shared__ float ni[32];
  __shared__ float pmv[64], prsv[64];
  __shared__ float mA[128], sgA[128];
  __shared__ float P2[4][14];
  __shared__ float fin[44];
  __shared__ float sout_s[16], stn[16];

  // ---- phase 0: stage ni, nd, jl, relv, Dv, xsep ----
  if (t < 32) ni[t] = node[i*32 + t];
  {
    const int pp = t >> 1, hh2 = t & 1;
    const int jj = nbr[i*TOPK + pp];
    const float4* nr = (const float4*)(node + jj*32 + hh2*16);
    float4 a0 = nr[0], a1 = nr[1], a2 = nr[2], a3 = nr[3];
    unsigned* dst = &nd[pp][hh2*8];
    dst[0] = bfpack(a0.x, a0.y); dst[1] = bfpack(a0.z, a0.w);
    dst[2] = bfpack(a1.x, a1.y); dst[3] = bfpack(a1.z, a1.w);
    dst[4] = bfpack(a2.x, a2.y); dst[5] = bfpack(a2.z, a2.w);
    dst[6] = bfpack(a3.x, a3.y); dst[7] = bfpack(a3.z, a3.w);
    if (hh2 == 0) {
      jl[pp] = jj;
      const float cix = xyz[i*9+3], ciy = xyz[i*9+4], ciz = xyz[i*9+5];
      const float cjx = xyz[jj*9+3], cjy = xyz[jj*9+4], cjz = xyz[jj*9+5];
      relv[pp][0] = cjx - cix;
      relv[pp][1] = cjy - ciy;
      relv[pp][2] = cjz - ciz;
      const float dx = __fadd_rn(cix, -cjx), dy = __fadd_rn(ciy, -cjy),
                  dz = __fadd_rn(ciz, -cjz);
      Dvv[pp] = sqrtf(__fadd_rn(__fadd_rn(__fadd_rn(__fmul_rn(dx,dx),
                        __fmul_rn(dy,dy)), __fmul_rn(dz,dz)), 1e-8f));
      const float offv = (float)(idx[jj] - idx[i]);
      const float sg = (offv > 0.f) ? 1.f : ((offv < 0.f) ? -1.f : 0.f);
      xsepv[pp] = sg * logf(fabsf(offv) + 1.f);
    }
  }
  __syncthreads();

  // ---- phase C1': edge0 into Ab, two 64-edge sub-passes ----
  unsigned (*pairB)[65] = (unsigned (*)[65])U;
  for (int sub = 0; sub < 2; ++sub) {
    {  // coalesced stage of 64 pair rows -> bf16 LDS; stats via quad shuffle
      const int r = t >> 2, qq = t & 3;
      const float* prow = pair + ((size_t)i*LL + jl[sub*64 + r])*128 + qq*32;
      float s = 0.f, ss = 0.f;
#pragma unroll
      for (int n = 0; n < 8; ++n) {
        float4 v = ((const float4*)prow)[n];
        s  += (v.x + v.y) + (v.z + v.w);
        ss += v.x*v.x + v.y*v.y + v.z*v.z + v.w*v.w;
        pairB[r][qq*16 + n*2]     = bfpack(v.x, v.y);
        pairB[r][qq*16 + n*2 + 1] = bfpack(v.z, v.w);
      }
      s  += __shfl_xor(s, 1);  s  += __shfl_xor(s, 2);
      ss += __shfl_xor(ss, 1); ss += __shfl_xor(ss, 2);
      if (qq == 0) {
        const float pm = s * (1.f/128.f);
        const float pv = ss * (1.f/128.f) - pm*pm;
        pmv[r] = pm; prsv[r] = 1.f / sqrtf(pv + 1e-5f);
      }
    }
    __syncthreads();
    {  // matvec: lane = local edge, wave = 8-ch strip (scalar weights)
      const int el = lane;
      const int e = sub*64 + el;
      float acc[8], acc2[8];
#pragma unroll
      for (int c = 0; c < 8; ++c) { acc[c] = 0.f; acc2[c] = 0.f; }
#pragma unroll 4
      for (int kk = 0; kk < 64; ++kk) {   // pair part, k = 2kk, 2kk+1
        const unsigned v = pairB[el][kk];
        const float al = bflo(v), ah = bfhi(v);
        const float* w0 = W_ee + (2*kk)*32   + 8*wv;   // uniform -> s_load
        const float* w1 = W_ee + (2*kk+1)*32 + 8*wv;
#pragma unroll
        for (int c = 0; c < 8; ++c)
          acc[c] = fmaf(al, w0[c], fmaf(ah, w1[c], acc[c]));
      }
      const float Dv = Dvv[e];
#pragma unroll 4
      for (int k = 0; k < 64; ++k) {      // RBF part
        const float mu = 2.f + (float)k * (20.f/63.f);
        const float u  = (Dv - mu) / 0.3125f;
        const float w  = expf(-(u*u));
        const float* wr = W_ee + (128+k)*32 + 8*wv;    // uniform
#pragma unroll
        for (int c = 0; c < 8; ++c) acc2[c] = fmaf(w, wr[c], acc2[c]);
      }
      const float pm = pmv[el], prs = prsv[el];
      const float corr = -prs * pm;
      const float xs = xsepv[e];
      float val[8];
#pragma unroll
      for (int c = 0; c < 8; ++c) {
        const int ch = 8*wv + c;
        val[c] = fmaf(prs, acc[c],
                   fmaf(corr, colsum_ee[ch],
                     fmaf(xs, W_ee[192*32 + ch], b_ee[ch] + acc2[c])));
      }
#pragma unroll
      for (int n = 0; n < 4; ++n)
        Ab[e][4*wv + n] = bfpack(val[2*n], val[2*n+1]);
    }
    __syncthreads();
  }

  // ---- C2 phases ----
  unsigned (*Bb)[33] = (unsigned (*)[33])U;

  // LN(Ab) in place; keep (mean, sigma) for the residual undo
  if (t < 128) {
    float av[32];
#pragma unroll
    for (int kk = 0; kk < 16; ++kk) {
      const unsigned v = Ab[t][kk];
      av[2*kk] = bflo(v); av[2*kk+1] = bfhi(v);
    }
    float mm = 0.f;
#pragma unroll
    for (int c = 0; c < 32; ++c) mm += av[c];
    mm *= (1.f/32.f);
    float vv = 0.f;
#pragma unroll
    for (int c = 0; c < 32; ++c) { float dd = av[c]-mm; vv += dd*dd; }
    vv *= (1.f/32.f);
    const float sg = sqrtf(vv + 1e-5f);
    const float rs = 1.f / sg;
#pragma unroll
    for (int kk = 0; kk < 16; ++kk)
      Ab[t][kk] = bfpack((av[2*kk]-mm)*rs, (av[2*kk+1]-mm)*rs);
    mA[t] = mm; sgA[t] = sg;
  }
  __syncthreads();

  // ---- h = relu(ed @ We1 + be1): 2 edges x 16 ch (cols [16wv,16wv+16)) ----
  {
    float hacc[2][16];
#pragma unroll
    for (int m = 0; m < 2; ++m)
#pragma unroll
      for (int c = 0; c < 16; ++c) hacc[m][c] = 0.f;
#pragma unroll 4
    for (int kk = 0; kk < 16; ++kk) {   // k = 2kk, 2kk+1
      const float* wbl = We1 + (2*kk)*64 + 16*wv;     // uniform -> s_load
      const float* wbh = We1 + (2*kk+1)*64 + 16*wv;
      const unsigned v0 = Ab[lane][kk], v1 = Ab[lane+64][kk];
#pragma unroll
      for (int m = 0; m < 2; ++m) {
        const unsigned v = m ? v1 : v0;
        const float al = bflo(v), ah = bfhi(v);
#pragma unroll
        for (int c = 0; c < 16; ++c)
          hacc[m][c] = fmaf(al, wbl[c], fmaf(ah, wbh[c], hacc[m][c]));
      }
    }
#pragma unroll
    for (int m = 0; m < 2; ++m) {
      const int e = lane + 64*m;
#pragma unroll
      for (int n = 0; n < 8; ++n) {
        const float lo = fmaxf(hacc[m][2*n]   + be1[16*wv + 2*n],   0.f);
        const float hi = fmaxf(hacc[m][2*n+1] + be1[16*wv + 2*n+1], 0.f);
        Bb[e][8*wv + n] = bfpack(lo, hi);
      }
    }
  }
  __syncthreads();

  // ---- e2 = e0raw + h @ We2 + be2: 2 edges x 8 ch (cols [8wv,8wv+8)) ----
  {
    float e2a[2][8];
#pragma unroll
    for (int m = 0; m < 2; ++m)
#pragma unroll
      for (int c = 0; c < 8; ++c) e2a[m][c] = 0.f;
#pragma unroll 4
    for (int kk = 0; kk < 32; ++kk) {   // k = 2kk, 2kk+1
      const float* wbl = We2 + (2*kk)*32   + 8*wv;   // uniform
      const float* wbh = We2 + (2*kk+1)*32 + 8*wv;
      const unsigned v0 = Bb[lane][kk], v1 = Bb[lane+64][kk];
#pragma unroll
      for (int m = 0; m < 2; ++m) {
        const unsigned v = m ? v1 : v0;
        const float al = bflo(v), ah = bfhi(v);
#pragma unroll
        for (int c = 0; c < 8; ++c)
          e2a[m][c] = fmaf(al, wbl[c], fmaf(ah, wbh[c], e2a[m][c]));
      }
    }
#pragma unroll
    for (int m = 0; m < 2; ++m) {
      const int e = lane + 64*m;
      const float sg = sgA[e], mm = mA[e];
#pragma unroll
      for (int n = 0; n < 4; ++n) {
        const int ch0 = 8*wv + 2*n;
        const unsigned old = Ab[e][4*wv + n];
        const float e0lo = fmaf(bflo(old), sg, mm);
        const float e0hi = fmaf(bfhi(old), sg, mm);
        Ab[e][4*wv + n] = bfpack(e2a[m][2*n]   + e0lo + be2[ch0],
                                 e2a[m][2*n+1] + e0hi + be2[ch0+1]);
      }
    }
  }
  __syncthreads();

  // LN(e2) in place
  if (t < 128) {
    float av[32];
#pragma unroll
    for (int kk = 0; kk < 16; ++kk) {
      const unsigned v = Ab[t][kk];
      av[2*kk] = bflo(v); av[2*kk+1] = bfhi(v);
    }
    float mm = 0.f;
#pragma unroll
    for (int c = 0; c < 32; ++c) mm += av[c];
    mm *= (1.f/32.f);
    float vv = 0.f;
#pragma unroll
    for (int c = 0; c < 32; ++c) { float dd = av[c]-mm; vv += dd*dd; }
    vv *= (1.f/32.f);
    const float rs = 1.f / sqrtf(vv + 1e-5f);
#pragma unroll
    for (int kk = 0; kk < 16; ++kk)
      Ab[t][kk] = bfpack((av[2*kk]-mm)*rs, (av[2*kk+1]-mm)*rs);
  }
  __syncthreads();

  // ---- m1 = relu([ni, nj, ed2] @ Wm1 + bm1): 2 edges x 16 ch ----
  {
    float tmp[16];   // ni part — identical for both edges
#pragma unroll
    for (int c = 0; c < 16; ++c) tmp[c] = bm1[16*wv + c];
#pragma unroll 4
    for (int k = 0; k < 32; ++k) {
      const float* wb = Wm1 + k*64 + 16*wv;   // uniform
      const float av = ni[k];
#pragma unroll
      for (int c = 0; c < 16; ++c) tmp[c] = fmaf(av, wb[c], tmp[c]);
    }
    float macc[2][16];
#pragma unroll
    for (int m = 0; m < 2; ++m)
#pragma unroll
      for (int c = 0; c < 16; ++c) macc[m][c] = 0.f;
#pragma unroll 4
    for (int kk = 0; kk < 16; ++kk) {   // h_j part (bf16 pairs)
      const float* wbl = Wm1 + (32+2*kk)*64 + 16*wv;   // uniform
      const float* wbh = Wm1 + (33+2*kk)*64 + 16*wv;
      const unsigned v0 = nd[lane][kk], v1 = nd[lane+64][kk];
#pragma unroll
      for (int m = 0; m < 2; ++m) {
        const unsigned v = m ? v1 : v0;
        const float al = bflo(v), ah = bfhi(v);
#pragma unroll
        for (int c = 0; c < 16; ++c)
          macc[m][c] = fmaf(al, wbl[c], fmaf(ah, wbh[c], macc[m][c]));
      }
    }
#pragma unroll 4
    for (int kk = 0; kk < 16; ++kk) {   // edge part (bf16 pairs from Ab)
      const float* wbl = Wm1 + (64+2*kk)*64 + 16*wv;   // uniform
      const float* wbh = Wm1 + (65+2*kk)*64 + 16*wv;
      const unsigned v0 = Ab[lane][kk], v1 = Ab[lane+64][kk];
#pragma unroll
      for (int m = 0; m < 2; ++m) {
        const unsigned v = m ? v1 : v0;
        const float al = bflo(v), ah = bfhi(v);
#pragma unroll
        for (int c = 0; c < 16; ++c)
          macc[m][c] = fmaf(al, wbl[c], fmaf(ah, wbh[c], macc[m][c]));
      }
    }
    __syncthreads();   // all Bb reads (e2 phase) complete before overwrite
#pragma unroll
    for (int m = 0; m < 2; ++m) {
      const int e = lane + 64*m;
#pragma unroll
      for (int n = 0; n < 8; ++n) {
        const float lo = fmaxf(macc[m][2*n]   + tmp[2*n],   0.f);
        const float hi = fmaxf(macc[m][2*n+1] + tmp[2*n+1], 0.f);
        Bb[e][8*wv + n] = bfpack(lo, hi);
      }
    }
  }
  __syncthreads();

  // ---- m2: 2 edges x 10 outs (cols [10wv,10wv+10)); expand + wave reduce ----
  {
    float p2[2][10];
#pragma unroll
    for (int m = 0; m < 2; ++m)
#pragma unroll
      for (int o = 0; o < 10; ++o) p2[m][o] = 0.f;
#pragma unroll 4
    for (int kk = 0; kk < 32; ++kk) {   // k = 2kk, 2kk+1
      const float* wr0 = Wm2 + (2*kk)*40   + 10*wv;   // uniform
      const float* wr1 = Wm2 + (2*kk+1)*40 + 10*wv;
      const unsigned v0 = Bb[lane][kk], v1 = Bb[lane+64][kk];
#pragma unroll
      for (int m = 0; m < 2; ++m) {
        const unsigned v = m ? v1 : v0;
        const float al = bflo(v), ah = bfhi(v);
#pragma unroll
        for (int o = 0; o < 10; ++o)
          p2[m][o] = fmaf(al, wr0[o], fmaf(ah, wr1[o], p2[m][o]));
      }
    }
    float outv[14];
#pragma unroll
    for (int s = 0; s < 14; ++s) outv[s] = 0.f;
#pragma unroll
    for (int m = 0; m < 2; ++m) {
      const int e = lane + 64*m;
      if (wv == 3) {   // outs 30..39: 30,31 plain; 32,33 x rel; 34..39 plain
        const float v0 = p2[m][0] + bm2[30], v1 = p2[m][1] + bm2[31];
        const float v2 = p2[m][2] + bm2[32], v3 = p2[m][3] + bm2[33];
        outv[0] += v0; outv[1] += v1;
        outv[2] = fmaf(v2, relv[e][0], outv[2]);
        outv[3] = fmaf(v2, relv[e][1], outv[3]);
        outv[4] = fmaf(v2, relv[e][2], outv[4]);
        outv[5] = fmaf(v3, relv[e][0], outv[5]);
        outv[6] = fmaf(v3, relv[e][1], outv[6]);
        outv[7] = fmaf(v3, relv[e][2], outv[7]);
#pragma unroll
        for (int o = 4; o < 10; ++o) outv[4 + o] += p2[m][o] + bm2[30 + o];
      } else {
#pragma unroll
        for (int o = 0; o < 10; ++o) outv[o] += p2[m][o] + bm2[10*wv + o];
      }
    }
#pragma unroll
    for (int s = 0; s < 14; ++s) {
      float v = outv[s];
#pragma unroll
      for (int o = 1; o < 64; o <<= 1) v += __shfl_xor(v, o);
      outv[s] = v;
    }
    if (lane == 0) {
      const int nsl = (wv == 3) ? 14 : 10;
      for (int s = 0; s < nsl; ++s) P2[wv][s] = outv[s];
    }
  }
  __syncthreads();
  if (t < 44) fin[t] = (t < 30) ? P2[t/10][t%10] : P2[3][t-30];
  __syncthreads();

  // ---- epilogue C: state_out + frame update; stage D inputs ----
  float* x0D    = (float*)U;           // 256 (U free after m2)
  float* actD   = x0D + 256;           // 128
  float* residD = actD + 128;          // 128
  float* partD  = residD + 128;        // 2*129

  if (t < 16) {  // state_out = [node_i, m_l0] @ Wl0 + bl0
    float a = bl0[t];
#pragma unroll
    for (int k = 0; k < 32; ++k) a = fmaf(ni[k], Wl0[k*16 + t], a);
#pragma unroll
    for (int k = 0; k < 32; ++k) a = fmaf(fin[k] * (1.f/128.f), Wl0[(32+k)*16 + t], a);
    sout_s[t] = a;
    out[LL*9 + i*16 + t] = a;
  }
  if (t == 0) {  // frame update
    float ve[6], wa[6];
#pragma unroll
    for (int qq = 0; qq < 6; ++qq) ve[qq] = fin[32 + qq] * (1.f/128.f);
#pragma unroll
    for (int qq = 0; qq < 6; ++qq) wa[qq] = fin[38 + qq] * (1.f/128.f);
    float l1[9];
#pragma unroll
    for (int a = 0; a < 3; ++a)
#pragma unroll
      for (int d = 0; d < 3; ++d) l1[a*3 + d] = xyz[i*9 + a*3 + d] - xyz[i*9 + 3 + d];
    float T[3], Rv[3];
#pragma unroll
    for (int d = 0; d < 3; ++d) {
      float va0 = wa[0]*l1[d] + wa[1]*l1[3 + d] + wa[2]*l1[6 + d];
      float va1 = wa[3]*l1[d] + wa[4]*l1[3 + d] + wa[5]*l1[6 + d];
      T[d]  = (ve[d] + va0) / 10.f;
      Rv[d] = (ve[3 + d] + va1) / 100.f;
    }
    float qn = sqrtf(1.f + Rv[0]*Rv[0] + Rv[1]*Rv[1] + Rv[2]*Rv[2]);
    float qA = 1.f/qn, qB = Rv[0]/qn, qC = Rv[1]/qn, qD = Rv[2]/qn;
    float Rm[9];
    Rm[0] = qA*qA + qB*qB - qC*qC - qD*qD;
    Rm[1] = 2.f*qB*qC - 2.f*qA*qD;
    Rm[2] = 2.f*qB*qD + 2.f*qA*qC;
    Rm[3] = 2.f*qB*qC + 2.f*qA*qD;
    Rm[4] = qA*qA - qB*qB + qC*qC - qD*qD;
    Rm[5] = 2.f*qC*qD - 2.f*qA*qB;
    Rm[6] = 2.f*qB*qD - 2.f*qA*qC;
    Rm[7] = 2.f*qC*qD + 2.f*qA*qB;
    Rm[8] = qA*qA - qB*qB - qC*qC + qD*qD;
    if (rmask[i]) {
      Rm[0] = 1.f; Rm[1] = 0.f; Rm[2] = 0.f;
      Rm[3] = 0.f; Rm[4] = 1.f; Rm[5] = 0.f;
      Rm[6] = 0.f; Rm[7] = 0.f; Rm[8] = 1.f;
    }
#pragma unroll
    for (int a = 0; a < 3; ++a)
#pragma unroll
      for (int di = 0; di < 3; ++di) {
        float xn = Rm[di*3+0]*l1[a*3+0] + Rm[di*3+1]*l1[a*3+1] + Rm[di*3+2]*l1[a*3+2]
                 + xyz[i*9 + 3 + di] + T[di];
        out[i*9 + a*3 + di] = xn;
      }
  }
  x0D[t] = seq_ln[i*256 + t];
  __syncthreads();

  // ---- D phase: si MLP stack -> alpha (256 thr, 2-way k-split) ----
  if (t < 16) {
    float m = 0.f;
    for (int k = 0; k < 16; ++k) m += sout_s[k];
    m *= (1.f/16.f);
    float v = 0.f;
    for (int k = 0; k < 16; ++k) { float dd = sout_s[k] - m; v += dd*dd; }
    v *= (1.f/16.f);
    stn[t] = (sout_s[t] - m) / sqrtf(v + 1e-5f);
  }
  __syncthreads();

  const int cD = t & 127, gD = t >> 7;   // gD = 0..1 k-group
  // L0: si = x0 @ Ws0 + stn @ Wsi + bs0 + bsi
  {
    float p = 0.f;
    for (int k = gD*128; k < gD*128 + 128; ++k) p = fmaf(x0D[k], Ws0[k*128 + cD], p);
    if (gD == 0)
      for (int k = 0; k < 16; ++k) p = fmaf(stn[k], Wsi[k*128 + cD], p);
    partD[gD*129 + cD] = p;
  }
  __syncthreads();
  if (t < 128) {
    const float si = partD[t] + partD[129 + t] + bs0[t] + bsi[t];
    residD[t] = si;
    actD[t] = fmaxf(si, 0.f);
  }
  __syncthreads();

  // L1: h = relu(act @ Wp1 + bp1)
  {
    float p = 0.f;
    for (int k = gD*64; k < gD*64 + 64; ++k) p = fmaf(actD[k], Wp1[k*128 + cD], p);
    partD[gD*129 + cD] = p;
  }
  __syncthreads();
  if (t < 128)
    actD[t] = fmaxf(partD[t] + partD[129 + t] + bp1[t], 0.f);
  __syncthreads();

  // L2: si += h @ Wp2 + bp2
  {
    float p = 0.f;
    for (int k = gD*64; k < gD*64 + 64; ++k) p = fmaf(actD[k], Wp2[k*128 + cD], p);
    partD[gD*129 + cD] = p;
  }
  __syncthreads();
  if (t < 128) {
    const float si = residD[t] + partD[t] + partD[129 + t] + bp2[t];
    residD[t] = si;
    actD[t] = fmaxf(si, 0.f);
  }
  __syncthreads();

  // L3: h = relu(act @ Wp3 + bp3)
  {
    float p = 0.f;
    for (int k = gD*64; k < gD*64 + 64; ++k) p = fmaf(actD[k], Wp3[k*128 + cD], p);
    partD[gD*129 + cD] = p;
  }
  __syncthreads();
  if (t < 128)
    actD[t] = fmaxf(partD[t] + partD[129 + t] + bp3[t], 0.f);
  __syncthreads();

  // L4: si += h @ Wp4 + bp4; rc = relu(si)
  {
    float p = 0.f;
    for (int k = gD*64; k < gD*64 + 64; ++k) p = fmaf(actD[k], Wp4[k*128 + cD], p);
    partD[gD*129 + cD] = p;
  }
  __syncthreads();
  if (t < 128)
    actD[t] = fmaxf(residD[t] + partD[t] + partD[129 + t] + bp4[t], 0.f);
  __syncthreads();

  // out: alpha = rc @ Wout + bout (20 outputs)
  if (t < 20) {
    float a = bout[t];
    for (int k = 0; k < 128; ++k) a = fmaf(actD[k], Wout[k*20 + t], a);
    out[19200 + i*20 + t] = a;
  }
}

extern "C" void kernel_launch(void* const* d_in, const int* in_sizes, int n_in,
                              void* d_out, int out_size, void* d_ws, size_t ws_size,
                              hipStream_t stream)
{
  (void)in_sizes; (void)n_in; (void)out_size; (void)ws_size;
  const float* msa   = (const float*)d_in[0];
  const float* pair  = (const float*)d_in[1];
  const float* xyz   = (const float*)d_in[2];
  const float* state = (const float*)d_in[3];
  const int*   idx   = (const int*)d_in[4];
  const unsigned char* rmask = (const unsigned char*)d_in[5];
  const float* W_en = (const float*)d_in[6];
  const float* b_en = (const float*)d_in[7];
  const float* Wn1  = (const float*)d_in[8];
  const float* bn1  = (const float*)d_in[9];
  const float* Wn2  = (const float*)d_in[10];
  const float* bn2  = (const float*)d_in[11];
  const float* W_ee = (const float*)d_in[12];
  const float* b_ee = (const float*)d_in[13];
  const float* We1  = (const float*)d_in[14];
  const float* be1  = (const float*)d_in[15];
  const float* We2  = (const float*)d_in[16];
  const float* be2  = (const float*)d_in[17];
  const float* Wm1  = (const float*)d_in[18];
  const float* bm1  = (const float*)d_in[19];
  const float* Wm2  = (const float*)d_in[20];
  const float* bm2  = (const float*)d_in[21];
  const float* Wl0  = (const float*)d_in[22];
  const float* bl0  = (const float*)d_in[23];
  const float* Ws0  = (const float*)d_in[24];
  const float* bs0  = (const float*)d_in[25];
  const float* Wsi  = (const float*)d_in[26];
  const float* bsi  = (const float*)d_in[27];
  const float* Wp1  = (const float*)d_in[28];
  const float* bp1  = (const float*)d_in[29];
  const float* Wp2  = (const float*)d_in[30];
  const float* bp2  = (const float*)d_in[31];
  const float* Wp3  = (const float*)d_in[32];
  const float* bp3  = (const float*)d_in[33];
  const float* Wp4  = (const float*)d_in[34];
  const float* bp4  = (const float*)d_in[35];
  const float* Wout = (const float*)d_in[36];
  const float* bout = (const float*)d_in[37];

  float* wsf    = (float*)d_ws;
  float* seq_ln = wsf + WS_SEQ;
  float* nodev  = wsf + WS_NODE;
  int*   nbr    = (int*)(wsf + WS_NBR);
  float* csee   = wsf + WS_CSEE;
  float* out = (float*)d_out;

  kernABP<<<2*LL + 1, 256, 0, stream>>>(msa, state, W_en, b_en, Wn1, bn1, Wn2, bn2,
                                        xyz, W_ee, seq_ln, nodev, nbr, csee);
  kernCD<<<LL, 256, 0, stream>>>(pair, xyz, idx, rmask, W_ee, b_ee, csee,
                                 We1, be1, We2, be2, Wm1, bm1, Wm2, bm2,
                                 Wl0, bl0, nodev, nbr, seq_ln,
                                 Ws0, bs0, Wsi, bsi, Wp1, bp1, Wp2, bp2,
                                 Wp3, bp3, Wp4, bp4, Wout, bout, out);
}

// Round 13
// 120.883 us; speedup vs baseline: 1.4085x; 1.4085x over previous
//
#include <hip/hip_runtime.h>
#include <hip/hip_bf16.h>

#define LL 768
#define TOPK 128

// workspace layout (floats)
#define WS_SEQ  0                        // 768*256
#define WS_NODE (WS_SEQ + LL*256)        // 768*32
#define WS_NBR  (WS_NODE + LL*32)        // 768*128 ints
#define WS_SOUT (WS_NBR + LL*TOPK)       // 768*16
#define WS_CSEE (WS_SOUT + LL*16)        // 32

// bf16 pair pack/unpack (RNE)
__device__ __forceinline__ unsigned bfpack(float a, float b) {
  unsigned ua = __float_as_uint(a);
  ua = (ua + 0x7fffu + ((ua >> 16) & 1u)) >> 16;
  unsigned ub = __float_as_uint(b);
  ub = (ub + 0x7fffu + ((ub >> 16) & 1u)) & 0xffff0000u;
  return ua | ub;
}
__device__ __forceinline__ float bflo(unsigned v) { return __uint_as_float(v << 16); }
__device__ __forceinline__ float bfhi(unsigned v) { return __uint_as_float(v & 0xffff0000u); }

__device__ __forceinline__ float block_sum_256(float v, float* red, int t) {
#pragma unroll
  for (int o = 32; o > 0; o >>= 1) v += __shfl_xor(v, o, 64);
  __syncthreads();
  if ((t & 63) == 0) red[t >> 6] = v;
  __syncthreads();
  return red[0] + red[1] + red[2] + red[3];
}

// ---------------- Kernel ABP: A (blocks 0..767), B (768..1535), P (1536) ----
__global__ __launch_bounds__(256) void kernABP(
    const float* __restrict__ msa, const float* __restrict__ state,
    const float* __restrict__ W_en, const float* __restrict__ b_en,
    const float* __restrict__ Wn1, const float* __restrict__ bn1,
    const float* __restrict__ Wn2, const float* __restrict__ bn2,
    const float* __restrict__ xyz, const float* __restrict__ W_ee,
    float* __restrict__ seq_ln, float* __restrict__ nodeo,
    int* __restrict__ nbr, float* __restrict__ colsum_ee)
{
  const int bid = blockIdx.x, t = threadIdx.x;
  __shared__ float x[256];
  __shared__ float red[4];
  __shared__ float sn[16], n0[32], tn[32], hh[64], n1v[32];
  __shared__ float partA[8][33];
  __shared__ unsigned hist[256];
  __shared__ int selBin, below;
  __shared__ unsigned wcL[4], wcE[4];

  if (bid < LL) {
    // ================= A: seq LN, state LN, node MLP + LN =================
    const int i = bid;
    float v = msa[i*256 + t];
    float mean = block_sum_256(v, red, t) * (1.f/256.f);
    float d = v - mean;
    float var = block_sum_256(d*d, red, t) * (1.f/256.f);
    float xn = d / sqrtf(var + 1e-5f);
    x[t] = xn;
    seq_ln[i*256 + t] = xn;

    if (t < 16) {
      float m2 = 0.f;
      for (int k = 0; k < 16; ++k) m2 += state[i*16 + k];
      m2 *= (1.f/16.f);
      float v2 = 0.f;
      for (int k = 0; k < 16; ++k) { float dd = state[i*16 + k] - m2; v2 += dd*dd; }
      v2 *= (1.f/16.f);
      sn[t] = (state[i*16 + t] - m2) / sqrtf(v2 + 1e-5f);
    }
    __syncthreads();

    {  // k-split matvec over ALL 256 threads
      const int g = t >> 5, c = t & 31;
      float p = 0.f;
      for (int k = g*32; k < g*32 + 32; ++k) p = fmaf(x[k], W_en[k*32 + c], p);
      if (g == 7)
        for (int k = 0; k < 16; ++k) p = fmaf(sn[k], W_en[(256+k)*32 + c], p);
      partA[g][c] = p;
    }
    __syncthreads();
    if (t < 32) {
      float a = b_en[t];
#pragma unroll
      for (int g = 0; g < 8; ++g) a += partA[g][t];
      n0[t] = a;
    }
    __syncthreads();
    if (t < 32) {
      float m = 0.f;
      for (int k = 0; k < 32; ++k) m += n0[k];
      m *= (1.f/32.f);
      float vv = 0.f;
      for (int k = 0; k < 32; ++k) { float dd = n0[k] - m; vv += dd*dd; }
      vv *= (1.f/32.f);
      tn[t] = (n0[t] - m) / sqrtf(vv + 1e-5f);
    }
    __syncthreads();
    if (t < 64) {
      float a = bn1[t];
      for (int k = 0; k < 32; ++k) a = fmaf(tn[k], Wn1[k*64 + t], a);
      hh[t] = fmaxf(a, 0.f);
    }
    __syncthreads();
    if (t < 32) {
      float a = n0[t] + bn2[t];
      for (int k = 0; k < 64; ++k) a = fmaf(hh[k], Wn2[k*32 + t], a);
      n1v[t] = a;
    }
    __syncthreads();
    if (t < 32) {
      float m = 0.f;
      for (int k = 0; k < 32; ++k) m += n1v[k];
      m *= (1.f/32.f);
      float vv = 0.f;
      for (int k = 0; k < 32; ++k) { float dd = n1v[k] - m; vv += dd*dd; }
      vv *= (1.f/32.f);
      nodeo[i*32 + t] = (n1v[t] - m) / sqrtf(vv + 1e-5f);
    }
    return;
  }

  if (bid < 2*LL) {
    // ================= B: top-128 nearest via 4-pass radix select ==========
    const int i = bid - LL;
    const int lane = t & 63, wv = t >> 6;

    const float cix = xyz[i*9+3], ciy = xyz[i*9+4], ciz = xyz[i*9+5];
    unsigned key[3];
#pragma unroll
    for (int r = 0; r < 3; ++r) {
      const int j = r*256 + t;
      float dx = __fadd_rn(cix, -xyz[j*9+3]);
      float dy = __fadd_rn(ciy, -xyz[j*9+4]);
      float dz = __fadd_rn(ciz, -xyz[j*9+5]);
      float Dv = sqrtf(__fadd_rn(__fadd_rn(__fadd_rn(__fmul_rn(dx,dx),
                         __fmul_rn(dy,dy)), __fmul_rn(dz,dz)), 1e-8f));
      key[r] = __float_as_uint(Dv);
    }

    unsigned prefix = 0;
    int rank = 127, cntLess = 0;
#pragma unroll
    for (int pass = 0; pass < 4; ++pass) {
      const int shift = 24 - pass*8;
      const unsigned hiMask = (pass == 0) ? 0u : (0xFFFFFFFFu << (shift + 8));
      hist[t] = 0;
      __syncthreads();
#pragma unroll
      for (int r = 0; r < 3; ++r)
        if ((key[r] & hiMask) == (prefix & hiMask))
          atomicAdd(&hist[(key[r] >> shift) & 0xffu], 1u);
      __syncthreads();
      if (t < 64) {
        unsigned s0 = hist[t*4], s1 = hist[t*4+1], s2 = hist[t*4+2], s3 = hist[t*4+3];
        int tot = (int)(s0 + s1 + s2 + s3);
        int inc = tot;
#pragma unroll
        for (int o = 1; o < 64; o <<= 1) {
          int v = __shfl_up(inc, o);
          if (t >= o) inc += v;
        }
        int excl = inc - tot;
        if (rank >= excl && rank < inc) {
          int c = excl, bsel = t*4;
          if (rank >= c + (int)s0) { c += (int)s0; bsel = t*4+1;
            if (rank >= c + (int)s1) { c += (int)s1; bsel = t*4+2;
              if (rank >= c + (int)s2) { c += (int)s2; bsel = t*4+3; } } }
          selBin = bsel; below = c;
        }
      }
      __syncthreads();
      prefix |= ((unsigned)selBin) << shift;
      rank -= below;
      cntLess += below;
      __syncthreads();
    }
    const unsigned thr = prefix;

    const unsigned long long lmask = (1ull << lane) - 1ull;
    unsigned baseLt = 0, baseEq = (unsigned)cntLess;
#pragma unroll
    for (int r = 0; r < 3; ++r) {
      const int j = r*256 + t;
      const bool pl = key[r] < thr;
      const bool pe = key[r] == thr;
      unsigned long long balL = __ballot(pl);
      unsigned long long balE = __ballot(pe);
      unsigned preL = (unsigned)__popcll(balL & lmask);
      unsigned preE = (unsigned)__popcll(balE & lmask);
      if (lane == 0) { wcL[wv] = (unsigned)__popcll(balL); wcE[wv] = (unsigned)__popcll(balE); }
      __syncthreads();
      unsigned wbL = 0, wbE = 0, totL = 0, totE = 0;
#pragma unroll
      for (int w = 0; w < 4; ++w) {
        if (w < wv) { wbL += wcL[w]; wbE += wcE[w]; }
        totL += wcL[w]; totE += wcE[w];
      }
      if (pl) nbr[i*TOPK + baseLt + wbL + preL] = j;
      if (pe) {
        unsigned pos = baseEq + wbE + preE;
        if (pos < TOPK) nbr[i*TOPK + pos] = j;
      }
      baseLt += totL; baseEq += totE;
      __syncthreads();
    }
    return;
  }

  // ================= P: column sums of W_ee pair-part ======================
  {
    const int c = t & 31, sg = t >> 5;
    float s = 0.f;
    for (int k = sg*16; k < sg*16 + 16; ++k) s += W_ee[k*32 + c];
    partA[sg][c] = s;
    __syncthreads();
    if (t < 32) {
      float tot = 0.f;
#pragma unroll
      for (int g = 0; g < 8; ++g) tot += partA[g][t];
      colsum_ee[t] = tot;
    }
  }
}

// ---------------- Kernel C (FUSED C1+C2), 4 blocks/CU -----------------------
__global__ __launch_bounds__(256, 4) void kernC(
    const float* __restrict__ pair, const float* __restrict__ xyz,
    const int* __restrict__ idx, const unsigned char* __restrict__ rmask,
    const float* __restrict__ W_ee, const float* __restrict__ b_ee,
    const float* __restrict__ colsum_ee,
    const float* __restrict__ We1, const float* __restrict__ be1,
    const float* __restrict__ We2, const float* __restrict__ be2,
    const float* __restrict__ Wm1, const float* __restrict__ bm1,
    const float* __restrict__ Wm2, const float* __restrict__ bm2,
    const float* __restrict__ Wl0, const float* __restrict__ bl0,
    const float* __restrict__ node, const int* __restrict__ nbr,
    float* __restrict__ soutf, float* __restrict__ out)
{
  const int i = blockIdx.x, t = threadIdx.x;
  const int lane = t & 63;
  const int wv = __builtin_amdgcn_readfirstlane(t >> 6);   // uniform 0..3
  __shared__ unsigned Ab[128][17];     // e0 -> ed -> e2 -> ed2 (bf16 pairs)
  __shared__ unsigned U[128*33];       // pairB[64][65] then Bb[128][33]
  __shared__ unsigned nd[128][17];     // node rows (bf16 pairs)
  __shared__ int   jl[128];
  __shared__ float Dvv[128], xsepv[128];
  __shared__ float relv[128][3];
  __shared__ float ni[32];
  __shared__ float pmv[64], prsv[64];
  __shared__ float mA[128], sgA[128];
  __shared__ float P2[4][14];
  __shared__ float fin[44];

  // ---- phase 0: stage ni, nd, jl, relv, Dv, xsep ----
  if (t < 32) ni[t] = node[i*32 + t];
  {
    const int pp = t >> 1, hh2 = t & 1;
    const int jj = nbr[i*TOPK + pp];
    const float4* nr = (const float4*)(node + jj*32 + hh2*16);
    float4 a0 = nr[0], a1 = nr[1], a2 = nr[2], a3 = nr[3];
    unsigned* dst = &nd[pp][hh2*8];
    dst[0] = bfpack(a0.x, a0.y); dst[1] = bfpack(a0.z, a0.w);
    dst[2] = bfpack(a1.x, a1.y); dst[3] = bfpack(a1.z, a1.w);
    dst[4] = bfpack(a2.x, a2.y); dst[5] = bfpack(a2.z, a2.w);
    dst[6] = bfpack(a3.x, a3.y); dst[7] = bfpack(a3.z, a3.w);
    if (hh2 == 0) {
      jl[pp] = jj;
      const float cix = xyz[i*9+3], ciy = xyz[i*9+4], ciz = xyz[i*9+5];
      const float cjx = xyz[jj*9+3], cjy = xyz[jj*9+4], cjz = xyz[jj*9+5];
      relv[pp][0] = cjx - cix;
      relv[pp][1] = cjy - ciy;
      relv[pp][2] = cjz - ciz;
      const float dx = __fadd_rn(cix, -cjx), dy = __fadd_rn(ciy, -cjy),
                  dz = __fadd_rn(ciz, -cjz);
      Dvv[pp] = sqrtf(__fadd_rn(__fadd_rn(__fadd_rn(__fmul_rn(dx,dx),
                        __fmul_rn(dy,dy)), __fmul_rn(dz,dz)), 1e-8f));
      const float offv = (float)(idx[jj] - idx[i]);
      const float sg = (offv > 0.f) ? 1.f : ((offv < 0.f) ? -1.f : 0.f);
      xsepv[pp] = sg * logf(fabsf(offv) + 1.f);
    }
  }
  __syncthreads();

  // ---- phase C1': edge0 into Ab, two 64-edge sub-passes ----
  unsigned (*pairB)[65] = (unsigned (*)[65])U;
  for (int sub = 0; sub < 2; ++sub) {
    {  // coalesced stage of 64 pair rows -> bf16 LDS; stats via quad shuffle
      const int r = t >> 2, qq = t & 3;
      const float* prow = pair + ((size_t)i*LL + jl[sub*64 + r])*128 + qq*32;
      float s = 0.f, ss = 0.f;
#pragma unroll
      for (int n = 0; n < 8; ++n) {
        float4 v = ((const float4*)prow)[n];
        s  += (v.x + v.y) + (v.z + v.w);
        ss += v.x*v.x + v.y*v.y + v.z*v.z + v.w*v.w;
        pairB[r][qq*16 + n*2]     = bfpack(v.x, v.y);
        pairB[r][qq*16 + n*2 + 1] = bfpack(v.z, v.w);
      }
      s  += __shfl_xor(s, 1);  s  += __shfl_xor(s, 2);
      ss += __shfl_xor(ss, 1); ss += __shfl_xor(ss, 2);
      if (qq == 0) {
        const float pm = s * (1.f/128.f);
        const float pv = ss * (1.f/128.f) - pm*pm;
        pmv[r] = pm; prsv[r] = 1.f / sqrtf(pv + 1e-5f);
      }
    }
    __syncthreads();
    {  // matvec: lane = local edge, wave = 8-ch strip (scalar weights)
      const int el = lane;
      const int e = sub*64 + el;
      float acc[8], acc2[8];
#pragma unroll
      for (int c = 0; c < 8; ++c) { acc[c] = 0.f; acc2[c] = 0.f; }
#pragma unroll 4
      for (int kk = 0; kk < 64; ++kk) {   // pair part, k = 2kk, 2kk+1
        const unsigned v = pairB[el][kk];
        const float al = bflo(v), ah = bfhi(v);
        const float* w0 = W_ee + (2*kk)*32   + 8*wv;   // uniform -> s_load
        const float* w1 = W_ee + (2*kk+1)*32 + 8*wv;
#pragma unroll
        for (int c = 0; c < 8; ++c)
          acc[c] = fmaf(al, w0[c], fmaf(ah, w1[c], acc[c]));
      }
      const float Dv = Dvv[e];
#pragma unroll 4
      for (int k = 0; k < 64; ++k) {      // RBF part
        const float mu = 2.f + (float)k * (20.f/63.f);
        const float u  = (Dv - mu) / 0.3125f;
        const float w  = expf(-(u*u));
        const float* wr = W_ee + (128+k)*32 + 8*wv;    // uniform
#pragma unroll
        for (int c = 0; c < 8; ++c) acc2[c] = fmaf(w, wr[c], acc2[c]);
      }
      const float pm = pmv[el], prs = prsv[el];
      const float corr = -prs * pm;
      const float xs = xsepv[e];
      float val[8];
#pragma unroll
      for (int c = 0; c < 8; ++c) {
        const int ch = 8*wv + c;
        val[c] = fmaf(prs, acc[c],
                   fmaf(corr, colsum_ee[ch],
                     fmaf(xs, W_ee[192*32 + ch], b_ee[ch] + acc2[c])));
      }
#pragma unroll
      for (int n = 0; n < 4; ++n)
        Ab[e][4*wv + n] = bfpack(val[2*n], val[2*n+1]);
    }
    __syncthreads();
  }

  // ---- C2 phases ----
  unsigned (*Bb)[33] = (unsigned (*)[33])U;

  // LN(Ab) in place; keep (mean, sigma) for the residual undo
  if (t < 128) {
    float av[32];
#pragma unroll
    for (int kk = 0; kk < 16; ++kk) {
      const unsigned v = Ab[t][kk];
      av[2*kk] = bflo(v); av[2*kk+1] = bfhi(v);
    }
    float mm = 0.f;
#pragma unroll
    for (int c = 0; c < 32; ++c) mm += av[c];
    mm *= (1.f/32.f);
    float vv = 0.f;
#pragma unroll
    for (int c = 0; c < 32; ++c) { float dd = av[c]-mm; vv += dd*dd; }
    vv *= (1.f/32.f);
    const float sg = sqrtf(vv + 1e-5f);
    const float rs = 1.f / sg;
#pragma unroll
    for (int kk = 0; kk < 16; ++kk)
      Ab[t][kk] = bfpack((av[2*kk]-mm)*rs, (av[2*kk+1]-mm)*rs);
    mA[t] = mm; sgA[t] = sg;
  }
  __syncthreads();

  // ---- h = relu(ed @ We1 + be1): 2 edges x 16 ch (cols [16wv,16wv+16)) ----
  {
    float hacc[2][16];
#pragma unroll
    for (int m = 0; m < 2; ++m)
#pragma unroll
      for (int c = 0; c < 16; ++c) hacc[m][c] = 0.f;
#pragma unroll 4
    for (int kk = 0; kk < 16; ++kk) {   // k = 2kk, 2kk+1
      const float* wbl = We1 + (2*kk)*64 + 16*wv;     // uniform -> s_load
      const float* wbh = We1 + (2*kk+1)*64 + 16*wv;
      const unsigned v0 = Ab[lane][kk], v1 = Ab[lane+64][kk];
#pragma unroll
      for (int m = 0; m < 2; ++m) {
        const unsigned v = m ? v1 : v0;
        const float al = bflo(v), ah = bfhi(v);
#pragma unroll
        for (int c = 0; c < 16; ++c)
          hacc[m][c] = fmaf(al, wbl[c], fmaf(ah, wbh[c], hacc[m][c]));
      }
    }
#pragma unroll
    for (int m = 0; m < 2; ++m) {
      const int e = lane + 64*m;
#pragma unroll
      for (int n = 0; n < 8; ++n) {
        const float lo = fmaxf(hacc[m][2*n]   + be1[16*wv + 2*n],   0.f);
        const float hi = fmaxf(hacc[m][2*n+1] + be1[16*wv + 2*n+1], 0.f);
        Bb[e][8*wv + n] = bfpack(lo, hi);
      }
    }
  }
  __syncthreads();

  // ---- e2 = e0raw + h @ We2 + be2: 2 edges x 8 ch (cols [8wv,8wv+8)) ----
  {
    float e2a[2][8];
#pragma unroll
    for (int m = 0; m < 2; ++m)
#pragma unroll
      for (int c = 0; c < 8; ++c) e2a[m][c] = 0.f;
#pragma unroll 4
    for (int kk = 0; kk < 32; ++kk) {   // k = 2kk, 2kk+1
      const float* wbl = We2 + (2*kk)*32   + 8*wv;   // uniform
      const float* wbh = We2 + (2*kk+1)*32 + 8*wv;
      const unsigned v0 = Bb[lane][kk], v1 = Bb[lane+64][kk];
#pragma unroll
      for (int m = 0; m < 2; ++m) {
        const unsigned v = m ? v1 : v0;
        const float al = bflo(v), ah = bfhi(v);
#pragma unroll
        for (int c = 0; c < 8; ++c)
          e2a[m][c] = fmaf(al, wbl[c], fmaf(ah, wbh[c], e2a[m][c]));
      }
    }
#pragma unroll
    for (int m = 0; m < 2; ++m) {
      const int e = lane + 64*m;
      const float sg = sgA[e], mm = mA[e];
#pragma unroll
      for (int n = 0; n < 4; ++n) {
        const int ch0 = 8*wv + 2*n;
        const unsigned old = Ab[e][4*wv + n];
        const float e0lo = fmaf(bflo(old), sg, mm);
        const float e0hi = fmaf(bfhi(old), sg, mm);
        Ab[e][4*wv + n] = bfpack(e2a[m][2*n]   + e0lo + be2[ch0],
                                 e2a[m][2*n+1] + e0hi + be2[ch0+1]);
      }
    }
  }
  __syncthreads();

  // LN(e2) in place
  if (t < 128) {
    float av[32];
#pragma unroll
    for (int kk = 0; kk < 16; ++kk) {
      const unsigned v = Ab[t][kk];
      av[2*kk] = bflo(v); av[2*kk+1] = bfhi(v);
    }
    float mm = 0.f;
#pragma unroll
    for (int c = 0; c < 32; ++c) mm += av[c];
    mm *= (1.f/32.f);
    float vv = 0.f;
#pragma unroll
    for (int c = 0; c < 32; ++c) { float dd = av[c]-mm; vv += dd*dd; }
    vv *= (1.f/32.f);
    const float rs = 1.f / sqrtf(vv + 1e-5f);
#pragma unroll
    for (int kk = 0; kk < 16; ++kk)
      Ab[t][kk] = bfpack((av[2*kk]-mm)*rs, (av[2*kk+1]-mm)*rs);
  }
  __syncthreads();

  // ---- m1 = relu([ni, nj, ed2] @ Wm1 + bm1): 2 edges x 16 ch ----
  {
    float tmp[16];   // ni part — identical for both edges
#pragma unroll
    for (int c = 0; c < 16; ++c) tmp[c] = bm1[16*wv + c];
#pragma unroll 4
    for (int k = 0; k < 32; ++k) {
      const float* wb = Wm1 + k*64 + 16*wv;   // uniform
      const float av = ni[k];
#pragma unroll
      for (int c = 0; c < 16; ++c) tmp[c] = fmaf(av, wb[c], tmp[c]);
    }
    float macc[2][16];
#pragma unroll
    for (int m = 0; m < 2; ++m)
#pragma unroll
      for (int c = 0; c < 16; ++c) macc[m][c] = 0.f;
#pragma unroll 4
    for (int kk = 0; kk < 16; ++kk) {   // h_j part (bf16 pairs)
      const float* wbl = Wm1 + (32+2*kk)*64 + 16*wv;   // uniform
      const float* wbh = Wm1 + (33+2*kk)*64 + 16*wv;
      const unsigned v0 = nd[lane][kk], v1 = nd[lane+64][kk];
#pragma unroll
      for (int m = 0; m < 2; ++m) {
        const unsigned v = m ? v1 : v0;
        const float al = bflo(v), ah = bfhi(v);
#pragma unroll
        for (int c = 0; c < 16; ++c)
          macc[m][c] = fmaf(al, wbl[c], fmaf(ah, wbh[c], macc[m][c]));
      }
    }
#pragma unroll 4
    for (int kk = 0; kk < 16; ++kk) {   // edge part (bf16 pairs from Ab)
      const float* wbl = Wm1 + (64+2*kk)*64 + 16*wv;   // uniform
      const float* wbh = Wm1 + (65+2*kk)*64 + 16*wv;
      const unsigned v0 = Ab[lane][kk], v1 = Ab[lane+64][kk];
#pragma unroll
      for (int m = 0; m < 2; ++m) {
        const unsigned v = m ? v1 : v0;
        const float al = bflo(v), ah = bfhi(v);
#pragma unroll
        for (int c = 0; c < 16; ++c)
          macc[m][c] = fmaf(al, wbl[c], fmaf(ah, wbh[c], macc[m][c]));
      }
    }
    __syncthreads();   // all Bb reads (e2 phase) complete before overwrite
#pragma unroll
    for (int m = 0; m < 2; ++m) {
      const int e = lane + 64*m;
#pragma unroll
      for (int n = 0; n < 8; ++n) {
        const float lo = fmaxf(macc[m][2*n]   + tmp[2*n],   0.f);
        const float hi = fmaxf(macc[m][2*n+1] + tmp[2*n+1], 0.f);
        Bb[e][8*wv + n] = bfpack(lo, hi);
      }
    }
  }
  __syncthreads();

  // ---- m2: 2 edges x 10 outs (cols [10wv,10wv+10)); expand + wave reduce ----
  {
    float p2[2][10];
#pragma unroll
    for (int m = 0; m < 2; ++m)
#pragma unroll
      for (int o = 0; o < 10; ++o) p2[m][o] = 0.f;
#pragma unroll 4
    for (int kk = 0; kk < 32; ++kk) {   // k = 2kk, 2kk+1
      const float* wr0 = Wm2 + (2*kk)*40   + 10*wv;   // uniform
      const float* wr1 = Wm2 + (2*kk+1)*40 + 10*wv;
      const unsigned v0 = Bb[lane][kk], v1 = Bb[lane+64][kk];
#pragma unroll
      for (int m = 0; m < 2; ++m) {
        const unsigned v = m ? v1 : v0;
        const float al = bflo(v), ah = bfhi(v);
#pragma unroll
        for (int o = 0; o < 10; ++o)
          p2[m][o] = fmaf(al, wr0[o], fmaf(ah, wr1[o], p2[m][o]));
      }
    }
    float outv[14];
#pragma unroll
    for (int s = 0; s < 14; ++s) outv[s] = 0.f;
#pragma unroll
    for (int m = 0; m < 2; ++m) {
      const int e = lane + 64*m;
      if (wv == 3) {   // outs 30..39: 30,31 plain; 32,33 x rel; 34..39 plain
        const float v0 = p2[m][0] + bm2[30], v1 = p2[m][1] + bm2[31];
        const float v2 = p2[m][2] + bm2[32], v3 = p2[m][3] + bm2[33];
        outv[0] += v0; outv[1] += v1;
        outv[2] = fmaf(v2, relv[e][0], outv[2]);
        outv[3] = fmaf(v2, relv[e][1], outv[3]);
        outv[4] = fmaf(v2, relv[e][2], outv[4]);
        outv[5] = fmaf(v3, relv[e][0], outv[5]);
        outv[6] = fmaf(v3, relv[e][1], outv[6]);
        outv[7] = fmaf(v3, relv[e][2], outv[7]);
#pragma unroll
        for (int o = 4; o < 10; ++o) outv[4 + o] += p2[m][o] + bm2[30 + o];
      } else {
#pragma unroll
        for (int o = 0; o < 10; ++o) outv[o] += p2[m][o] + bm2[10*wv + o];
      }
    }
#pragma unroll
    for (int s = 0; s < 14; ++s) {
      float v = outv[s];
#pragma unroll
      for (int o = 1; o < 64; o <<= 1) v += __shfl_xor(v, o);
      outv[s] = v;
    }
    if (lane == 0) {
      const int nsl = (wv == 3) ? 14 : 10;
      for (int s = 0; s < nsl; ++s) P2[wv][s] = outv[s];
    }
  }
  __syncthreads();
  if (t < 44) fin[t] = (t < 30) ? P2[t/10][t%10] : P2[3][t-30];
  __syncthreads();

  if (t < 16) {  // state_out = [node_i, m_l0] @ Wl0 + bl0
    float a = bl0[t];
#pragma unroll
    for (int k = 0; k < 32; ++k) a = fmaf(ni[k], Wl0[k*16 + t], a);
#pragma unroll
    for (int k = 0; k < 32; ++k) a = fmaf(fin[k] * (1.f/128.f), Wl0[(32+k)*16 + t], a);
    soutf[i*16 + t] = a;
    out[LL*9 + i*16 + t] = a;
  }
  if (t == 0) {  // frame update
    float ve[6], wa[6];
#pragma unroll
    for (int qq = 0; qq < 6; ++qq) ve[qq] = fin[32 + qq] * (1.f/128.f);
#pragma unroll
    for (int qq = 0; qq < 6; ++qq) wa[qq] = fin[38 + qq] * (1.f/128.f);
    float l1[9];
#pragma unroll
    for (int a = 0; a < 3; ++a)
#pragma unroll
      for (int d = 0; d < 3; ++d) l1[a*3 + d] = xyz[i*9 + a*3 + d] - xyz[i*9 + 3 + d];
    float T[3], Rv[3];
#pragma unroll
    for (int d = 0; d < 3; ++d) {
      float va0 = wa[0]*l1[d] + wa[1]*l1[3 + d] + wa[2]*l1[6 + d];
      float va1 = wa[3]*l1[d] + wa[4]*l1[3 + d] + wa[5]*l1[6 + d];
      T[d]  = (ve[d] + va0) / 10.f;
      Rv[d] = (ve[3 + d] + va1) / 100.f;
    }
    float qn = sqrtf(1.f + Rv[0]*Rv[0] + Rv[1]*Rv[1] + Rv[2]*Rv[2]);
    float qA = 1.f/qn, qB = Rv[0]/qn, qC = Rv[1]/qn, qD = Rv[2]/qn;
    float Rm[9];
    Rm[0] = qA*qA + qB*qB - qC*qC - qD*qD;
    Rm[1] = 2.f*qB*qC - 2.f*qA*qD;
    Rm[2] = 2.f*qB*qD + 2.f*qA*qC;
    Rm[3] = 2.f*qB*qC + 2.f*qA*qD;
    Rm[4] = qA*qA - qB*qB + qC*qC - qD*qD;
    Rm[5] = 2.f*qC*qD - 2.f*qA*qB;
    Rm[6] = 2.f*qB*qD - 2.f*qA*qC;
    Rm[7] = 2.f*qC*qD + 2.f*qA*qB;
    Rm[8] = qA*qA - qB*qB - qC*qC + qD*qD;
    if (rmask[i]) {
      Rm[0] = 1.f; Rm[1] = 0.f; Rm[2] = 0.f;
      Rm[3] = 0.f; Rm[4] = 1.f; Rm[5] = 0.f;
      Rm[6] = 0.f; Rm[7] = 0.f; Rm[8] = 1.f;
    }
#pragma unroll
    for (int a = 0; a < 3; ++a)
#pragma unroll
      for (int di = 0; di < 3; ++di) {
        float xn = Rm[di*3+0]*l1[a*3+0] + Rm[di*3+1]*l1[a*3+1] + Rm[di*3+2]*l1[a*3+2]
                 + xyz[i*9 + 3 + di] + T[di];
        out[i*9 + a*3 + di] = xn;
      }
  }
}

// ---------------- Kernel D: si MLP stack -> alpha (512 thr, 4-way k-split) --
__global__ __launch_bounds__(512) void kernD(
    const float* __restrict__ seq_ln, const float* __restrict__ st_out,
    const float* __restrict__ Ws0, const float* __restrict__ bs0,
    const float* __restrict__ Wsi, const float* __restrict__ bsi,
    const float* __restrict__ Wp1, const float* __restrict__ bp1,
    const float* __restrict__ Wp2, const float* __restrict__ bp2,
    const float* __restrict__ Wp3, const float* __restrict__ bp3,
    const float* __restrict__ Wp4, const float* __restrict__ bp4,
    const float* __restrict__ Wout, const float* __restrict__ bout,
    float* __restrict__ out)
{
  const int i = blockIdx.x, t = threadIdx.x;
  const int c = t & 127, g = t >> 7;   // g = 0..3 k-group
  __shared__ float x0[256], stn[16], act[128], resid[128], part[4][129];

  if (t < 256) x0[t] = seq_ln[i*256 + t];
  if (t < 16) {
    float m = 0.f;
    for (int k = 0; k < 16; ++k) m += st_out[i*16 + k];
    m *= (1.f/16.f);
    float v = 0.f;
    for (int k = 0; k < 16; ++k) { float dd = st_out[i*16 + k] - m; v += dd*dd; }
    v *= (1.f/16.f);
    stn[t] = (st_out[i*16 + t] - m) / sqrtf(v + 1e-5f);
  }
  __syncthreads();

  // L0: si = x0 @ Ws0 + stn @ Wsi + bs0 + bsi
  {
    float p = 0.f;
    for (int k = g*64; k < g*64 + 64; ++k) p = fmaf(x0[k], Ws0[k*128 + c], p);
    if (g == 0)
      for (int k = 0; k < 16; ++k) p = fmaf(stn[k], Wsi[k*128 + c], p);
    part[g][c] = p;
  }
  __syncthreads();
  if (t < 128) {
    const float si = part[0][t] + part[1][t] + part[2][t] + part[3][t]
                   + bs0[t] + bsi[t];
    resid[t] = si;
    act[t] = fmaxf(si, 0.f);
  }
  __syncthreads();

  // L1: h = relu(act @ Wp1 + bp1)
  {
    float p = 0.f;
    for (int k = g*32; k < g*32 + 32; ++k) p = fmaf(act[k], Wp1[k*128 + c], p);
    part[g][c] = p;
  }
  __syncthreads();
  if (t < 128)
    act[t] = fmaxf(part[0][t] + part[1][t] + part[2][t] + part[3][t] + bp1[t], 0.f);
  __syncthreads();

  // L2: si += h @ Wp2 + bp2; act = relu(si)
  {
    float p = 0.f;
    for (int k = g*32; k < g*32 + 32; ++k) p = fmaf(act[k], Wp2[k*128 + c], p);
    part[g][c] = p;
  }
  __syncthreads();
  if (t < 128) {
    const float si = resid[t] + part[0][t] + part[1][t] + part[2][t] + part[3][t] + bp2[t];
    resid[t] = si;
    act[t] = fmaxf(si, 0.f);
  }
  __syncthreads();

  // L3: h = relu(act @ Wp3 + bp3)
  {
    float p = 0.f;
    for (int k = g*32; k < g*32 + 32; ++k) p = fmaf(act[k], Wp3[k*128 + c], p);
    part[g][c] = p;
  }
  __syncthreads();
  if (t < 128)
    act[t] = fmaxf(part[0][t] + part[1][t] + part[2][t] + part[3][t] + bp3[t], 0.f);
  __syncthreads();

  // L4: si += h @ Wp4 + bp4; rc = relu(si)
  {
    float p = 0.f;
    for (int k = g*32; k < g*32 + 32; ++k) p = fmaf(act[k], Wp4[k*128 + c], p);
    part[g][c] = p;
  }
  __syncthreads();
  if (t < 128)
    act[t] = fmaxf(resid[t] + part[0][t] + part[1][t] + part[2][t] + part[3][t] + bp4[t], 0.f);
  __syncthreads();

  // out: alpha = rc @ Wout + bout (20 outputs)
  if (t < 20) {
    float a = bout[t];
    for (int k = 0; k < 128; ++k) a = fmaf(act[k], Wout[k*20 + t], a);
    out[19200 + i*20 + t] = a;
  }
}

extern "C" void kernel_launch(void* const* d_in, const int* in_sizes, int n_in,
                              void* d_out, int out_size, void* d_ws, size_t ws_size,
                              hipStream_t stream)
{
  (void)in_sizes; (void)n_in; (void)out_size; (void)ws_size;
  const float* msa   = (const float*)d_in[0];
  const float* pair  = (const float*)d_in[1];
  const float* xyz   = (const float*)d_in[2];
  const float* state = (const float*)d_in[3];
  const int*   idx   = (const int*)d_in[4];
  const unsigned char* rmask = (const unsigned char*)d_in[5];
  const float* W_en = (const float*)d_in[6];
  const float* b_en = (const float*)d_in[7];
  const float* Wn1  = (const float*)d_in[8];
  const float* bn1  = (const float*)d_in[9];
  const float* Wn2  = (const float*)d_in[10];
  const float* bn2  = (const float*)d_in[11];
  const float* W_ee = (const float*)d_in[12];
  const float* b_ee = (const float*)d_in[13];
  const float* We1  = (const float*)d_in[14];
  const float* be1  = (const float*)d_in[15];
  const float* We2  = (const float*)d_in[16];
  const float* be2  = (const float*)d_in[17];
  const float* Wm1  = (const float*)d_in[18];
  const float* bm1  = (const float*)d_in[19];
  const float* Wm2  = (const float*)d_in[20];
  const float* bm2  = (const float*)d_in[21];
  const float* Wl0  = (const float*)d_in[22];
  const float* bl0  = (const float*)d_in[23];
  const float* Ws0  = (const float*)d_in[24];
  const float* bs0  = (const float*)d_in[25];
  const float* Wsi  = (const float*)d_in[26];
  const float* bsi  = (const float*)d_in[27];
  const float* Wp1  = (const float*)d_in[28];
  const float* bp1  = (const float*)d_in[29];
  const float* Wp2  = (const float*)d_in[30];
  const float* bp2  = (const float*)d_in[31];
  const float* Wp3  = (const float*)d_in[32];
  const float* bp3  = (const float*)d_in[33];
  const float* Wp4  = (const float*)d_in[34];
  const float* bp4  = (const float*)d_in[35];
  const float* Wout = (const float*)d_in[36];
  const float* bout = (const float*)d_in[37];

  float* wsf    = (float*)d_ws;
  float* seq_ln = wsf + WS_SEQ;
  float* nodev  = wsf + WS_NODE;
  int*   nbr    = (int*)(wsf + WS_NBR);
  float* soutf  = wsf + WS_SOUT;
  float* csee   = wsf + WS_CSEE;
  float* out = (float*)d_out;

  kernABP<<<2*LL + 1, 256, 0, stream>>>(msa, state, W_en, b_en, Wn1, bn1, Wn2, bn2,
                                        xyz, W_ee, seq_ln, nodev, nbr, csee);
  kernC<<<LL, 256, 0, stream>>>(pair, xyz, idx, rmask, W_ee, b_ee, csee,
                                We1, be1, We2, be2, Wm1, bm1, Wm2, bm2,
                                Wl0, bl0, nodev, nbr, soutf, out);
  kernD<<<LL, 512, 0, stream>>>(seq_ln, soutf, Ws0, bs0, Wsi, bsi, Wp1, bp1, Wp2, bp2,
                                Wp3, bp3, Wp4, bp4, Wout, bout, out);
}

// Round 14
// 104.058 us; speedup vs baseline: 1.6362x; 1.1617x over previous
//
#include <hip/hip_runtime.h>
#include <hip/hip_bf16.h>

#define LL 768
#define TOPK 128

// workspace layout (floats)
#define WS_SEQ  0                        // 768*256
#define WS_NODE (WS_SEQ + LL*256)        // 768*32
#define WS_NBR  (WS_NODE + LL*32)        // 768*128 ints
#define WS_SOUT (WS_NBR + LL*TOPK)       // 768*16
#define WS_CSEE (WS_SOUT + LL*16)        // 32
#define WS_PK   (WS_CSEE + 32)           // 22 frags x 256 dwords (packed bf16 weights)

typedef __attribute__((ext_vector_type(8))) short  bf16x8_t;
typedef __attribute__((ext_vector_type(4))) float  f32x4_t;
typedef __attribute__((ext_vector_type(4))) unsigned u32x4_t;

// bf16 pair pack/unpack (RNE)
__device__ __forceinline__ unsigned bfpack(float a, float b) {
  unsigned ua = __float_as_uint(a);
  ua = (ua + 0x7fffu + ((ua >> 16) & 1u)) >> 16;
  unsigned ub = __float_as_uint(b);
  ub = (ub + 0x7fffu + ((ub >> 16) & 1u)) & 0xffff0000u;
  return ua | ub;
}
__device__ __forceinline__ float bflo(unsigned v) { return __uint_as_float(v << 16); }
__device__ __forceinline__ float bfhi(unsigned v) { return __uint_as_float(v & 0xffff0000u); }

__device__ __forceinline__ float block_sum_256(float v, float* red, int t) {
#pragma unroll
  for (int o = 32; o > 0; o >>= 1) v += __shfl_xor(v, o, 64);
  __syncthreads();
  if ((t & 63) == 0) red[t >> 6] = v;
  __syncthreads();
  return red[0] + red[1] + red[2] + red[3];
}

// ---------------- Kernel ABP: A (0..767), B (768..1535), P (1536) ----------
__global__ __launch_bounds__(256) void kernABP(
    const float* __restrict__ msa, const float* __restrict__ state,
    const float* __restrict__ W_en, const float* __restrict__ b_en,
    const float* __restrict__ Wn1, const float* __restrict__ bn1,
    const float* __restrict__ Wn2, const float* __restrict__ bn2,
    const float* __restrict__ xyz, const float* __restrict__ W_ee,
    const float* __restrict__ We1, const float* __restrict__ We2,
    const float* __restrict__ Wm1, const float* __restrict__ Wm2,
    float* __restrict__ seq_ln, float* __restrict__ nodeo,
    int* __restrict__ nbr, float* __restrict__ colsum_ee,
    unsigned* __restrict__ pkws)
{
  const int bid = blockIdx.x, t = threadIdx.x;
  __shared__ float x[256];
  __shared__ float red[4];
  __shared__ float sn[16], n0[32], tn[32], hh[64], n1v[32];
  __shared__ float partA[8][33];
  __shared__ unsigned hist[256];
  __shared__ int selBin, below;
  __shared__ unsigned wcL[4], wcE[4];

  if (bid < LL) {
    // ================= A =================
    const int i = bid;
    float v = msa[i*256 + t];
    float mean = block_sum_256(v, red, t) * (1.f/256.f);
    float d = v - mean;
    float var = block_sum_256(d*d, red, t) * (1.f/256.f);
    float xn = d / sqrtf(var + 1e-5f);
    x[t] = xn;
    seq_ln[i*256 + t] = xn;

    if (t < 16) {
      float m2 = 0.f;
      for (int k = 0; k < 16; ++k) m2 += state[i*16 + k];
      m2 *= (1.f/16.f);
      float v2 = 0.f;
      for (int k = 0; k < 16; ++k) { float dd = state[i*16 + k] - m2; v2 += dd*dd; }
      v2 *= (1.f/16.f);
      sn[t] = (state[i*16 + t] - m2) / sqrtf(v2 + 1e-5f);
    }
    __syncthreads();

    {
      const int g = t >> 5, c = t & 31;
      float p = 0.f;
      for (int k = g*32; k < g*32 + 32; ++k) p = fmaf(x[k], W_en[k*32 + c], p);
      if (g == 7)
        for (int k = 0; k < 16; ++k) p = fmaf(sn[k], W_en[(256+k)*32 + c], p);
      partA[g][c] = p;
    }
    __syncthreads();
    if (t < 32) {
      float a = b_en[t];
#pragma unroll
      for (int g = 0; g < 8; ++g) a += partA[g][t];
      n0[t] = a;
    }
    __syncthreads();
    if (t < 32) {
      float m = 0.f;
      for (int k = 0; k < 32; ++k) m += n0[k];
      m *= (1.f/32.f);
      float vv = 0.f;
      for (int k = 0; k < 32; ++k) { float dd = n0[k] - m; vv += dd*dd; }
      vv *= (1.f/32.f);
      tn[t] = (n0[t] - m) / sqrtf(vv + 1e-5f);
    }
    __syncthreads();
    if (t < 64) {
      float a = bn1[t];
      for (int k = 0; k < 32; ++k) a = fmaf(tn[k], Wn1[k*64 + t], a);
      hh[t] = fmaxf(a, 0.f);
    }
    __syncthreads();
    if (t < 32) {
      float a = n0[t] + bn2[t];
      for (int k = 0; k < 64; ++k) a = fmaf(hh[k], Wn2[k*32 + t], a);
      n1v[t] = a;
    }
    __syncthreads();
    if (t < 32) {
      float m = 0.f;
      for (int k = 0; k < 32; ++k) m += n1v[k];
      m *= (1.f/32.f);
      float vv = 0.f;
      for (int k = 0; k < 32; ++k) { float dd = n1v[k] - m; vv += dd*dd; }
      vv *= (1.f/32.f);
      nodeo[i*32 + t] = (n1v[t] - m) / sqrtf(vv + 1e-5f);
    }
    return;
  }

  if (bid < 2*LL) {
    // ================= B: radix select =================
    const int i = bid - LL;
    const int lane = t & 63, wv = t >> 6;

    const float cix = xyz[i*9+3], ciy = xyz[i*9+4], ciz = xyz[i*9+5];
    unsigned key[3];
#pragma unroll
    for (int r = 0; r < 3; ++r) {
      const int j = r*256 + t;
      float dx = __fadd_rn(cix, -xyz[j*9+3]);
      float dy = __fadd_rn(ciy, -xyz[j*9+4]);
      float dz = __fadd_rn(ciz, -xyz[j*9+5]);
      float Dv = sqrtf(__fadd_rn(__fadd_rn(__fadd_rn(__fmul_rn(dx,dx),
                         __fmul_rn(dy,dy)), __fmul_rn(dz,dz)), 1e-8f));
      key[r] = __float_as_uint(Dv);
    }

    unsigned prefix = 0;
    int rank = 127, cntLess = 0;
#pragma unroll
    for (int pass = 0; pass < 4; ++pass) {
      const int shift = 24 - pass*8;
      const unsigned hiMask = (pass == 0) ? 0u : (0xFFFFFFFFu << (shift + 8));
      hist[t] = 0;
      __syncthreads();
#pragma unroll
      for (int r = 0; r < 3; ++r)
        if ((key[r] & hiMask) == (prefix & hiMask))
          atomicAdd(&hist[(key[r] >> shift) & 0xffu], 1u);
      __syncthreads();
      if (t < 64) {
        unsigned s0 = hist[t*4], s1 = hist[t*4+1], s2 = hist[t*4+2], s3 = hist[t*4+3];
        int tot = (int)(s0 + s1 + s2 + s3);
        int inc = tot;
#pragma unroll
        for (int o = 1; o < 64; o <<= 1) {
          int v = __shfl_up(inc, o);
          if (t >= o) inc += v;
        }
        int excl = inc - tot;
        if (rank >= excl && rank < inc) {
          int c = excl, bsel = t*4;
          if (rank >= c + (int)s0) { c += (int)s0; bsel = t*4+1;
            if (rank >= c + (int)s1) { c += (int)s1; bsel = t*4+2;
              if (rank >= c + (int)s2) { c += (int)s2; bsel = t*4+3; } } }
          selBin = bsel; below = c;
        }
      }
      __syncthreads();
      prefix |= ((unsigned)selBin) << shift;
      rank -= below;
      cntLess += below;
      __syncthreads();
    }
    const unsigned thr = prefix;

    const unsigned long long lmask = (1ull << lane) - 1ull;
    unsigned baseLt = 0, baseEq = (unsigned)cntLess;
#pragma unroll
    for (int r = 0; r < 3; ++r) {
      const int j = r*256 + t;
      const bool pl = key[r] < thr;
      const bool pe = key[r] == thr;
      unsigned long long balL = __ballot(pl);
      unsigned long long balE = __ballot(pe);
      unsigned preL = (unsigned)__popcll(balL & lmask);
      unsigned preE = (unsigned)__popcll(balE & lmask);
      if (lane == 0) { wcL[wv] = (unsigned)__popcll(balL); wcE[wv] = (unsigned)__popcll(balE); }
      __syncthreads();
      unsigned wbL = 0, wbE = 0, totL = 0, totE = 0;
#pragma unroll
      for (int w = 0; w < 4; ++w) {
        if (w < wv) { wbL += wcL[w]; wbE += wcE[w]; }
        totL += wcL[w]; totE += wcE[w];
      }
      if (pl) nbr[i*TOPK + baseLt + wbL + preL] = j;
      if (pe) {
        unsigned pos = baseEq + wbE + preE;
        if (pos < TOPK) nbr[i*TOPK + pos] = j;
      }
      baseLt += totL; baseEq += totE;
      __syncthreads();
    }
    return;
  }

  // ================= P: colsum + MFMA B-fragment weight packing ============
  {
    const int c = t & 31, sg = t >> 5;
    float s = 0.f;
    for (int k = sg*16; k < sg*16 + 16; ++k) s += W_ee[k*32 + c];
    partA[sg][c] = s;
    __syncthreads();
    if (t < 32) {
      float tot = 0.f;
#pragma unroll
      for (int g = 0; g < 8; ++g) tot += partA[g][t];
      colsum_ee[t] = tot;
    }

    // 22 B-frags: lane l holds W[kb+(l>>4)*8 + 2d .. +2d+1][ct*16 + (l&15)]
    const int lane6 = t & 63;
    for (int f = t >> 6; f < 22; f += 4) {
      const float* W; int N, krow0, ct;
      if (f < 4)       { W = We1; N = 64; krow0 = 0;             ct = f;        }
      else if (f < 8)  { W = We2; N = 32; krow0 = ((f-4)>>1)*32; ct = (f-4)&1;  }
      else if (f < 12) { W = Wm1; N = 64; krow0 = 32;            ct = f-8;      }
      else if (f < 16) { W = Wm1; N = 64; krow0 = 64;            ct = f-12;     }
      else             { W = Wm2; N = 40; krow0 = ((f-16)/3)*32; ct = (f-16)%3; }
      const int cc = ct*16 + (lane6 & 15);
      const int kb = krow0 + ((lane6 >> 4) << 3);
#pragma unroll
      for (int d = 0; d < 4; ++d) {
        const int k = kb + 2*d;
        const float lo = (cc < N) ? W[k*N + cc]     : 0.f;
        const float hi = (cc < N) ? W[(k+1)*N + cc] : 0.f;
        pkws[f*256 + lane6*4 + d] = bfpack(lo, hi);
      }
    }
  }
}

// ---------------- Kernel C (FUSED C1 + MFMA MLP), 4 blocks/CU ---------------
__global__ __launch_bounds__(256, 4) void kernC(
    const float* __restrict__ pair, const float* __restrict__ xyz,
    const int* __restrict__ idx, const unsigned char* __restrict__ rmask,
    const float* __restrict__ W_ee, const float* __restrict__ b_ee,
    const float* __restrict__ colsum_ee,
    const float* __restrict__ be1, const float* __restrict__ be2,
    const float* __restrict__ Wm1, const float* __restrict__ bm1,
    const float* __restrict__ bm2,
    const float* __restrict__ Wl0, const float* __restrict__ bl0,
    const float* __restrict__ node, const int* __restrict__ nbr,
    const unsigned* __restrict__ pkws,
    float* __restrict__ soutf, float* __restrict__ out)
{
  const int i = blockIdx.x, t = threadIdx.x;
  const int lane = t & 63;
  const int wv = __builtin_amdgcn_readfirstlane(t >> 6);   // uniform 0..3
  __shared__ unsigned Ab[128][17];     // e0 -> ed -> e2 -> ed2 (bf16 pairs)
  __shared__ unsigned U[128*33];       // pairB[64][65] then Bb[128][33]
  __shared__ unsigned nd[128][17];     // node rows (bf16 pairs)
  __shared__ int   jl[128];
  __shared__ float Dvv[128], xsepv[128];
  __shared__ float relv[128][3];
  __shared__ float ni[32];
  __shared__ float pmv[64], prsv[64];
  __shared__ float mA[128], sgA[128];
  __shared__ float P2[4][44];
  __shared__ float fin[44];

  // ---- phase 0: stage ni, nd, jl, relv, Dv, xsep ----
  if (t < 32) ni[t] = node[i*32 + t];
  {
    const int pp = t >> 1, hh2 = t & 1;
    const int jj = nbr[i*TOPK + pp];
    const float4* nr = (const float4*)(node + jj*32 + hh2*16);
    float4 a0 = nr[0], a1 = nr[1], a2 = nr[2], a3 = nr[3];
    unsigned* dst = &nd[pp][hh2*8];
    dst[0] = bfpack(a0.x, a0.y); dst[1] = bfpack(a0.z, a0.w);
    dst[2] = bfpack(a1.x, a1.y); dst[3] = bfpack(a1.z, a1.w);
    dst[4] = bfpack(a2.x, a2.y); dst[5] = bfpack(a2.z, a2.w);
    dst[6] = bfpack(a3.x, a3.y); dst[7] = bfpack(a3.z, a3.w);
    if (hh2 == 0) {
      jl[pp] = jj;
      const float cix = xyz[i*9+3], ciy = xyz[i*9+4], ciz = xyz[i*9+5];
      const float cjx = xyz[jj*9+3], cjy = xyz[jj*9+4], cjz = xyz[jj*9+5];
      relv[pp][0] = cjx - cix;
      relv[pp][1] = cjy - ciy;
      relv[pp][2] = cjz - ciz;
      const float dx = __fadd_rn(cix, -cjx), dy = __fadd_rn(ciy, -cjy),
                  dz = __fadd_rn(ciz, -cjz);
      Dvv[pp] = sqrtf(__fadd_rn(__fadd_rn(__fadd_rn(__fmul_rn(dx,dx),
                        __fmul_rn(dy,dy)), __fmul_rn(dz,dz)), 1e-8f));
      const float offv = (float)(idx[jj] - idx[i]);
      const float sg = (offv > 0.f) ? 1.f : ((offv < 0.f) ? -1.f : 0.f);
      xsepv[pp] = sg * logf(fabsf(offv) + 1.f);
    }
  }
  __syncthreads();

  // ---- phase C1: edge0 into Ab, two 64-edge sub-passes (f32 weights) ----
  unsigned (*pairB)[65] = (unsigned (*)[65])U;
  for (int sub = 0; sub < 2; ++sub) {
    {
      const int r = t >> 2, qq = t & 3;
      const float* prow = pair + ((size_t)i*LL + jl[sub*64 + r])*128 + qq*32;
      float s = 0.f, ss = 0.f;
#pragma unroll
      for (int n = 0; n < 8; ++n) {
        float4 v = ((const float4*)prow)[n];
        s  += (v.x + v.y) + (v.z + v.w);
        ss += v.x*v.x + v.y*v.y + v.z*v.z + v.w*v.w;
        pairB[r][qq*16 + n*2]     = bfpack(v.x, v.y);
        pairB[r][qq*16 + n*2 + 1] = bfpack(v.z, v.w);
      }
      s  += __shfl_xor(s, 1);  s  += __shfl_xor(s, 2);
      ss += __shfl_xor(ss, 1); ss += __shfl_xor(ss, 2);
      if (qq == 0) {
        const float pm = s * (1.f/128.f);
        const float pv = ss * (1.f/128.f) - pm*pm;
        pmv[r] = pm; prsv[r] = 1.f / sqrtf(pv + 1e-5f);
      }
    }
    __syncthreads();
    {
      const int el = lane;
      const int e = sub*64 + el;
      float acc[8], acc2[8];
#pragma unroll
      for (int c = 0; c < 8; ++c) { acc[c] = 0.f; acc2[c] = 0.f; }
#pragma unroll 4
      for (int kk = 0; kk < 64; ++kk) {
        const unsigned v = pairB[el][kk];
        const float al = bflo(v), ah = bfhi(v);
        const float* w0 = W_ee + (2*kk)*32   + 8*wv;
        const float* w1 = W_ee + (2*kk+1)*32 + 8*wv;
#pragma unroll
        for (int c = 0; c < 8; ++c)
          acc[c] = fmaf(al, w0[c], fmaf(ah, w1[c], acc[c]));
      }
      const float Dv = Dvv[e];
#pragma unroll 4
      for (int k = 0; k < 64; ++k) {
        const float mu = 2.f + (float)k * (20.f/63.f);
        const float u  = (Dv - mu) / 0.3125f;
        const float w  = expf(-(u*u));
        const float* wr = W_ee + (128+k)*32 + 8*wv;
#pragma unroll
        for (int c = 0; c < 8; ++c) acc2[c] = fmaf(w, wr[c], acc2[c]);
      }
      const float pm = pmv[el], prs = prsv[el];
      const float corr = -prs * pm;
      const float xs = xsepv[e];
      float val[8];
#pragma unroll
      for (int c = 0; c < 8; ++c) {
        const int ch = 8*wv + c;
        val[c] = fmaf(prs, acc[c],
                   fmaf(corr, colsum_ee[ch],
                     fmaf(xs, W_ee[192*32 + ch], b_ee[ch] + acc2[c])));
      }
#pragma unroll
      for (int n = 0; n < 4; ++n)
        Ab[e][4*wv + n] = bfpack(val[2*n], val[2*n+1]);
    }
    __syncthreads();
  }

  // ---- MFMA MLP chain: wave wv owns edges [32wv, 32wv+32); NO barriers ----
  unsigned (*Bb)[33] = (unsigned (*)[33])U;
  {
    const int e0b = 32 * wv;
    const int row = lane & 15;    // A M-row / D N-col
    const int kg  = lane >> 4;    // k-group
    const int r0  = kg * 4;       // D M-row base
    const f32x4_t fz = {0.f, 0.f, 0.f, 0.f};

    // LN(Ab) per-wave (2 lanes/edge), keep mean/sigma
    {
      const int eL = e0b + (lane & 31);
      const int hf = lane >> 5;
      float av[16];
#pragma unroll
      for (int kk = 0; kk < 8; ++kk) {
        const unsigned v = Ab[eL][hf*8 + kk];
        av[2*kk] = bflo(v); av[2*kk+1] = bfhi(v);
      }
      float s = 0.f;
#pragma unroll
      for (int c = 0; c < 16; ++c) s += av[c];
      s += __shfl_xor(s, 32);
      const float mm = s * (1.f/32.f);
      float vv = 0.f;
#pragma unroll
      for (int c = 0; c < 16; ++c) { const float dd = av[c] - mm; vv += dd*dd; }
      vv += __shfl_xor(vv, 32);
      vv *= (1.f/32.f);
      const float sg = sqrtf(vv + 1e-5f);
      const float rs = 1.f / sg;
#pragma unroll
      for (int kk = 0; kk < 8; ++kk)
        Ab[eL][hf*8 + kk] = bfpack((av[2*kk]-mm)*rs, (av[2*kk+1]-mm)*rs);
      if (hf == 0) { mA[eL] = mm; sgA[eL] = sg; }
    }

    // ---- h = relu(ed @ We1 + be1): MFMA, K=32, N=64 ----
    {
      f32x4_t acc[2][4];
#pragma unroll
      for (int m = 0; m < 2; ++m) {
        u32x4_t av4;
        const unsigned* rp = &Ab[e0b + 16*m + row][0];
        av4.x = rp[kg*4]; av4.y = rp[kg*4+1]; av4.z = rp[kg*4+2]; av4.w = rp[kg*4+3];
        const bf16x8_t af = __builtin_bit_cast(bf16x8_t, av4);
#pragma unroll
        for (int ct = 0; ct < 4; ++ct) {
          const u32x4_t bv = ((const u32x4_t*)(pkws + (0 + ct)*256))[lane];
          acc[m][ct] = __builtin_amdgcn_mfma_f32_16x16x32_bf16(
              af, __builtin_bit_cast(bf16x8_t, bv), fz, 0, 0, 0);
        }
      }
#pragma unroll
      for (int m = 0; m < 2; ++m)
#pragma unroll
        for (int ct = 0; ct < 4; ++ct) {
          const int ch = ct*16 + row;
#pragma unroll
          for (int j = 0; j < 4; ++j) {
            float v = fmaxf(acc[m][ct][j] + be1[ch], 0.f);
            const float p = __shfl_xor(v, 1);
            if (!(lane & 1))
              Bb[e0b + 16*m + r0 + j][ct*8 + (row >> 1)] = bfpack(v, p);
          }
        }
    }

    // ---- e2 = e0raw + h @ We2 + be2: MFMA, K=64, N=32 ----
    {
      f32x4_t acc[2][2];
#pragma unroll
      for (int m = 0; m < 2; ++m)
#pragma unroll
        for (int ct = 0; ct < 2; ++ct) acc[m][ct] = fz;
#pragma unroll
      for (int m = 0; m < 2; ++m)
#pragma unroll
        for (int ks = 0; ks < 2; ++ks) {
          u32x4_t av4;
          const unsigned* rp = &Bb[e0b + 16*m + row][0];
          const int kd = ks*16 + kg*4;
          av4.x = rp[kd]; av4.y = rp[kd+1]; av4.z = rp[kd+2]; av4.w = rp[kd+3];
          const bf16x8_t af = __builtin_bit_cast(bf16x8_t, av4);
#pragma unroll
          for (int ct = 0; ct < 2; ++ct) {
            const u32x4_t bv = ((const u32x4_t*)(pkws + (4 + ks*2 + ct)*256))[lane];
            acc[m][ct] = __builtin_amdgcn_mfma_f32_16x16x32_bf16(
                af, __builtin_bit_cast(bf16x8_t, bv), acc[m][ct], 0, 0, 0);
          }
        }
#pragma unroll
      for (int m = 0; m < 2; ++m)
#pragma unroll
        for (int ct = 0; ct < 2; ++ct) {
          const int ch = ct*16 + row;
          const int dw = ct*8 + (row >> 1);
#pragma unroll
          for (int j = 0; j < 4; ++j) {
            const int e = e0b + 16*m + r0 + j;
            const unsigned old = Ab[e][dw];
            const float e0v = (lane & 1) ? bfhi(old) : bflo(old);
            float v = acc[m][ct][j] + fmaf(e0v, sgA[e], mA[e]) + be2[ch];
            const float p = __shfl_xor(v, 1);
            if (!(lane & 1)) Ab[e][dw] = bfpack(v, p);
          }
        }
    }

    // LN(e2) per-wave
    {
      const int eL = e0b + (lane & 31);
      const int hf = lane >> 5;
      float av[16];
#pragma unroll
      for (int kk = 0; kk < 8; ++kk) {
        const unsigned v = Ab[eL][hf*8 + kk];
        av[2*kk] = bflo(v); av[2*kk+1] = bfhi(v);
      }
      float s = 0.f;
#pragma unroll
      for (int c = 0; c < 16; ++c) s += av[c];
      s += __shfl_xor(s, 32);
      const float mm = s * (1.f/32.f);
      float vv = 0.f;
#pragma unroll
      for (int c = 0; c < 16; ++c) { const float dd = av[c] - mm; vv += dd*dd; }
      vv += __shfl_xor(vv, 32);
      vv *= (1.f/32.f);
      const float rs = 1.f / sqrtf(vv + 1e-5f);
#pragma unroll
      for (int kk = 0; kk < 8; ++kk)
        Ab[eL][hf*8 + kk] = bfpack((av[2*kk]-mm)*rs, (av[2*kk+1]-mm)*rs);
    }

    // ---- m1 = relu(ni-part + nd@Wm1[32:64] + ed2@Wm1[64:96] + bm1) ----
    {
      float tmpni = bm1[lane];   // lane = channel 0..63
      for (int k = 0; k < 32; ++k) tmpni = fmaf(ni[k], Wm1[k*64 + lane], tmpni);
      f32x4_t acc[2][4];
#pragma unroll
      for (int m = 0; m < 2; ++m)
#pragma unroll
        for (int ct = 0; ct < 4; ++ct) acc[m][ct] = fz;
#pragma unroll
      for (int m = 0; m < 2; ++m) {
        u32x4_t aN, aE;
        const unsigned* rn = &nd[e0b + 16*m + row][0];
        aN.x = rn[kg*4]; aN.y = rn[kg*4+1]; aN.z = rn[kg*4+2]; aN.w = rn[kg*4+3];
        const unsigned* ra = &Ab[e0b + 16*m + row][0];
        aE.x = ra[kg*4]; aE.y = ra[kg*4+1]; aE.z = ra[kg*4+2]; aE.w = ra[kg*4+3];
        const bf16x8_t afN = __builtin_bit_cast(bf16x8_t, aN);
        const bf16x8_t afE = __builtin_bit_cast(bf16x8_t, aE);
#pragma unroll
        for (int ct = 0; ct < 4; ++ct) {
          const u32x4_t bN = ((const u32x4_t*)(pkws + (8 + ct)*256))[lane];
          const u32x4_t bE = ((const u32x4_t*)(pkws + (12 + ct)*256))[lane];
          acc[m][ct] = __builtin_amdgcn_mfma_f32_16x16x32_bf16(
              afN, __builtin_bit_cast(bf16x8_t, bN), acc[m][ct], 0, 0, 0);
          acc[m][ct] = __builtin_amdgcn_mfma_f32_16x16x32_bf16(
              afE, __builtin_bit_cast(bf16x8_t, bE), acc[m][ct], 0, 0, 0);
        }
      }
#pragma unroll
      for (int m = 0; m < 2; ++m)
#pragma unroll
        for (int ct = 0; ct < 4; ++ct) {
          const int ch = ct*16 + row;
          const float tb = __shfl(tmpni, ch);
#pragma unroll
          for (int j = 0; j < 4; ++j) {
            float v = fmaxf(acc[m][ct][j] + tb, 0.f);
            const float p = __shfl_xor(v, 1);
            if (!(lane & 1))
              Bb[e0b + 16*m + r0 + j][ct*8 + (row >> 1)] = bfpack(v, p);
          }
        }
    }

    // ---- m2: MFMA K=64, N=48 (40 valid) + expand + reduce ----
    {
      f32x4_t acc[2][3];
#pragma unroll
      for (int m = 0; m < 2; ++m)
#pragma unroll
        for (int ct = 0; ct < 3; ++ct) acc[m][ct] = fz;
#pragma unroll
      for (int m = 0; m < 2; ++m)
#pragma unroll
        for (int ks = 0; ks < 2; ++ks) {
          u32x4_t av4;
          const unsigned* rp = &Bb[e0b + 16*m + row][0];
          const int kd = ks*16 + kg*4;
          av4.x = rp[kd]; av4.y = rp[kd+1]; av4.z = rp[kd+2]; av4.w = rp[kd+3];
          const bf16x8_t af = __builtin_bit_cast(bf16x8_t, av4);
#pragma unroll
          for (int ct = 0; ct < 3; ++ct) {
            const u32x4_t bv = ((const u32x4_t*)(pkws + (16 + ks*3 + ct)*256))[lane];
            acc[m][ct] = __builtin_amdgcn_mfma_f32_16x16x32_bf16(
                af, __builtin_bit_cast(bf16x8_t, bv), acc[m][ct], 0, 0, 0);
          }
        }
      float plain[3] = {0.f, 0.f, 0.f};
      float rel3[3]  = {0.f, 0.f, 0.f};
#pragma unroll
      for (int m = 0; m < 2; ++m)
#pragma unroll
        for (int ct = 0; ct < 3; ++ct) {
          const int o = ct*16 + row;
          if (ct == 2 && row >= 8) continue;   // o >= 40
#pragma unroll
          for (int j = 0; j < 4; ++j) {
            const int e = e0b + 16*m + r0 + j;
            const float v = acc[m][ct][j] + bm2[o];
            if (ct == 2 && row < 2) {
              rel3[0] = fmaf(v, relv[e][0], rel3[0]);
              rel3[1] = fmaf(v, relv[e][1], rel3[1]);
              rel3[2] = fmaf(v, relv[e][2], rel3[2]);
            } else {
              plain[ct] += v;
            }
          }
        }
#pragma unroll
      for (int d = 0; d < 3; ++d) {
        plain[d] += __shfl_xor(plain[d], 16); plain[d] += __shfl_xor(plain[d], 32);
        rel3[d]  += __shfl_xor(rel3[d], 16);  rel3[d]  += __shfl_xor(rel3[d], 32);
      }
      if (lane < 16) {
        P2[wv][lane]      = plain[0];
        P2[wv][16 + lane] = plain[1];
        if (lane < 2) {
#pragma unroll
          for (int d = 0; d < 3; ++d) P2[wv][32 + lane*3 + d] = rel3[d];
        } else if (lane < 8) {
          P2[wv][38 + lane - 2] = plain[2];
        }
      }
    }
  }
  __syncthreads();
  if (t < 44) fin[t] = P2[0][t] + P2[1][t] + P2[2][t] + P2[3][t];
  __syncthreads();

  if (t < 16) {  // state_out = [node_i, m_l0] @ Wl0 + bl0
    float a = bl0[t];
#pragma unroll
    for (int k = 0; k < 32; ++k) a = fmaf(ni[k], Wl0[k*16 + t], a);
#pragma unroll
    for (int k = 0; k < 32; ++k) a = fmaf(fin[k] * (1.f/128.f), Wl0[(32+k)*16 + t], a);
    soutf[i*16 + t] = a;
    out[LL*9 + i*16 + t] = a;
  }
  if (t == 0) {  // frame update
    float ve[6], wa[6];
#pragma unroll
    for (int qq = 0; qq < 6; ++qq) ve[qq] = fin[32 + qq] * (1.f/128.f);
#pragma unroll
    for (int qq = 0; qq < 6; ++qq) wa[qq] = fin[38 + qq] * (1.f/128.f);
    float l1[9];
#pragma unroll
    for (int a = 0; a < 3; ++a)
#pragma unroll
      for (int d = 0; d < 3; ++d) l1[a*3 + d] = xyz[i*9 + a*3 + d] - xyz[i*9 + 3 + d];
    float T[3], Rv[3];
#pragma unroll
    for (int d = 0; d < 3; ++d) {
      float va0 = wa[0]*l1[d] + wa[1]*l1[3 + d] + wa[2]*l1[6 + d];
      float va1 = wa[3]*l1[d] + wa[4]*l1[3 + d] + wa[5]*l1[6 + d];
      T[d]  = (ve[d] + va0) / 10.f;
      Rv[d] = (ve[3 + d] + va1) / 100.f;
    }
    float qn = sqrtf(1.f + Rv[0]*Rv[0] + Rv[1]*Rv[1] + Rv[2]*Rv[2]);
    float qA = 1.f/qn, qB = Rv[0]/qn, qC = Rv[1]/qn, qD = Rv[2]/qn;
    float Rm[9];
    Rm[0] = qA*qA + qB*qB - qC*qC - qD*qD;
    Rm[1] = 2.f*qB*qC - 2.f*qA*qD;
    Rm[2] = 2.f*qB*qD + 2.f*qA*qC;
    Rm[3] = 2.f*qB*qC + 2.f*qA*qD;
    Rm[4] = qA*qA - qB*qB + qC*qC - qD*qD;
    Rm[5] = 2.f*qC*qD - 2.f*qA*qB;
    Rm[6] = 2.f*qB*qD - 2.f*qA*qC;
    Rm[7] = 2.f*qC*qD + 2.f*qA*qB;
    Rm[8] = qA*qA - qB*qB - qC*qC + qD*qD;
    if (rmask[i]) {
      Rm[0] = 1.f; Rm[1] = 0.f; Rm[2] = 0.f;
      Rm[3] = 0.f; Rm[4] = 1.f; Rm[5] = 0.f;
      Rm[6] = 0.f; Rm[7] = 0.f; Rm[8] = 1.f;
    }
#pragma unroll
    for (int a = 0; a < 3; ++a)
#pragma unroll
      for (int di = 0; di < 3; ++di) {
        float xn = Rm[di*3+0]*l1[a*3+0] + Rm[di*3+1]*l1[a*3+1] + Rm[di*3+2]*l1[a*3+2]
                 + xyz[i*9 + 3 + di] + T[di];
        out[i*9 + a*3 + di] = xn;
      }
  }
}

// ---------------- Kernel D: si MLP stack -> alpha (512 thr, 4-way k-split) --
__global__ __launch_bounds__(512) void kernD(
    const float* __restrict__ seq_ln, const float* __restrict__ st_out,
    const float* __restrict__ Ws0, const float* __restrict__ bs0,
    const float* __restrict__ Wsi, const float* __restrict__ bsi,
    const float* __restrict__ Wp1, const float* __restrict__ bp1,
    const float* __restrict__ Wp2, const float* __restrict__ bp2,
    const float* __restrict__ Wp3, const float* __restrict__ bp3,
    const float* __restrict__ Wp4, const float* __restrict__ bp4,
    const float* __restrict__ Wout, const float* __restrict__ bout,
    float* __restrict__ out)
{
  const int i = blockIdx.x, t = threadIdx.x;
  const int c = t & 127, g = t >> 7;
  __shared__ float x0[256], stn[16], act[128], resid[128], part[4][129];

  if (t < 256) x0[t] = seq_ln[i*256 + t];
  if (t < 16) {
    float m = 0.f;
    for (int k = 0; k < 16; ++k) m += st_out[i*16 + k];
    m *= (1.f/16.f);
    float v = 0.f;
    for (int k = 0; k < 16; ++k) { float dd = st_out[i*16 + k] - m; v += dd*dd; }
    v *= (1.f/16.f);
    stn[t] = (st_out[i*16 + t] - m) / sqrtf(v + 1e-5f);
  }
  __syncthreads();

  {
    float p = 0.f;
    for (int k = g*64; k < g*64 + 64; ++k) p = fmaf(x0[k], Ws0[k*128 + c], p);
    if (g == 0)
      for (int k = 0; k < 16; ++k) p = fmaf(stn[k], Wsi[k*128 + c], p);
    part[g][c] = p;
  }
  __syncthreads();
  if (t < 128) {
    const float si = part[0][t] + part[1][t] + part[2][t] + part[3][t]
                   + bs0[t] + bsi[t];
    resid[t] = si;
    act[t] = fmaxf(si, 0.f);
  }
  __syncthreads();

  {
    float p = 0.f;
    for (int k = g*32; k < g*32 + 32; ++k) p = fmaf(act[k], Wp1[k*128 + c], p);
    part[g][c] = p;
  }
  __syncthreads();
  if (t < 128)
    act[t] = fmaxf(part[0][t] + part[1][t] + part[2][t] + part[3][t] + bp1[t], 0.f);
  __syncthreads();

  {
    float p = 0.f;
    for (int k = g*32; k < g*32 + 32; ++k) p = fmaf(act[k], Wp2[k*128 + c], p);
    part[g][c] = p;
  }
  __syncthreads();
  if (t < 128) {
    const float si = resid[t] + part[0][t] + part[1][t] + part[2][t] + part[3][t] + bp2[t];
    resid[t] = si;
    act[t] = fmaxf(si, 0.f);
  }
  __syncthreads();

  {
    float p = 0.f;
    for (int k = g*32; k < g*32 + 32; ++k) p = fmaf(act[k], Wp3[k*128 + c], p);
    part[g][c] = p;
  }
  __syncthreads();
  if (t < 128)
    act[t] = fmaxf(part[0][t] + part[1][t] + part[2][t] + part[3][t] + bp3[t], 0.f);
  __syncthreads();

  {
    float p = 0.f;
    for (int k = g*32; k < g*32 + 32; ++k) p = fmaf(act[k], Wp4[k*128 + c], p);
    part[g][c] = p;
  }
  __syncthreads();
  if (t < 128)
    act[t] = fmaxf(resid[t] + part[0][t] + part[1][t] + part[2][t] + part[3][t] + bp4[t], 0.f);
  __syncthreads();

  if (t < 20) {
    float a = bout[t];
    for (int k = 0; k < 128; ++k) a = fmaf(act[k], Wout[k*20 + t], a);
    out[19200 + i*20 + t] = a;
  }
}

extern "C" void kernel_launch(void* const* d_in, const int* in_sizes, int n_in,
                              void* d_out, int out_size, void* d_ws, size_t ws_size,
                              hipStream_t stream)
{
  (void)in_sizes; (void)n_in; (void)out_size; (void)ws_size;
  const float* msa   = (const float*)d_in[0];
  const float* pair  = (const float*)d_in[1];
  const float* xyz   = (const float*)d_in[2];
  const float* state = (const float*)d_in[3];
  const int*   idx   = (const int*)d_in[4];
  const unsigned char* rmask = (const unsigned char*)d_in[5];
  const float* W_en = (const float*)d_in[6];
  const float* b_en = (const float*)d_in[7];
  const float* Wn1  = (const float*)d_in[8];
  const float* bn1  = (const float*)d_in[9];
  const float* Wn2  = (const float*)d_in[10];
  const float* bn2  = (const float*)d_in[11];
  const float* W_ee = (const float*)d_in[12];
  const float* b_ee = (const float*)d_in[13];
  const float* We1  = (const float*)d_in[14];
  const float* be1  = (const float*)d_in[15];
  const float* We2  = (const float*)d_in[16];
  const float* be2  = (const float*)d_in[17];
  const float* Wm1  = (const float*)d_in[18];
  const float* bm1  = (const float*)d_in[19];
  const float* Wm2  = (const float*)d_in[20];
  const float* bm2  = (const float*)d_in[21];
  const float* Wl0  = (const float*)d_in[22];
  const float* bl0  = (const float*)d_in[23];
  const float* Ws0  = (const float*)d_in[24];
  const float* bs0  = (const float*)d_in[25];
  const float* Wsi  = (const float*)d_in[26];
  const float* bsi  = (const float*)d_in[27];
  const float* Wp1  = (const float*)d_in[28];
  const float* bp1  = (const float*)d_in[29];
  const float* Wp2  = (const float*)d_in[30];
  const float* bp2  = (const float*)d_in[31];
  const float* Wp3  = (const float*)d_in[32];
  const float* bp3  = (const float*)d_in[33];
  const float* Wp4  = (const float*)d_in[34];
  const float* bp4  = (const float*)d_in[35];
  const float* Wout = (const float*)d_in[36];
  const float* bout = (const float*)d_in[37];

  float* wsf    = (float*)d_ws;
  float* seq_ln = wsf + WS_SEQ;
  float* nodev  = wsf + WS_NODE;
  int*   nbr    = (int*)(wsf + WS_NBR);
  float* soutf  = wsf + WS_SOUT;
  float* csee   = wsf + WS_CSEE;
  unsigned* pkws = (unsigned*)(wsf + WS_PK);
  float* out = (float*)d_out;

  kernABP<<<2*LL + 1, 256, 0, stream>>>(msa, state, W_en, b_en, Wn1, bn1, Wn2, bn2,
                                        xyz, W_ee, We1, We2, Wm1, Wm2,
                                        seq_ln, nodev, nbr, csee, pkws);
  kernC<<<LL, 256, 0, stream>>>(pair, xyz, idx, rmask, W_ee, b_ee, csee,
                                be1, be2, Wm1, bm1, bm2,
                                Wl0, bl0, nodev, nbr, pkws, soutf, out);
  kernD<<<LL, 512, 0, stream>>>(seq_ln, soutf, Ws0, bs0, Wsi, bsi, Wp1, bp1, Wp2, bp2,
                                Wp3, bp3, Wp4, bp4, Wout, bout, out);
}

// Round 15
// 81.726 us; speedup vs baseline: 2.0833x; 1.2733x over previous
//
#include <hip/hip_runtime.h>
#include <hip/hip_bf16.h>

#define LL 768
#define TOPK 128

// workspace layout (floats)
#define WS_SEQ  0                        // 768*256
#define WS_NODE (WS_SEQ + LL*256)        // 768*32
#define WS_NBR  (WS_NODE + LL*32)        // 768*128 ints
#define WS_SOUT (WS_NBR + LL*TOPK)       // 768*16
#define WS_CSEE (WS_SOUT + LL*16)        // 32
#define WS_PK   (WS_CSEE + 32)           // 34 frags x 256 dwords (packed bf16 weights)

typedef __attribute__((ext_vector_type(8))) short  bf16x8_t;
typedef __attribute__((ext_vector_type(4))) float  f32x4_t;
typedef __attribute__((ext_vector_type(4))) unsigned u32x4_t;

// bf16 pair pack/unpack (RNE)
__device__ __forceinline__ unsigned bfpack(float a, float b) {
  unsigned ua = __float_as_uint(a);
  ua = (ua + 0x7fffu + ((ua >> 16) & 1u)) >> 16;
  unsigned ub = __float_as_uint(b);
  ub = (ub + 0x7fffu + ((ub >> 16) & 1u)) & 0xffff0000u;
  return ua | ub;
}
__device__ __forceinline__ float bflo(unsigned v) { return __uint_as_float(v << 16); }
__device__ __forceinline__ float bfhi(unsigned v) { return __uint_as_float(v & 0xffff0000u); }

__device__ __forceinline__ float block_sum_256(float v, float* red, int t) {
#pragma unroll
  for (int o = 32; o > 0; o >>= 1) v += __shfl_xor(v, o, 64);
  __syncthreads();
  if ((t & 63) == 0) red[t >> 6] = v;
  __syncthreads();
  return red[0] + red[1] + red[2] + red[3];
}

// ---------------- Kernel ABP: A (0..767), B (768..1535), P (1536) ----------
__global__ __launch_bounds__(256) void kernABP(
    const float* __restrict__ msa, const float* __restrict__ state,
    const float* __restrict__ W_en, const float* __restrict__ b_en,
    const float* __restrict__ Wn1, const float* __restrict__ bn1,
    const float* __restrict__ Wn2, const float* __restrict__ bn2,
    const float* __restrict__ xyz, const float* __restrict__ W_ee,
    const float* __restrict__ We1, const float* __restrict__ We2,
    const float* __restrict__ Wm1, const float* __restrict__ Wm2,
    float* __restrict__ seq_ln, float* __restrict__ nodeo,
    int* __restrict__ nbr, float* __restrict__ colsum_ee,
    unsigned* __restrict__ pkws)
{
  const int bid = blockIdx.x, t = threadIdx.x;
  __shared__ float x[256];
  __shared__ float red[4];
  __shared__ float sn[16], n0[32], tn[32], hh[64], n1v[32];
  __shared__ float partA[8][33];
  __shared__ unsigned hist[256];
  __shared__ int selBin, below;
  __shared__ unsigned wcL[4], wcE[4];

  if (bid < LL) {
    // ================= A =================
    const int i = bid;
    float v = msa[i*256 + t];
    float mean = block_sum_256(v, red, t) * (1.f/256.f);
    float d = v - mean;
    float var = block_sum_256(d*d, red, t) * (1.f/256.f);
    float xn = d / sqrtf(var + 1e-5f);
    x[t] = xn;
    seq_ln[i*256 + t] = xn;

    if (t < 16) {
      float m2 = 0.f;
      for (int k = 0; k < 16; ++k) m2 += state[i*16 + k];
      m2 *= (1.f/16.f);
      float v2 = 0.f;
      for (int k = 0; k < 16; ++k) { float dd = state[i*16 + k] - m2; v2 += dd*dd; }
      v2 *= (1.f/16.f);
      sn[t] = (state[i*16 + t] - m2) / sqrtf(v2 + 1e-5f);
    }
    __syncthreads();

    {
      const int g = t >> 5, c = t & 31;
      float p = 0.f;
      for (int k = g*32; k < g*32 + 32; ++k) p = fmaf(x[k], W_en[k*32 + c], p);
      if (g == 7)
        for (int k = 0; k < 16; ++k) p = fmaf(sn[k], W_en[(256+k)*32 + c], p);
      partA[g][c] = p;
    }
    __syncthreads();
    if (t < 32) {
      float a = b_en[t];
#pragma unroll
      for (int g = 0; g < 8; ++g) a += partA[g][t];
      n0[t] = a;
    }
    __syncthreads();
    if (t < 32) {
      float m = 0.f;
      for (int k = 0; k < 32; ++k) m += n0[k];
      m *= (1.f/32.f);
      float vv = 0.f;
      for (int k = 0; k < 32; ++k) { float dd = n0[k] - m; vv += dd*dd; }
      vv *= (1.f/32.f);
      tn[t] = (n0[t] - m) / sqrtf(vv + 1e-5f);
    }
    __syncthreads();
    if (t < 64) {
      float a = bn1[t];
      for (int k = 0; k < 32; ++k) a = fmaf(tn[k], Wn1[k*64 + t], a);
      hh[t] = fmaxf(a, 0.f);
    }
    __syncthreads();
    if (t < 32) {
      float a = n0[t] + bn2[t];
      for (int k = 0; k < 64; ++k) a = fmaf(hh[k], Wn2[k*32 + t], a);
      n1v[t] = a;
    }
    __syncthreads();
    if (t < 32) {
      float m = 0.f;
      for (int k = 0; k < 32; ++k) m += n1v[k];
      m *= (1.f/32.f);
      float vv = 0.f;
      for (int k = 0; k < 32; ++k) { float dd = n1v[k] - m; vv += dd*dd; }
      vv *= (1.f/32.f);
      nodeo[i*32 + t] = (n1v[t] - m) / sqrtf(vv + 1e-5f);
    }
    return;
  }

  if (bid < 2*LL) {
    // ================= B: radix select =================
    const int i = bid - LL;
    const int lane = t & 63, wv = t >> 6;

    const float cix = xyz[i*9+3], ciy = xyz[i*9+4], ciz = xyz[i*9+5];
    unsigned key[3];
#pragma unroll
    for (int r = 0; r < 3; ++r) {
      const int j = r*256 + t;
      float dx = __fadd_rn(cix, -xyz[j*9+3]);
      float dy = __fadd_rn(ciy, -xyz[j*9+4]);
      float dz = __fadd_rn(ciz, -xyz[j*9+5]);
      float Dv = sqrtf(__fadd_rn(__fadd_rn(__fadd_rn(__fmul_rn(dx,dx),
                         __fmul_rn(dy,dy)), __fmul_rn(dz,dz)), 1e-8f));
      key[r] = __float_as_uint(Dv);
    }

    unsigned prefix = 0;
    int rank = 127, cntLess = 0;
#pragma unroll
    for (int pass = 0; pass < 4; ++pass) {
      const int shift = 24 - pass*8;
      const unsigned hiMask = (pass == 0) ? 0u : (0xFFFFFFFFu << (shift + 8));
      hist[t] = 0;
      __syncthreads();
#pragma unroll
      for (int r = 0; r < 3; ++r)
        if ((key[r] & hiMask) == (prefix & hiMask))
          atomicAdd(&hist[(key[r] >> shift) & 0xffu], 1u);
      __syncthreads();
      if (t < 64) {
        unsigned s0 = hist[t*4], s1 = hist[t*4+1], s2 = hist[t*4+2], s3 = hist[t*4+3];
        int tot = (int)(s0 + s1 + s2 + s3);
        int inc = tot;
#pragma unroll
        for (int o = 1; o < 64; o <<= 1) {
          int v = __shfl_up(inc, o);
          if (t >= o) inc += v;
        }
        int excl = inc - tot;
        if (rank >= excl && rank < inc) {
          int c = excl, bsel = t*4;
          if (rank >= c + (int)s0) { c += (int)s0; bsel = t*4+1;
            if (rank >= c + (int)s1) { c += (int)s1; bsel = t*4+2;
              if (rank >= c + (int)s2) { c += (int)s2; bsel = t*4+3; } } }
          selBin = bsel; below = c;
        }
      }
      __syncthreads();
      prefix |= ((unsigned)selBin) << shift;
      rank -= below;
      cntLess += below;
      __syncthreads();
    }
    const unsigned thr = prefix;

    const unsigned long long lmask = (1ull << lane) - 1ull;
    unsigned baseLt = 0, baseEq = (unsigned)cntLess;
#pragma unroll
    for (int r = 0; r < 3; ++r) {
      const int j = r*256 + t;
      const bool pl = key[r] < thr;
      const bool pe = key[r] == thr;
      unsigned long long balL = __ballot(pl);
      unsigned long long balE = __ballot(pe);
      unsigned preL = (unsigned)__popcll(balL & lmask);
      unsigned preE = (unsigned)__popcll(balE & lmask);
      if (lane == 0) { wcL[wv] = (unsigned)__popcll(balL); wcE[wv] = (unsigned)__popcll(balE); }
      __syncthreads();
      unsigned wbL = 0, wbE = 0, totL = 0, totE = 0;
#pragma unroll
      for (int w = 0; w < 4; ++w) {
        if (w < wv) { wbL += wcL[w]; wbE += wcE[w]; }
        totL += wcL[w]; totE += wcE[w];
      }
      if (pl) nbr[i*TOPK + baseLt + wbL + preL] = j;
      if (pe) {
        unsigned pos = baseEq + wbE + preE;
        if (pos < TOPK) nbr[i*TOPK + pos] = j;
      }
      baseLt += totL; baseEq += totE;
      __syncthreads();
    }
    return;
  }

  // ================= P: colsum + MFMA B-fragment weight packing ============
  {
    const int c = t & 31, sg = t >> 5;
    float s = 0.f;
    for (int k = sg*16; k < sg*16 + 16; ++k) s += W_ee[k*32 + c];
    partA[sg][c] = s;
    __syncthreads();
    if (t < 32) {
      float tot = 0.f;
#pragma unroll
      for (int g = 0; g < 8; ++g) tot += partA[g][t];
      colsum_ee[t] = tot;
    }

    // 34 B-frags: lane l holds W[kb+(l>>4)*8 + 2d .. +2d+1][ct*16 + (l&15)]
    const int lane6 = t & 63;
    for (int f = t >> 6; f < 34; f += 4) {
      const float* W; int N, krow0, ct;
      if (f < 4)       { W = We1;  N = 64; krow0 = 0;                    ct = f;        }
      else if (f < 8)  { W = We2;  N = 32; krow0 = ((f-4)>>1)*32;        ct = (f-4)&1;  }
      else if (f < 12) { W = Wm1;  N = 64; krow0 = 32;                   ct = f-8;      }
      else if (f < 16) { W = Wm1;  N = 64; krow0 = 64;                   ct = f-12;     }
      else if (f < 22) { W = Wm2;  N = 40; krow0 = ((f-16)/3)*32;        ct = (f-16)%3; }
      else if (f < 30) { W = W_ee; N = 32; krow0 = ((f-22)>>1)*32;       ct = (f-22)&1; }
      else             { W = W_ee; N = 32; krow0 = 128 + ((f-30)>>1)*32; ct = (f-30)&1; }
      const int cc = ct*16 + (lane6 & 15);
      const int kb = krow0 + ((lane6 >> 4) << 3);
#pragma unroll
      for (int d = 0; d < 4; ++d) {
        const int k = kb + 2*d;
        const float lo = (cc < N) ? W[k*N + cc]     : 0.f;
        const float hi = (cc < N) ? W[(k+1)*N + cc] : 0.f;
        pkws[f*256 + lane6*4 + d] = bfpack(lo, hi);
      }
    }
  }
}

// ---------------- Kernel C (FUSED C1 + MFMA MLP), 4 blocks/CU ---------------
__global__ __launch_bounds__(256, 4) void kernC(
    const float* __restrict__ pair, const float* __restrict__ xyz,
    const int* __restrict__ idx, const unsigned char* __restrict__ rmask,
    const float* __restrict__ W_ee, const float* __restrict__ b_ee,
    const float* __restrict__ colsum_ee,
    const float* __restrict__ be1, const float* __restrict__ be2,
    const float* __restrict__ Wm1, const float* __restrict__ bm1,
    const float* __restrict__ bm2,
    const float* __restrict__ Wl0, const float* __restrict__ bl0,
    const float* __restrict__ node, const int* __restrict__ nbr,
    const unsigned* __restrict__ pkws,
    float* __restrict__ soutf, float* __restrict__ out)
{
  const int i = blockIdx.x, t = threadIdx.x;
  const int lane = t & 63;
  const int wv = __builtin_amdgcn_readfirstlane(t >> 6);   // uniform 0..3
  __shared__ unsigned Ab[128][17];     // e0 -> ed -> e2 -> ed2 (bf16 pairs)
  __shared__ unsigned U[128*33];       // pairB[64][65] then Bb[128][33]
  __shared__ unsigned nd[128][17];     // node rows (bf16 pairs)
  __shared__ int   jl[128];
  __shared__ float Dvv[128], xsepv[128];
  __shared__ float relv[128][3];
  __shared__ float ni[32];
  __shared__ float pmv[64], prsv[64];
  __shared__ float mA[128], sgA[128];
  __shared__ float P2[4][44];
  __shared__ float fin[44];

  // ---- phase 0: stage ni, nd, jl, relv, Dv, xsep ----
  if (t < 32) ni[t] = node[i*32 + t];
  {
    const int pp = t >> 1, hh2 = t & 1;
    const int jj = nbr[i*TOPK + pp];
    const float4* nr = (const float4*)(node + jj*32 + hh2*16);
    float4 a0 = nr[0], a1 = nr[1], a2 = nr[2], a3 = nr[3];
    unsigned* dst = &nd[pp][hh2*8];
    dst[0] = bfpack(a0.x, a0.y); dst[1] = bfpack(a0.z, a0.w);
    dst[2] = bfpack(a1.x, a1.y); dst[3] = bfpack(a1.z, a1.w);
    dst[4] = bfpack(a2.x, a2.y); dst[5] = bfpack(a2.z, a2.w);
    dst[6] = bfpack(a3.x, a3.y); dst[7] = bfpack(a3.z, a3.w);
    if (hh2 == 0) {
      jl[pp] = jj;
      const float cix = xyz[i*9+3], ciy = xyz[i*9+4], ciz = xyz[i*9+5];
      const float cjx = xyz[jj*9+3], cjy = xyz[jj*9+4], cjz = xyz[jj*9+5];
      relv[pp][0] = cjx - cix;
      relv[pp][1] = cjy - ciy;
      relv[pp][2] = cjz - ciz;
      const float dx = __fadd_rn(cix, -cjx), dy = __fadd_rn(ciy, -cjy),
                  dz = __fadd_rn(ciz, -cjz);
      Dvv[pp] = sqrtf(__fadd_rn(__fadd_rn(__fadd_rn(__fmul_rn(dx,dx),
                        __fmul_rn(dy,dy)), __fmul_rn(dz,dz)), 1e-8f));
      const float offv = (float)(idx[jj] - idx[i]);
      const float sg = (offv > 0.f) ? 1.f : ((offv < 0.f) ? -1.f : 0.f);
      xsepv[pp] = sg * logf(fabsf(offv) + 1.f);
    }
  }
  __syncthreads();

  // ---- phase C1: edge0 into Ab via MFMA, two 64-edge sub-passes ----
  unsigned (*pairB)[65] = (unsigned (*)[65])U;
  const f32x4_t fz = {0.f, 0.f, 0.f, 0.f};
  for (int sub = 0; sub < 2; ++sub) {
    {  // coalesced stage of 64 pair rows -> bf16 LDS; stats via quad shuffle
      const int r = t >> 2, qq = t & 3;
      const float* prow = pair + ((size_t)i*LL + jl[sub*64 + r])*128 + qq*32;
      float s = 0.f, ss = 0.f;
#pragma unroll
      for (int n = 0; n < 8; ++n) {
        float4 v = ((const float4*)prow)[n];
        s  += (v.x + v.y) + (v.z + v.w);
        ss += v.x*v.x + v.y*v.y + v.z*v.z + v.w*v.w;
        pairB[r][qq*16 + n*2]     = bfpack(v.x, v.y);
        pairB[r][qq*16 + n*2 + 1] = bfpack(v.z, v.w);
      }
      s  += __shfl_xor(s, 1);  s  += __shfl_xor(s, 2);
      ss += __shfl_xor(ss, 1); ss += __shfl_xor(ss, 2);
      if (qq == 0) {
        const float pm = s * (1.f/128.f);
        const float pv = ss * (1.f/128.f) - pm*pm;
        pmv[r] = pm; prsv[r] = 1.f / sqrtf(pv + 1e-5f);
      }
    }
    __syncthreads();
    {  // MFMA matvec: wave wv owns m-tile wv (16 edges), both col-tiles
      const int col = lane & 15, rg = lane >> 4;
      const int eM = wv*16;   // local m-tile base
      f32x4_t accP[2] = {fz, fz}, accR[2] = {fz, fz};
#pragma unroll
      for (int ks = 0; ks < 4; ++ks) {   // pair part: K=128
        u32x4_t av;
        const unsigned* rp = &pairB[eM + col][ks*16 + rg*4];
        av.x = rp[0]; av.y = rp[1]; av.z = rp[2]; av.w = rp[3];
        const bf16x8_t af = __builtin_bit_cast(bf16x8_t, av);
#pragma unroll
        for (int ct = 0; ct < 2; ++ct) {
          const u32x4_t bv = ((const u32x4_t*)(pkws + (22 + ks*2 + ct)*256))[lane];
          accP[ct] = __builtin_amdgcn_mfma_f32_16x16x32_bf16(
              af, __builtin_bit_cast(bf16x8_t, bv), accP[ct], 0, 0, 0);
        }
      }
      const float Dv = Dvv[sub*64 + eM + col];   // this lane's A-row edge
#pragma unroll
      for (int ks = 0; ks < 2; ++ks) {   // RBF part: K=64, A in-register
        u32x4_t av;
#pragma unroll
        for (int d = 0; d < 4; ++d) {
          const int k = ks*32 + rg*8 + 2*d;
          const float mu0 = 2.f + (float)k     * (20.f/63.f);
          const float mu1 = 2.f + (float)(k+1) * (20.f/63.f);
          const float u0 = (Dv - mu0) / 0.3125f;
          const float u1 = (Dv - mu1) / 0.3125f;
          ((unsigned*)&av)[d] = bfpack(expf(-(u0*u0)), expf(-(u1*u1)));
        }
        const bf16x8_t af = __builtin_bit_cast(bf16x8_t, av);
#pragma unroll
        for (int ct = 0; ct < 2; ++ct) {
          const u32x4_t bv = ((const u32x4_t*)(pkws + (30 + ks*2 + ct)*256))[lane];
          accR[ct] = __builtin_amdgcn_mfma_f32_16x16x32_bf16(
              af, __builtin_bit_cast(bf16x8_t, bv), accR[ct], 0, 0, 0);
        }
      }
      // epilogue: e0 = prs*pairacc - prs*pm*colsum + rbfacc + xsep*w3 + bias
#pragma unroll
      for (int ct = 0; ct < 2; ++ct) {
        const int ch = ct*16 + col;
        const float cs = colsum_ee[ch];
        const float w3 = W_ee[192*32 + ch];
        const float bb = b_ee[ch];
#pragma unroll
        for (int j = 0; j < 4; ++j) {
          const int eloc = eM + rg*4 + j;
          const int e = sub*64 + eloc;
          const float prs = prsv[eloc], pm = pmv[eloc];
          float v = fmaf(prs, accP[ct][j],
                     fmaf(-prs*pm, cs,
                       fmaf(xsepv[e], w3, bb + accR[ct][j])));
          const float p = __shfl_xor(v, 1);
          if (!(lane & 1)) Ab[e][ct*8 + (col >> 1)] = bfpack(v, p);
        }
      }
    }
    __syncthreads();
  }

  // ---- MFMA MLP chain: wave wv owns edges [32wv, 32wv+32); NO barriers ----
  unsigned (*Bb)[33] = (unsigned (*)[33])U;
  {
    const int e0b = 32 * wv;
    const int row = lane & 15;    // A M-row / D N-col
    const int kg  = lane >> 4;    // k-group
    const int r0  = kg * 4;       // D M-row base

    // LN(Ab) per-wave (2 lanes/edge), keep mean/sigma
    {
      const int eL = e0b + (lane & 31);
      const int hf = lane >> 5;
      float av[16];
#pragma unroll
      for (int kk = 0; kk < 8; ++kk) {
        const unsigned v = Ab[eL][hf*8 + kk];
        av[2*kk] = bflo(v); av[2*kk+1] = bfhi(v);
      }
      float s = 0.f;
#pragma unroll
      for (int c = 0; c < 16; ++c) s += av[c];
      s += __shfl_xor(s, 32);
      const float mm = s * (1.f/32.f);
      float vv = 0.f;
#pragma unroll
      for (int c = 0; c < 16; ++c) { const float dd = av[c] - mm; vv += dd*dd; }
      vv += __shfl_xor(vv, 32);
      vv *= (1.f/32.f);
      const float sg = sqrtf(vv + 1e-5f);
      const float rs = 1.f / sg;
#pragma unroll
      for (int kk = 0; kk < 8; ++kk)
        Ab[eL][hf*8 + kk] = bfpack((av[2*kk]-mm)*rs, (av[2*kk+1]-mm)*rs);
      if (hf == 0) { mA[eL] = mm; sgA[eL] = sg; }
    }

    // ---- h = relu(ed @ We1 + be1): MFMA, K=32, N=64 ----
    {
      f32x4_t acc[2][4];
#pragma unroll
      for (int m = 0; m < 2; ++m) {
        u32x4_t av4;
        const unsigned* rp = &Ab[e0b + 16*m + row][0];
        av4.x = rp[kg*4]; av4.y = rp[kg*4+1]; av4.z = rp[kg*4+2]; av4.w = rp[kg*4+3];
        const bf16x8_t af = __builtin_bit_cast(bf16x8_t, av4);
#pragma unroll
        for (int ct = 0; ct < 4; ++ct) {
          const u32x4_t bv = ((const u32x4_t*)(pkws + (0 + ct)*256))[lane];
          acc[m][ct] = __builtin_amdgcn_mfma_f32_16x16x32_bf16(
              af, __builtin_bit_cast(bf16x8_t, bv), fz, 0, 0, 0);
        }
      }
#pragma unroll
      for (int m = 0; m < 2; ++m)
#pragma unroll
        for (int ct = 0; ct < 4; ++ct) {
          const int ch = ct*16 + row;
#pragma unroll
          for (int j = 0; j < 4; ++j) {
            float v = fmaxf(acc[m][ct][j] + be1[ch], 0.f);
            const float p = __shfl_xor(v, 1);
            if (!(lane & 1))
              Bb[e0b + 16*m + r0 + j][ct*8 + (row >> 1)] = bfpack(v, p);
          }
        }
    }

    // ---- e2 = e0raw + h @ We2 + be2: MFMA, K=64, N=32 ----
    {
      f32x4_t acc[2][2];
#pragma unroll
      for (int m = 0; m < 2; ++m)
#pragma unroll
        for (int ct = 0; ct < 2; ++ct) acc[m][ct] = fz;
#pragma unroll
      for (int m = 0; m < 2; ++m)
#pragma unroll
        for (int ks = 0; ks < 2; ++ks) {
          u32x4_t av4;
          const unsigned* rp = &Bb[e0b + 16*m + row][0];
          const int kd = ks*16 + kg*4;
          av4.x = rp[kd]; av4.y = rp[kd+1]; av4.z = rp[kd+2]; av4.w = rp[kd+3];
          const bf16x8_t af = __builtin_bit_cast(bf16x8_t, av4);
#pragma unroll
          for (int ct = 0; ct < 2; ++ct) {
            const u32x4_t bv = ((const u32x4_t*)(pkws + (4 + ks*2 + ct)*256))[lane];
            acc[m][ct] = __builtin_amdgcn_mfma_f32_16x16x32_bf16(
                af, __builtin_bit_cast(bf16x8_t, bv), acc[m][ct], 0, 0, 0);
          }
        }
#pragma unroll
      for (int m = 0; m < 2; ++m)
#pragma unroll
        for (int ct = 0; ct < 2; ++ct) {
          const int ch = ct*16 + row;
          const int dw = ct*8 + (row >> 1);
#pragma unroll
          for (int j = 0; j < 4; ++j) {
            const int e = e0b + 16*m + r0 + j;
            const unsigned old = Ab[e][dw];
            const float e0v = (lane & 1) ? bfhi(old) : bflo(old);
            float v = acc[m][ct][j] + fmaf(e0v, sgA[e], mA[e]) + be2[ch];
            const float p = __shfl_xor(v, 1);
            if (!(lane & 1)) Ab[e][dw] = bfpack(v, p);
          }
        }
    }

    // LN(e2) per-wave
    {
      const int eL = e0b + (lane & 31);
      const int hf = lane >> 5;
      float av[16];
#pragma unroll
      for (int kk = 0; kk < 8; ++kk) {
        const unsigned v = Ab[eL][hf*8 + kk];
        av[2*kk] = bflo(v); av[2*kk+1] = bfhi(v);
      }
      float s = 0.f;
#pragma unroll
      for (int c = 0; c < 16; ++c) s += av[c];
      s += __shfl_xor(s, 32);
      const float mm = s * (1.f/32.f);
      float vv = 0.f;
#pragma unroll
      for (int c = 0; c < 16; ++c) { const float dd = av[c] - mm; vv += dd*dd; }
      vv += __shfl_xor(vv, 32);
      vv *= (1.f/32.f);
      const float rs = 1.f / sqrtf(vv + 1e-5f);
#pragma unroll
      for (int kk = 0; kk < 8; ++kk)
        Ab[eL][hf*8 + kk] = bfpack((av[2*kk]-mm)*rs, (av[2*kk+1]-mm)*rs);
    }

    // ---- m1 = relu(ni-part + nd@Wm1[32:64] + ed2@Wm1[64:96] + bm1) ----
    {
      float tmpni = bm1[lane];   // lane = channel 0..63
      for (int k = 0; k < 32; ++k) tmpni = fmaf(ni[k], Wm1[k*64 + lane], tmpni);
      f32x4_t acc[2][4];
#pragma unroll
      for (int m = 0; m < 2; ++m)
#pragma unroll
        for (int ct = 0; ct < 4; ++ct) acc[m][ct] = fz;
#pragma unroll
      for (int m = 0; m < 2; ++m) {
        u32x4_t aN, aE;
        const unsigned* rn = &nd[e0b + 16*m + row][0];
        aN.x = rn[kg*4]; aN.y = rn[kg*4+1]; aN.z = rn[kg*4+2]; aN.w = rn[kg*4+3];
        const unsigned* ra = &Ab[e0b + 16*m + row][0];
        aE.x = ra[kg*4]; aE.y = ra[kg*4+1]; aE.z = ra[kg*4+2]; aE.w = ra[kg*4+3];
        const bf16x8_t afN = __builtin_bit_cast(bf16x8_t, aN);
        const bf16x8_t afE = __builtin_bit_cast(bf16x8_t, aE);
#pragma unroll
        for (int ct = 0; ct < 4; ++ct) {
          const u32x4_t bN = ((const u32x4_t*)(pkws + (8 + ct)*256))[lane];
          const u32x4_t bE = ((const u32x4_t*)(pkws + (12 + ct)*256))[lane];
          acc[m][ct] = __builtin_amdgcn_mfma_f32_16x16x32_bf16(
              afN, __builtin_bit_cast(bf16x8_t, bN), acc[m][ct], 0, 0, 0);
          acc[m][ct] = __builtin_amdgcn_mfma_f32_16x16x32_bf16(
              afE, __builtin_bit_cast(bf16x8_t, bE), acc[m][ct], 0, 0, 0);
        }
      }
#pragma unroll
      for (int m = 0; m < 2; ++m)
#pragma unroll
        for (int ct = 0; ct < 4; ++ct) {
          const int ch = ct*16 + row;
          const float tb = __shfl(tmpni, ch);
#pragma unroll
          for (int j = 0; j < 4; ++j) {
            float v = fmaxf(acc[m][ct][j] + tb, 0.f);
            const float p = __shfl_xor(v, 1);
            if (!(lane & 1))
              Bb[e0b + 16*m + r0 + j][ct*8 + (row >> 1)] = bfpack(v, p);
          }
        }
    }

    // ---- m2: MFMA K=64, N=48 (40 valid) + expand + reduce ----
    {
      f32x4_t acc[2][3];
#pragma unroll
      for (int m = 0; m < 2; ++m)
#pragma unroll
        for (int ct = 0; ct < 3; ++ct) acc[m][ct] = fz;
#pragma unroll
      for (int m = 0; m < 2; ++m)
#pragma unroll
        for (int ks = 0; ks < 2; ++ks) {
          u32x4_t av4;
          const unsigned* rp = &Bb[e0b + 16*m + row][0];
          const int kd = ks*16 + kg*4;
          av4.x = rp[kd]; av4.y = rp[kd+1]; av4.z = rp[kd+2]; av4.w = rp[kd+3];
          const bf16x8_t af = __builtin_bit_cast(bf16x8_t, av4);
#pragma unroll
          for (int ct = 0; ct < 3; ++ct) {
            const u32x4_t bv = ((const u32x4_t*)(pkws + (16 + ks*3 + ct)*256))[lane];
            acc[m][ct] = __builtin_amdgcn_mfma_f32_16x16x32_bf16(
                af, __builtin_bit_cast(bf16x8_t, bv), acc[m][ct], 0, 0, 0);
          }
        }
      float plain[3] = {0.f, 0.f, 0.f};
      float rel3[3]  = {0.f, 0.f, 0.f};
#pragma unroll
      for (int m = 0; m < 2; ++m)
#pragma unroll
        for (int ct = 0; ct < 3; ++ct) {
          const int o = ct*16 + row;
          if (ct == 2 && row >= 8) continue;   // o >= 40
#pragma unroll
          for (int j = 0; j < 4; ++j) {
            const int e = e0b + 16*m + r0 + j;
            const float v = acc[m][ct][j] + bm2[o];
            if (ct == 2 && row < 2) {
              rel3[0] = fmaf(v, relv[e][0], rel3[0]);
              rel3[1] = fmaf(v, relv[e][1], rel3[1]);
              rel3[2] = fmaf(v, relv[e][2], rel3[2]);
            } else {
              plain[ct] += v;
            }
          }
        }
#pragma unroll
      for (int d = 0; d < 3; ++d) {
        plain[d] += __shfl_xor(plain[d], 16); plain[d] += __shfl_xor(plain[d], 32);
        rel3[d]  += __shfl_xor(rel3[d], 16);  rel3[d]  += __shfl_xor(rel3[d], 32);
      }
      if (lane < 16) {
        P2[wv][lane]      = plain[0];
        P2[wv][16 + lane] = plain[1];
        if (lane < 2) {
#pragma unroll
          for (int d = 0; d < 3; ++d) P2[wv][32 + lane*3 + d] = rel3[d];
        } else if (lane < 8) {
          P2[wv][38 + lane - 2] = plain[2];
        }
      }
    }
  }
  __syncthreads();
  if (t < 44) fin[t] = P2[0][t] + P2[1][t] + P2[2][t] + P2[3][t];
  __syncthreads();

  if (t < 16) {  // state_out = [node_i, m_l0] @ Wl0 + bl0
    float a = bl0[t];
#pragma unroll
    for (int k = 0; k < 32; ++k) a = fmaf(ni[k], Wl0[k*16 + t], a);
#pragma unroll
    for (int k = 0; k < 32; ++k) a = fmaf(fin[k] * (1.f/128.f), Wl0[(32+k)*16 + t], a);
    soutf[i*16 + t] = a;
    out[LL*9 + i*16 + t] = a;
  }
  if (t == 0) {  // frame update
    float ve[6], wa[6];
#pragma unroll
    for (int qq = 0; qq < 6; ++qq) ve[qq] = fin[32 + qq] * (1.f/128.f);
#pragma unroll
    for (int qq = 0; qq < 6; ++qq) wa[qq] = fin[38 + qq] * (1.f/128.f);
    float l1[9];
#pragma unroll
    for (int a = 0; a < 3; ++a)
#pragma unroll
      for (int d = 0; d < 3; ++d) l1[a*3 + d] = xyz[i*9 + a*3 + d] - xyz[i*9 + 3 + d];
    float T[3], Rv[3];
#pragma unroll
    for (int d = 0; d < 3; ++d) {
      float va0 = wa[0]*l1[d] + wa[1]*l1[3 + d] + wa[2]*l1[6 + d];
      float va1 = wa[3]*l1[d] + wa[4]*l1[3 + d] + wa[5]*l1[6 + d];
      T[d]  = (ve[d] + va0) / 10.f;
      Rv[d] = (ve[3 + d] + va1) / 100.f;
    }
    float qn = sqrtf(1.f + Rv[0]*Rv[0] + Rv[1]*Rv[1] + Rv[2]*Rv[2]);
    float qA = 1.f/qn, qB = Rv[0]/qn, qC = Rv[1]/qn, qD = Rv[2]/qn;
    float Rm[9];
    Rm[0] = qA*qA + qB*qB - qC*qC - qD*qD;
    Rm[1] = 2.f*qB*qC - 2.f*qA*qD;
    Rm[2] = 2.f*qB*qD + 2.f*qA*qC;
    Rm[3] = 2.f*qB*qC + 2.f*qA*qD;
    Rm[4] = qA*qA - qB*qB + qC*qC - qD*qD;
    Rm[5] = 2.f*qC*qD - 2.f*qA*qB;
    Rm[6] = 2.f*qB*qD - 2.f*qA*qC;
    Rm[7] = 2.f*qC*qD + 2.f*qA*qB;
    Rm[8] = qA*qA - qB*qB - qC*qC + qD*qD;
    if (rmask[i]) {
      Rm[0] = 1.f; Rm[1] = 0.f; Rm[2] = 0.f;
      Rm[3] = 0.f; Rm[4] = 1.f; Rm[5] = 0.f;
      Rm[6] = 0.f; Rm[7] = 0.f; Rm[8] = 1.f;
    }
#pragma unroll
    for (int a = 0; a < 3; ++a)
#pragma unroll
      for (int di = 0; di < 3; ++di) {
        float xn = Rm[di*3+0]*l1[a*3+0] + Rm[di*3+1]*l1[a*3+1] + Rm[di*3+2]*l1[a*3+2]
                 + xyz[i*9 + 3 + di] + T[di];
        out[i*9 + a*3 + di] = xn;
      }
  }
}

// ---------------- Kernel D: si MLP stack -> alpha (512 thr, 4-way k-split) --
__global__ __launch_bounds__(512) void kernD(
    const float* __restrict__ seq_ln, const float* __restrict__ st_out,
    const float* __restrict__ Ws0, const float* __restrict__ bs0,
    const float* __restrict__ Wsi, const float* __restrict__ bsi,
    const float* __restrict__ Wp1, const float* __restrict__ bp1,
    const float* __restrict__ Wp2, const float* __restrict__ bp2,
    const float* __restrict__ Wp3, const float* __restrict__ bp3,
    const float* __restrict__ Wp4, const float* __restrict__ bp4,
    const float* __restrict__ Wout, const float* __restrict__ bout,
    float* __restrict__ out)
{
  const int i = blockIdx.x, t = threadIdx.x;
  const int c = t & 127, g = t >> 7;
  __shared__ float x0[256], stn[16], act[128], resid[128], part[4][129];

  if (t < 256) x0[t] = seq_ln[i*256 + t];
  if (t < 16) {
    float m = 0.f;
    for (int k = 0; k < 16; ++k) m += st_out[i*16 + k];
    m *= (1.f/16.f);
    float v = 0.f;
    for (int k = 0; k < 16; ++k) { float dd = st_out[i*16 + k] - m; v += dd*dd; }
    v *= (1.f/16.f);
    stn[t] = (st_out[i*16 + t] - m) / sqrtf(v + 1e-5f);
  }
  __syncthreads();

  {
    float p = 0.f;
    for (int k = g*64; k < g*64 + 64; ++k) p = fmaf(x0[k], Ws0[k*128 + c], p);
    if (g == 0)
      for (int k = 0; k < 16; ++k) p = fmaf(stn[k], Wsi[k*128 + c], p);
    part[g][c] = p;
  }
  __syncthreads();
  if (t < 128) {
    const float si = part[0][t] + part[1][t] + part[2][t] + part[3][t]
                   + bs0[t] + bsi[t];
    resid[t] = si;
    act[t] = fmaxf(si, 0.f);
  }
  __syncthreads();

  {
    float p = 0.f;
    for (int k = g*32; k < g*32 + 32; ++k) p = fmaf(act[k], Wp1[k*128 + c], p);
    part[g][c] = p;
  }
  __syncthreads();
  if (t < 128)
    act[t] = fmaxf(part[0][t] + part[1][t] + part[2][t] + part[3][t] + bp1[t], 0.f);
  __syncthreads();

  {
    float p = 0.f;
    for (int k = g*32; k < g*32 + 32; ++k) p = fmaf(act[k], Wp2[k*128 + c], p);
    part[g][c] = p;
  }
  __syncthreads();
  if (t < 128) {
    const float si = resid[t] + part[0][t] + part[1][t] + part[2][t] + part[3][t] + bp2[t];
    resid[t] = si;
    act[t] = fmaxf(si, 0.f);
  }
  __syncthreads();

  {
    float p = 0.f;
    for (int k = g*32; k < g*32 + 32; ++k) p = fmaf(act[k], Wp3[k*128 + c], p);
    part[g][c] = p;
  }
  __syncthreads();
  if (t < 128)
    act[t] = fmaxf(part[0][t] + part[1][t] + part[2][t] + part[3][t] + bp3[t], 0.f);
  __syncthreads();

  {
    float p = 0.f;
    for (int k = g*32; k < g*32 + 32; ++k) p = fmaf(act[k], Wp4[k*128 + c], p);
    part[g][c] = p;
  }
  __syncthreads();
  if (t < 128)
    act[t] = fmaxf(resid[t] + part[0][t] + part[1][t] + part[2][t] + part[3][t] + bp4[t], 0.f);
  __syncthreads();

  if (t < 20) {
    float a = bout[t];
    for (int k = 0; k < 128; ++k) a = fmaf(act[k], Wout[k*20 + t], a);
    out[19200 + i*20 + t] = a;
  }
}

extern "C" void kernel_launch(void* const* d_in, const int* in_sizes, int n_in,
                              void* d_out, int out_size, void* d_ws, size_t ws_size,
                              hipStream_t stream)
{
  (void)in_sizes; (void)n_in; (void)out_size; (void)ws_size;
  const float* msa   = (const float*)d_in[0];
  const float* pair  = (const float*)d_in[1];
  const float* xyz   = (const float*)d_in[2];
  const float* state = (const float*)d_in[3];
  const int*   idx   = (const int*)d_in[4];
  const unsigned char* rmask = (const unsigned char*)d_in[5];
  const float* W_en = (const float*)d_in[6];
  const float* b_en = (const float*)d_in[7];
  const float* Wn1  = (const float*)d_in[8];
  const float* bn1  = (const float*)d_in[9];
  const float* Wn2  = (const float*)d_in[10];
  const float* bn2  = (const float*)d_in[11];
  const float* W_ee = (const float*)d_in[12];
  const float* b_ee = (const float*)d_in[13];
  const float* We1  = (const float*)d_in[14];
  const float* be1  = (const float*)d_in[15];
  const float* We2  = (const float*)d_in[16];
  const float* be2  = (const float*)d_in[17];
  const float* Wm1  = (const float*)d_in[18];
  const float* bm1  = (const float*)d_in[19];
  const float* Wm2  = (const float*)d_in[20];
  const float* bm2  = (const float*)d_in[21];
  const float* Wl0  = (const float*)d_in[22];
  const float* bl0  = (const float*)d_in[23];
  const float* Ws0  = (const float*)d_in[24];
  const float* bs0  = (const float*)d_in[25];
  const float* Wsi  = (const float*)d_in[26];
  const float* bsi  = (const float*)d_in[27];
  const float* Wp1  = (const float*)d_in[28];
  const float* bp1  = (const float*)d_in[29];
  const float* Wp2  = (const float*)d_in[30];
  const float* bp2  = (const float*)d_in[31];
  const float* Wp3  = (const float*)d_in[32];
  const float* bp3  = (const float*)d_in[33];
  const float* Wp4  = (const float*)d_in[34];
  const float* bp4  = (const float*)d_in[35];
  const float* Wout = (const float*)d_in[36];
  const float* bout = (const float*)d_in[37];

  float* wsf    = (float*)d_ws;
  float* seq_ln = wsf + WS_SEQ;
  float* nodev  = wsf + WS_NODE;
  int*   nbr    = (int*)(wsf + WS_NBR);
  float* soutf  = wsf + WS_SOUT;
  float* csee   = wsf + WS_CSEE;
  unsigned* pkws = (unsigned*)(wsf + WS_PK);
  float* out = (float*)d_out;

  kernABP<<<2*LL + 1, 256, 0, stream>>>(msa, state, W_en, b_en, Wn1, bn1, Wn2, bn2,
                                        xyz, W_ee, We1, We2, Wm1, Wm2,
                                        seq_ln, nodev, nbr, csee, pkws);
  kernC<<<LL, 256, 0, stream>>>(pair, xyz, idx, rmask, W_ee, b_ee, csee,
                                be1, be2, Wm1, bm1, bm2,
                                Wl0, bl0, nodev, nbr, pkws, soutf, out);
  kernD<<<LL, 512, 0, stream>>>(seq_ln, soutf, Ws0, bs0, Wsi, bsi, Wp1, bp1, Wp2, bp2,
                                Wp3, bp3, Wp4, bp4, Wout, bout, out);
}

// Round 16
// 73.955 us; speedup vs baseline: 2.3022x; 1.1051x over previous
//
#include <hip/hip_runtime.h>
#include <hip/hip_bf16.h>

#define LL 768
#define TOPK 128

// workspace layout (floats)
#define WS_SEQ  0                        // 768*256
#define WS_NODE (WS_SEQ + LL*256)        // 768*32
#define WS_NBR  (WS_NODE + LL*32)        // 768*128 ints
#define WS_CSEE (WS_NBR + LL*TOPK)       // 32
#define WS_FIN  (WS_CSEE + 32)           // 768*2*44
#define WS_PK   (WS_FIN + LL*2*44)       // 34 frags x 256 dwords

typedef __attribute__((ext_vector_type(8))) short  bf16x8_t;
typedef __attribute__((ext_vector_type(4))) float  f32x4_t;
typedef __attribute__((ext_vector_type(4))) unsigned u32x4_t;

// bf16 pair pack/unpack (RNE)
__device__ __forceinline__ unsigned bfpack(float a, float b) {
  unsigned ua = __float_as_uint(a);
  ua = (ua + 0x7fffu + ((ua >> 16) & 1u)) >> 16;
  unsigned ub = __float_as_uint(b);
  ub = (ub + 0x7fffu + ((ub >> 16) & 1u)) & 0xffff0000u;
  return ua | ub;
}
__device__ __forceinline__ float bflo(unsigned v) { return __uint_as_float(v << 16); }
__device__ __forceinline__ float bfhi(unsigned v) { return __uint_as_float(v & 0xffff0000u); }

__device__ __forceinline__ float block_sum_256(float v, float* red, int t) {
#pragma unroll
  for (int o = 32; o > 0; o >>= 1) v += __shfl_xor(v, o, 64);
  __syncthreads();
  if ((t & 63) == 0) red[t >> 6] = v;
  __syncthreads();
  return red[0] + red[1] + red[2] + red[3];
}

// ---------------- Kernel ABP: A (0..767), B (768..1535), P (1536) ----------
__global__ __launch_bounds__(256) void kernABP(
    const float* __restrict__ msa, const float* __restrict__ state,
    const float* __restrict__ W_en, const float* __restrict__ b_en,
    const float* __restrict__ Wn1, const float* __restrict__ bn1,
    const float* __restrict__ Wn2, const float* __restrict__ bn2,
    const float* __restrict__ xyz, const float* __restrict__ W_ee,
    const float* __restrict__ We1, const float* __restrict__ We2,
    const float* __restrict__ Wm1, const float* __restrict__ Wm2,
    float* __restrict__ seq_ln, float* __restrict__ nodeo,
    int* __restrict__ nbr, float* __restrict__ colsum_ee,
    unsigned* __restrict__ pkws)
{
  const int bid = blockIdx.x, t = threadIdx.x;
  __shared__ float x[256];
  __shared__ float red[4];
  __shared__ float sn[16], n0[32], tn[32], hh[64], n1v[32];
  __shared__ float partA[8][33];
  __shared__ unsigned hist[256];
  __shared__ int selBin, below;
  __shared__ unsigned wcL[4], wcE[4];

  if (bid < LL) {
    // ================= A =================
    const int i = bid;
    float v = msa[i*256 + t];
    float mean = block_sum_256(v, red, t) * (1.f/256.f);
    float d = v - mean;
    float var = block_sum_256(d*d, red, t) * (1.f/256.f);
    float xn = d / sqrtf(var + 1e-5f);
    x[t] = xn;
    seq_ln[i*256 + t] = xn;

    if (t < 16) {
      float m2 = 0.f;
      for (int k = 0; k < 16; ++k) m2 += state[i*16 + k];
      m2 *= (1.f/16.f);
      float v2 = 0.f;
      for (int k = 0; k < 16; ++k) { float dd = state[i*16 + k] - m2; v2 += dd*dd; }
      v2 *= (1.f/16.f);
      sn[t] = (state[i*16 + t] - m2) / sqrtf(v2 + 1e-5f);
    }
    __syncthreads();

    {
      const int g = t >> 5, c = t & 31;
      float p = 0.f;
      for (int k = g*32; k < g*32 + 32; ++k) p = fmaf(x[k], W_en[k*32 + c], p);
      if (g == 7)
        for (int k = 0; k < 16; ++k) p = fmaf(sn[k], W_en[(256+k)*32 + c], p);
      partA[g][c] = p;
    }
    __syncthreads();
    if (t < 32) {
      float a = b_en[t];
#pragma unroll
      for (int g = 0; g < 8; ++g) a += partA[g][t];
      n0[t] = a;
    }
    __syncthreads();
    if (t < 32) {
      float m = 0.f;
      for (int k = 0; k < 32; ++k) m += n0[k];
      m *= (1.f/32.f);
      float vv = 0.f;
      for (int k = 0; k < 32; ++k) { float dd = n0[k] - m; vv += dd*dd; }
      vv *= (1.f/32.f);
      tn[t] = (n0[t] - m) / sqrtf(vv + 1e-5f);
    }
    __syncthreads();
    if (t < 64) {
      float a = bn1[t];
      for (int k = 0; k < 32; ++k) a = fmaf(tn[k], Wn1[k*64 + t], a);
      hh[t] = fmaxf(a, 0.f);
    }
    __syncthreads();
    if (t < 32) {
      float a = n0[t] + bn2[t];
      for (int k = 0; k < 64; ++k) a = fmaf(hh[k], Wn2[k*32 + t], a);
      n1v[t] = a;
    }
    __syncthreads();
    if (t < 32) {
      float m = 0.f;
      for (int k = 0; k < 32; ++k) m += n1v[k];
      m *= (1.f/32.f);
      float vv = 0.f;
      for (int k = 0; k < 32; ++k) { float dd = n1v[k] - m; vv += dd*dd; }
      vv *= (1.f/32.f);
      nodeo[i*32 + t] = (n1v[t] - m) / sqrtf(vv + 1e-5f);
    }
    return;
  }

  if (bid < 2*LL) {
    // ================= B: radix select =================
    const int i = bid - LL;
    const int lane = t & 63, wv = t >> 6;

    const float cix = xyz[i*9+3], ciy = xyz[i*9+4], ciz = xyz[i*9+5];
    unsigned key[3];
#pragma unroll
    for (int r = 0; r < 3; ++r) {
      const int j = r*256 + t;
      float dx = __fadd_rn(cix, -xyz[j*9+3]);
      float dy = __fadd_rn(ciy, -xyz[j*9+4]);
      float dz = __fadd_rn(ciz, -xyz[j*9+5]);
      float Dv = sqrtf(__fadd_rn(__fadd_rn(__fadd_rn(__fmul_rn(dx,dx),
                         __fmul_rn(dy,dy)), __fmul_rn(dz,dz)), 1e-8f));
      key[r] = __float_as_uint(Dv);
    }

    unsigned prefix = 0;
    int rank = 127, cntLess = 0;
#pragma unroll
    for (int pass = 0; pass < 4; ++pass) {
      const int shift = 24 - pass*8;
      const unsigned hiMask = (pass == 0) ? 0u : (0xFFFFFFFFu << (shift + 8));
      hist[t] = 0;
      __syncthreads();
#pragma unroll
      for (int r = 0; r < 3; ++r)
        if ((key[r] & hiMask) == (prefix & hiMask))
          atomicAdd(&hist[(key[r] >> shift) & 0xffu], 1u);
      __syncthreads();
      if (t < 64) {
        unsigned s0 = hist[t*4], s1 = hist[t*4+1], s2 = hist[t*4+2], s3 = hist[t*4+3];
        int tot = (int)(s0 + s1 + s2 + s3);
        int inc = tot;
#pragma unroll
        for (int o = 1; o < 64; o <<= 1) {
          int v = __shfl_up(inc, o);
          if (t >= o) inc += v;
        }
        int excl = inc - tot;
        if (rank >= excl && rank < inc) {
          int c = excl, bsel = t*4;
          if (rank >= c + (int)s0) { c += (int)s0; bsel = t*4+1;
            if (rank >= c + (int)s1) { c += (int)s1; bsel = t*4+2;
              if (rank >= c + (int)s2) { c += (int)s2; bsel = t*4+3; } } }
          selBin = bsel; below = c;
        }
      }
      __syncthreads();
      prefix |= ((unsigned)selBin) << shift;
      rank -= below;
      cntLess += below;
      __syncthreads();
    }
    const unsigned thr = prefix;

    const unsigned long long lmask = (1ull << lane) - 1ull;
    unsigned baseLt = 0, baseEq = (unsigned)cntLess;
#pragma unroll
    for (int r = 0; r < 3; ++r) {
      const int j = r*256 + t;
      const bool pl = key[r] < thr;
      const bool pe = key[r] == thr;
      unsigned long long balL = __ballot(pl);
      unsigned long long balE = __ballot(pe);
      unsigned preL = (unsigned)__popcll(balL & lmask);
      unsigned preE = (unsigned)__popcll(balE & lmask);
      if (lane == 0) { wcL[wv] = (unsigned)__popcll(balL); wcE[wv] = (unsigned)__popcll(balE); }
      __syncthreads();
      unsigned wbL = 0, wbE = 0, totL = 0, totE = 0;
#pragma unroll
      for (int w = 0; w < 4; ++w) {
        if (w < wv) { wbL += wcL[w]; wbE += wcE[w]; }
        totL += wcL[w]; totE += wcE[w];
      }
      if (pl) nbr[i*TOPK + baseLt + wbL + preL] = j;
      if (pe) {
        unsigned pos = baseEq + wbE + preE;
        if (pos < TOPK) nbr[i*TOPK + pos] = j;
      }
      baseLt += totL; baseEq += totE;
      __syncthreads();
    }
    return;
  }

  // ================= P: colsum + MFMA B-fragment weight packing ============
  {
    const int c = t & 31, sg = t >> 5;
    float s = 0.f;
    for (int k = sg*16; k < sg*16 + 16; ++k) s += W_ee[k*32 + c];
    partA[sg][c] = s;
    __syncthreads();
    if (t < 32) {
      float tot = 0.f;
#pragma unroll
      for (int g = 0; g < 8; ++g) tot += partA[g][t];
      colsum_ee[t] = tot;
    }

    // 34 B-frags: lane l holds W[kb+(l>>4)*8 + 2d .. +2d+1][ct*16 + (l&15)]
    const int lane6 = t & 63;
    for (int f = t >> 6; f < 34; f += 4) {
      const float* W; int N, krow0, ct;
      if (f < 4)       { W = We1;  N = 64; krow0 = 0;                    ct = f;        }
      else if (f < 8)  { W = We2;  N = 32; krow0 = ((f-4)>>1)*32;        ct = (f-4)&1;  }
      else if (f < 12) { W = Wm1;  N = 64; krow0 = 32;                   ct = f-8;      }
      else if (f < 16) { W = Wm1;  N = 64; krow0 = 64;                   ct = f-12;     }
      else if (f < 22) { W = Wm2;  N = 40; krow0 = ((f-16)/3)*32;        ct = (f-16)%3; }
      else if (f < 30) { W = W_ee; N = 32; krow0 = ((f-22)>>1)*32;       ct = (f-22)&1; }
      else             { W = W_ee; N = 32; krow0 = 128 + ((f-30)>>1)*32; ct = (f-30)&1; }
      const int cc = ct*16 + (lane6 & 15);
      const int kb = krow0 + ((lane6 >> 4) << 3);
#pragma unroll
      for (int d = 0; d < 4; ++d) {
        const int k = kb + 2*d;
        const float lo = (cc < N) ? W[k*N + cc]     : 0.f;
        const float hi = (cc < N) ? W[(k+1)*N + cc] : 0.f;
        pkws[f*256 + lane6*4 + d] = bfpack(lo, hi);
      }
    }
  }
}

// ---------------- Kernel C: 64 edges/block, MFMA chain, 5 blocks/CU --------
// blockIdx = i*2 + part. Wave wv owns edges [16wv, 16wv+16). Partial 44-sum
// written to fin2; the per-residue epilogue moved to kernD's prologue.
__global__ __launch_bounds__(256, 5) void kernC(
    const float* __restrict__ pair, const float* __restrict__ xyz,
    const int* __restrict__ idx,
    const float* __restrict__ W_ee, const float* __restrict__ b_ee,
    const float* __restrict__ colsum_ee,
    const float* __restrict__ be1, const float* __restrict__ be2,
    const float* __restrict__ Wm1, const float* __restrict__ bm1,
    const float* __restrict__ bm2,
    const float* __restrict__ node, const int* __restrict__ nbr,
    const unsigned* __restrict__ pkws, float* __restrict__ fin2)
{
  const int i = blockIdx.x >> 1, part = blockIdx.x & 1;
  const int t = threadIdx.x, lane = t & 63;
  const int wv = __builtin_amdgcn_readfirstlane(t >> 6);   // uniform 0..3
  __shared__ unsigned Ab[64][17];      // e0 -> ed -> e2 -> ed2 (bf16 pairs)
  __shared__ unsigned U[64*65];        // pairB[64][65]; Bb[64][33] reuses
  __shared__ unsigned nd[64][17];      // node rows (bf16 pairs)
  __shared__ int   jl[64];
  __shared__ float Dvv[64], xsepv[64];
  __shared__ float relv[64][3];
  __shared__ float ni[32];
  __shared__ float pmv[64], prsv[64];
  __shared__ float mA[64], sgA[64];
  __shared__ float P2[4][44];

  // ---- phase 0: stage ni, nd, jl, relv, Dv, xsep (64 edges) ----
  if (t < 32) ni[t] = node[i*32 + t];
  if (t < 128) {
    const int pp = t >> 1, hh2 = t & 1;
    const int jj = nbr[i*TOPK + part*64 + pp];
    const float4* nr = (const float4*)(node + jj*32 + hh2*16);
    float4 a0 = nr[0], a1 = nr[1], a2 = nr[2], a3 = nr[3];
    unsigned* dst = &nd[pp][hh2*8];
    dst[0] = bfpack(a0.x, a0.y); dst[1] = bfpack(a0.z, a0.w);
    dst[2] = bfpack(a1.x, a1.y); dst[3] = bfpack(a1.z, a1.w);
    dst[4] = bfpack(a2.x, a2.y); dst[5] = bfpack(a2.z, a2.w);
    dst[6] = bfpack(a3.x, a3.y); dst[7] = bfpack(a3.z, a3.w);
    if (hh2 == 0) {
      jl[pp] = jj;
      const float cix = xyz[i*9+3], ciy = xyz[i*9+4], ciz = xyz[i*9+5];
      const float cjx = xyz[jj*9+3], cjy = xyz[jj*9+4], cjz = xyz[jj*9+5];
      relv[pp][0] = cjx - cix;
      relv[pp][1] = cjy - ciy;
      relv[pp][2] = cjz - ciz;
      const float dx = __fadd_rn(cix, -cjx), dy = __fadd_rn(ciy, -cjy),
                  dz = __fadd_rn(ciz, -cjz);
      Dvv[pp] = sqrtf(__fadd_rn(__fadd_rn(__fadd_rn(__fmul_rn(dx,dx),
                        __fmul_rn(dy,dy)), __fmul_rn(dz,dz)), 1e-8f));
      const float offv = (float)(idx[jj] - idx[i]);
      const float sg = (offv > 0.f) ? 1.f : ((offv < 0.f) ? -1.f : 0.f);
      xsepv[pp] = sg * logf(fabsf(offv) + 1.f);
    }
  }
  __syncthreads();

  // ---- C1 staging: 64 pair rows -> bf16 LDS (single pass) ----
  unsigned (*pairB)[65] = (unsigned (*)[65])U;
  {
    const int r = t >> 2, qq = t & 3;
    const float* prow = pair + ((size_t)i*LL + jl[r])*128 + qq*32;
    float s = 0.f, ss = 0.f;
#pragma unroll
    for (int n = 0; n < 8; ++n) {
      float4 v = ((const float4*)prow)[n];
      s  += (v.x + v.y) + (v.z + v.w);
      ss += v.x*v.x + v.y*v.y + v.z*v.z + v.w*v.w;
      pairB[r][qq*16 + n*2]     = bfpack(v.x, v.y);
      pairB[r][qq*16 + n*2 + 1] = bfpack(v.z, v.w);
    }
    s  += __shfl_xor(s, 1);  s  += __shfl_xor(s, 2);
    ss += __shfl_xor(ss, 1); ss += __shfl_xor(ss, 2);
    if (qq == 0) {
      const float pm = s * (1.f/128.f);
      const float pv = ss * (1.f/128.f) - pm*pm;
      pmv[r] = pm; prsv[r] = 1.f / sqrtf(pv + 1e-5f);
    }
  }
  __syncthreads();

  const f32x4_t fz = {0.f, 0.f, 0.f, 0.f};

  // ---- C1 MFMA: wave wv owns m-tile wv (16 edges), both col-tiles ----
  {
    const int col = lane & 15, rg = lane >> 4;
    const int eM = wv*16;
    f32x4_t accP[2] = {fz, fz}, accR[2] = {fz, fz};
#pragma unroll
    for (int ks = 0; ks < 4; ++ks) {   // pair part: K=128
      u32x4_t av;
      const unsigned* rp = &pairB[eM + col][ks*16 + rg*4];
      av.x = rp[0]; av.y = rp[1]; av.z = rp[2]; av.w = rp[3];
      const bf16x8_t af = __builtin_bit_cast(bf16x8_t, av);
#pragma unroll
      for (int ct = 0; ct < 2; ++ct) {
        const u32x4_t bv = ((const u32x4_t*)(pkws + (22 + ks*2 + ct)*256))[lane];
        accP[ct] = __builtin_amdgcn_mfma_f32_16x16x32_bf16(
            af, __builtin_bit_cast(bf16x8_t, bv), accP[ct], 0, 0, 0);
      }
    }
    const float Dv = Dvv[eM + col];
#pragma unroll
    for (int ks = 0; ks < 2; ++ks) {   // RBF part: K=64, A in-register
      u32x4_t av;
#pragma unroll
      for (int d = 0; d < 4; ++d) {
        const int k = ks*32 + rg*8 + 2*d;
        const float mu0 = 2.f + (float)k     * (20.f/63.f);
        const float mu1 = 2.f + (float)(k+1) * (20.f/63.f);
        const float u0 = (Dv - mu0) / 0.3125f;
        const float u1 = (Dv - mu1) / 0.3125f;
        ((unsigned*)&av)[d] = bfpack(expf(-(u0*u0)), expf(-(u1*u1)));
      }
      const bf16x8_t af = __builtin_bit_cast(bf16x8_t, av);
#pragma unroll
      for (int ct = 0; ct < 2; ++ct) {
        const u32x4_t bv = ((const u32x4_t*)(pkws + (30 + ks*2 + ct)*256))[lane];
        accR[ct] = __builtin_amdgcn_mfma_f32_16x16x32_bf16(
            af, __builtin_bit_cast(bf16x8_t, bv), accR[ct], 0, 0, 0);
      }
    }
#pragma unroll
    for (int ct = 0; ct < 2; ++ct) {
      const int ch = ct*16 + col;
      const float cs = colsum_ee[ch];
      const float w3 = W_ee[192*32 + ch];
      const float bb = b_ee[ch];
#pragma unroll
      for (int j = 0; j < 4; ++j) {
        const int e = eM + rg*4 + j;
        const float prs = prsv[e], pm = pmv[e];
        float v = fmaf(prs, accP[ct][j],
                   fmaf(-prs*pm, cs,
                     fmaf(xsepv[e], w3, bb + accR[ct][j])));
        const float p = __shfl_xor(v, 1);
        if (!(lane & 1)) Ab[e][ct*8 + (col >> 1)] = bfpack(v, p);
      }
    }
  }
  __syncthreads();

  // ---- MFMA MLP chain: wave wv owns edges [16wv, 16wv+16); NO barriers ----
  unsigned (*Bb)[33] = (unsigned (*)[33])U;
  {
    const int e0b = 16 * wv;
    const int row = lane & 15;    // A M-row / D N-col
    const int kg  = lane >> 4;    // k-group
    const int r0  = kg * 4;       // D M-row base

    // LN(Ab) per-wave: 4 lanes per edge (16 edges)
    {
      const int eL = e0b + row;
      float av[8];
#pragma unroll
      for (int kk = 0; kk < 4; ++kk) {
        const unsigned v = Ab[eL][kg*4 + kk];
        av[2*kk] = bflo(v); av[2*kk+1] = bfhi(v);
      }
      float s = 0.f;
#pragma unroll
      for (int c = 0; c < 8; ++c) s += av[c];
      s += __shfl_xor(s, 16); s += __shfl_xor(s, 32);
      const float mm = s * (1.f/32.f);
      float vv = 0.f;
#pragma unroll
      for (int c = 0; c < 8; ++c) { const float dd = av[c] - mm; vv += dd*dd; }
      vv += __shfl_xor(vv, 16); vv += __shfl_xor(vv, 32);
      vv *= (1.f/32.f);
      const float sg = sqrtf(vv + 1e-5f);
      const float rs = 1.f / sg;
#pragma unroll
      for (int kk = 0; kk < 4; ++kk)
        Ab[eL][kg*4 + kk] = bfpack((av[2*kk]-mm)*rs, (av[2*kk+1]-mm)*rs);
      if (kg == 0) { mA[eL] = mm; sgA[eL] = sg; }
    }

    // ---- h = relu(ed @ We1 + be1): MFMA, K=32, N=64 ----
    {
      u32x4_t av4;
      const unsigned* rp = &Ab[e0b + row][0];
      av4.x = rp[kg*4]; av4.y = rp[kg*4+1]; av4.z = rp[kg*4+2]; av4.w = rp[kg*4+3];
      const bf16x8_t af = __builtin_bit_cast(bf16x8_t, av4);
      f32x4_t acc[4];
#pragma unroll
      for (int ct = 0; ct < 4; ++ct) {
        const u32x4_t bv = ((const u32x4_t*)(pkws + (0 + ct)*256))[lane];
        acc[ct] = __builtin_amdgcn_mfma_f32_16x16x32_bf16(
            af, __builtin_bit_cast(bf16x8_t, bv), fz, 0, 0, 0);
      }
#pragma unroll
      for (int ct = 0; ct < 4; ++ct) {
        const int ch = ct*16 + row;
#pragma unroll
        for (int j = 0; j < 4; ++j) {
          float v = fmaxf(acc[ct][j] + be1[ch], 0.f);
          const float p = __shfl_xor(v, 1);
          if (!(lane & 1))
            Bb[e0b + r0 + j][ct*8 + (row >> 1)] = bfpack(v, p);
        }
      }
    }

    // ---- e2 = e0raw + h @ We2 + be2: MFMA, K=64, N=32 ----
    {
      f32x4_t acc[2] = {fz, fz};
#pragma unroll
      for (int ks = 0; ks < 2; ++ks) {
        u32x4_t av4;
        const unsigned* rp = &Bb[e0b + row][0];
        const int kd = ks*16 + kg*4;
        av4.x = rp[kd]; av4.y = rp[kd+1]; av4.z = rp[kd+2]; av4.w = rp[kd+3];
        const bf16x8_t af = __builtin_bit_cast(bf16x8_t, av4);
#pragma unroll
        for (int ct = 0; ct < 2; ++ct) {
          const u32x4_t bv = ((const u32x4_t*)(pkws + (4 + ks*2 + ct)*256))[lane];
          acc[ct] = __builtin_amdgcn_mfma_f32_16x16x32_bf16(
              af, __builtin_bit_cast(bf16x8_t, bv), acc[ct], 0, 0, 0);
        }
      }
#pragma unroll
      for (int ct = 0; ct < 2; ++ct) {
        const int ch = ct*16 + row;
        const int dw = ct*8 + (row >> 1);
#pragma unroll
        for (int j = 0; j < 4; ++j) {
          const int e = e0b + r0 + j;
          const unsigned old = Ab[e][dw];
          const float e0v = (lane & 1) ? bfhi(old) : bflo(old);
          float v = acc[ct][j] + fmaf(e0v, sgA[e], mA[e]) + be2[ch];
          const float p = __shfl_xor(v, 1);
          if (!(lane & 1)) Ab[e][dw] = bfpack(v, p);
        }
      }
    }

    // LN(e2) per-wave
    {
      const int eL = e0b + row;
      float av[8];
#pragma unroll
      for (int kk = 0; kk < 4; ++kk) {
        const unsigned v = Ab[eL][kg*4 + kk];
        av[2*kk] = bflo(v); av[2*kk+1] = bfhi(v);
      }
      float s = 0.f;
#pragma unroll
      for (int c = 0; c < 8; ++c) s += av[c];
      s += __shfl_xor(s, 16); s += __shfl_xor(s, 32);
      const float mm = s * (1.f/32.f);
      float vv = 0.f;
#pragma unroll
      for (int c = 0; c < 8; ++c) { const float dd = av[c] - mm; vv += dd*dd; }
      vv += __shfl_xor(vv, 16); vv += __shfl_xor(vv, 32);
      vv *= (1.f/32.f);
      const float rs = 1.f / sqrtf(vv + 1e-5f);
#pragma unroll
      for (int kk = 0; kk < 4; ++kk)
        Ab[eL][kg*4 + kk] = bfpack((av[2*kk]-mm)*rs, (av[2*kk+1]-mm)*rs);
    }

    // ---- m1 = relu(ni-part + nd@Wm1[32:64] + ed2@Wm1[64:96] + bm1) ----
    {
      float tmpni = bm1[lane];   // lane = channel 0..63
      for (int k = 0; k < 32; ++k) tmpni = fmaf(ni[k], Wm1[k*64 + lane], tmpni);
      u32x4_t aN, aE;
      const unsigned* rn = &nd[e0b + row][0];
      aN.x = rn[kg*4]; aN.y = rn[kg*4+1]; aN.z = rn[kg*4+2]; aN.w = rn[kg*4+3];
      const unsigned* ra = &Ab[e0b + row][0];
      aE.x = ra[kg*4]; aE.y = ra[kg*4+1]; aE.z = ra[kg*4+2]; aE.w = ra[kg*4+3];
      const bf16x8_t afN = __builtin_bit_cast(bf16x8_t, aN);
      const bf16x8_t afE = __builtin_bit_cast(bf16x8_t, aE);
      f32x4_t acc[4];
#pragma unroll
      for (int ct = 0; ct < 4; ++ct) {
        const u32x4_t bN = ((const u32x4_t*)(pkws + (8 + ct)*256))[lane];
        const u32x4_t bE = ((const u32x4_t*)(pkws + (12 + ct)*256))[lane];
        acc[ct] = __builtin_amdgcn_mfma_f32_16x16x32_bf16(
            afN, __builtin_bit_cast(bf16x8_t, bN), fz, 0, 0, 0);
        acc[ct] = __builtin_amdgcn_mfma_f32_16x16x32_bf16(
            afE, __builtin_bit_cast(bf16x8_t, bE), acc[ct], 0, 0, 0);
      }
#pragma unroll
      for (int ct = 0; ct < 4; ++ct) {
        const int ch = ct*16 + row;
        const float tb = __shfl(tmpni, ch);
#pragma unroll
        for (int j = 0; j < 4; ++j) {
          float v = fmaxf(acc[ct][j] + tb, 0.f);
          const float p = __shfl_xor(v, 1);
          if (!(lane & 1))
            Bb[e0b + r0 + j][ct*8 + (row >> 1)] = bfpack(v, p);
        }
      }
    }

    // ---- m2: MFMA K=64, N=48 (40 valid) + expand + wave reduce ----
    {
      f32x4_t acc[3] = {fz, fz, fz};
#pragma unroll
      for (int ks = 0; ks < 2; ++ks) {
        u32x4_t av4;
        const unsigned* rp = &Bb[e0b + row][0];
        const int kd = ks*16 + kg*4;
        av4.x = rp[kd]; av4.y = rp[kd+1]; av4.z = rp[kd+2]; av4.w = rp[kd+3];
        const bf16x8_t af = __builtin_bit_cast(bf16x8_t, av4);
#pragma unroll
        for (int ct = 0; ct < 3; ++ct) {
          const u32x4_t bv = ((const u32x4_t*)(pkws + (16 + ks*3 + ct)*256))[lane];
          acc[ct] = __builtin_amdgcn_mfma_f32_16x16x32_bf16(
              af, __builtin_bit_cast(bf16x8_t, bv), acc[ct], 0, 0, 0);
        }
      }
      float plain[3] = {0.f, 0.f, 0.f};
      float rel3[3]  = {0.f, 0.f, 0.f};
#pragma unroll
      for (int ct = 0; ct < 3; ++ct) {
        const int o = ct*16 + row;
        if (ct == 2 && row >= 8) continue;   // o >= 40
#pragma unroll
        for (int j = 0; j < 4; ++j) {
          const int e = e0b + r0 + j;
          const float v = acc[ct][j] + bm2[o];
          if (ct == 2 && row < 2) {
            rel3[0] = fmaf(v, relv[e][0], rel3[0]);
            rel3[1] = fmaf(v, relv[e][1], rel3[1]);
            rel3[2] = fmaf(v, relv[e][2], rel3[2]);
          } else {
            plain[ct] += v;
          }
        }
      }
#pragma unroll
      for (int d = 0; d < 3; ++d) {
        plain[d] += __shfl_xor(plain[d], 16); plain[d] += __shfl_xor(plain[d], 32);
        rel3[d]  += __shfl_xor(rel3[d], 16);  rel3[d]  += __shfl_xor(rel3[d], 32);
      }
      if (lane < 16) {
        P2[wv][lane]      = plain[0];
        P2[wv][16 + lane] = plain[1];
        if (lane < 2) {
#pragma unroll
          for (int d = 0; d < 3; ++d) P2[wv][32 + lane*3 + d] = rel3[d];
        } else if (lane < 8) {
          P2[wv][38 + lane - 2] = plain[2];
        }
      }
    }
  }
  __syncthreads();
  if (t < 44)
    fin2[(size_t)(i*2 + part)*44 + t] = P2[0][t] + P2[1][t] + P2[2][t] + P2[3][t];
}

// ---------------- Kernel D: epilogue (state_out/frame) + si MLP -> alpha ----
__global__ __launch_bounds__(512) void kernD(
    const float* __restrict__ seq_ln, const float* __restrict__ xyz,
    const unsigned char* __restrict__ rmask,
    const float* __restrict__ Wl0, const float* __restrict__ bl0,
    const float* __restrict__ node, const float* __restrict__ fin2,
    const float* __restrict__ Ws0, const float* __restrict__ bs0,
    const float* __restrict__ Wsi, const float* __restrict__ bsi,
    const float* __restrict__ Wp1, const float* __restrict__ bp1,
    const float* __restrict__ Wp2, const float* __restrict__ bp2,
    const float* __restrict__ Wp3, const float* __restrict__ bp3,
    const float* __restrict__ Wp4, const float* __restrict__ bp4,
    const float* __restrict__ Wout, const float* __restrict__ bout,
    float* __restrict__ out)
{
  const int i = blockIdx.x, t = threadIdx.x;
  const int c = t & 127, g = t >> 7;
  __shared__ float fin[44], niD[32], sout_s[16], stn[16];
  __shared__ float x0[256], act[128], resid[128], part[4][129];

  if (t < 44) fin[t] = fin2[(size_t)(i*2)*44 + t] + fin2[(size_t)(i*2+1)*44 + t];
  if (t >= 64 && t < 96) niD[t-64] = node[i*32 + (t-64)];
  if (t >= 256) x0[t-256] = seq_ln[i*256 + (t-256)];
  else if (t >= 128) x0[t] = seq_ln[i*256 + t];   // t in [128,256) covers x0[128..256)
  __syncthreads();

  if (t < 16) {  // state_out = [node_i, m_l0] @ Wl0 + bl0
    float a = bl0[t];
#pragma unroll
    for (int k = 0; k < 32; ++k) a = fmaf(niD[k], Wl0[k*16 + t], a);
#pragma unroll
    for (int k = 0; k < 32; ++k) a = fmaf(fin[k] * (1.f/128.f), Wl0[(32+k)*16 + t], a);
    sout_s[t] = a;
    out[LL*9 + i*16 + t] = a;
  }
  if (t == 32) {  // frame update
    float ve[6], wa[6];
#pragma unroll
    for (int qq = 0; qq < 6; ++qq) ve[qq] = fin[32 + qq] * (1.f/128.f);
#pragma unroll
    for (int qq = 0; qq < 6; ++qq) wa[qq] = fin[38 + qq] * (1.f/128.f);
    float l1[9];
#pragma unroll
    for (int a = 0; a < 3; ++a)
#pragma unroll
      for (int d = 0; d < 3; ++d) l1[a*3 + d] = xyz[i*9 + a*3 + d] - xyz[i*9 + 3 + d];
    float T[3], Rv[3];
#pragma unroll
    for (int d = 0; d < 3; ++d) {
      float va0 = wa[0]*l1[d] + wa[1]*l1[3 + d] + wa[2]*l1[6 + d];
      float va1 = wa[3]*l1[d] + wa[4]*l1[3 + d] + wa[5]*l1[6 + d];
      T[d]  = (ve[d] + va0) / 10.f;
      Rv[d] = (ve[3 + d] + va1) / 100.f;
    }
    float qn = sqrtf(1.f + Rv[0]*Rv[0] + Rv[1]*Rv[1] + Rv[2]*Rv[2]);
    float qA = 1.f/qn, qB = Rv[0]/qn, qC = Rv[1]/qn, qD = Rv[2]/qn;
    float Rm[9];
    Rm[0] = qA*qA + qB*qB - qC*qC - qD*qD;
    Rm[1] = 2.f*qB*qC - 2.f*qA*qD;
    Rm[2] = 2.f*qB*qD + 2.f*qA*qC;
    Rm[3] = 2.f*qB*qC + 2.f*qA*qD;
    Rm[4] = qA*qA - qB*qB + qC*qC - qD*qD;
    Rm[5] = 2.f*qC*qD - 2.f*qA*qB;
    Rm[6] = 2.f*qB*qD - 2.f*qA*qC;
    Rm[7] = 2.f*qC*qD + 2.f*qA*qB;
    Rm[8] = qA*qA - qB*qB - qC*qC + qD*qD;
    if (rmask[i]) {
      Rm[0] = 1.f; Rm[1] = 0.f; Rm[2] = 0.f;
      Rm[3] = 0.f; Rm[4] = 1.f; Rm[5] = 0.f;
      Rm[6] = 0.f; Rm[7] = 0.f; Rm[8] = 1.f;
    }
#pragma unroll
    for (int a = 0; a < 3; ++a)
#pragma unroll
      for (int di = 0; di < 3; ++di) {
        float xn = Rm[di*3+0]*l1[a*3+0] + Rm[di*3+1]*l1[a*3+1] + Rm[di*3+2]*l1[a*3+2]
                 + xyz[i*9 + 3 + di] + T[di];
        out[i*9 + a*3 + di] = xn;
      }
  }
  __syncthreads();

  if (t < 16) {
    float m = 0.f;
    for (int k = 0; k < 16; ++k) m += sout_s[k];
    m *= (1.f/16.f);
    float v = 0.f;
    for (int k = 0; k < 16; ++k) { float dd = sout_s[k] - m; v += dd*dd; }
    v *= (1.f/16.f);
    stn[t] = (sout_s[t] - m) / sqrtf(v + 1e-5f);
  }
  __syncthreads();

  // L0: si = x0 @ Ws0 + stn @ Wsi + bs0 + bsi
  {
    float p = 0.f;
    for (int k = g*64; k < g*64 + 64; ++k) p = fmaf(x0[k], Ws0[k*128 + c], p);
    if (g == 0)
      for (int k = 0; k < 16; ++k) p = fmaf(stn[k], Wsi[k*128 + c], p);
    part[g][c] = p;
  }
  __syncthreads();
  if (t < 128) {
    const float si = part[0][t] + part[1][t] + part[2][t] + part[3][t]
                   + bs0[t] + bsi[t];
    resid[t] = si;
    act[t] = fmaxf(si, 0.f);
  }
  __syncthreads();

  {
    float p = 0.f;
    for (int k = g*32; k < g*32 + 32; ++k) p = fmaf(act[k], Wp1[k*128 + c], p);
    part[g][c] = p;
  }
  __syncthreads();
  if (t < 128)
    act[t] = fmaxf(part[0][t] + part[1][t] + part[2][t] + part[3][t] + bp1[t], 0.f);
  __syncthreads();

  {
    float p = 0.f;
    for (int k = g*32; k < g*32 + 32; ++k) p = fmaf(act[k], Wp2[k*128 + c], p);
    part[g][c] = p;
  }
  __syncthreads();
  if (t < 128) {
    const float si = resid[t] + part[0][t] + part[1][t] + part[2][t] + part[3][t] + bp2[t];
    resid[t] = si;
    act[t] = fmaxf(si, 0.f);
  }
  __syncthreads();

  {
    float p = 0.f;
    for (int k = g*32; k < g*32 + 32; ++k) p = fmaf(act[k], Wp3[k*128 + c], p);
    part[g][c] = p;
  }
  __syncthreads();
  if (t < 128)
    act[t] = fmaxf(part[0][t] + part[1][t] + part[2][t] + part[3][t] + bp3[t], 0.f);
  __syncthreads();

  {
    float p = 0.f;
    for (int k = g*32; k < g*32 + 32; ++k) p = fmaf(act[k], Wp4[k*128 + c], p);
    part[g][c] = p;
  }
  __syncthreads();
  if (t < 128)
    act[t] = fmaxf(resid[t] + part[0][t] + part[1][t] + part[2][t] + part[3][t] + bp4[t], 0.f);
  __syncthreads();

  if (t < 20) {
    float a = bout[t];
    for (int k = 0; k < 128; ++k) a = fmaf(act[k], Wout[k*20 + t], a);
    out[19200 + i*20 + t] = a;
  }
}

extern "C" void kernel_launch(void* const* d_in, const int* in_sizes, int n_in,
                              void* d_out, int out_size, void* d_ws, size_t ws_size,
                              hipStream_t stream)
{
  (void)in_sizes; (void)n_in; (void)out_size; (void)ws_size;
  const float* msa   = (const float*)d_in[0];
  const float* pair  = (const float*)d_in[1];
  const float* xyz   = (const float*)d_in[2];
  const float* state = (const float*)d_in[3];
  const int*   idx   = (const int*)d_in[4];
  const unsigned char* rmask = (const unsigned char*)d_in[5];
  const float* W_en = (const float*)d_in[6];
  const float* b_en = (const float*)d_in[7];
  const float* Wn1  = (const float*)d_in[8];
  const float* bn1  = (const float*)d_in[9];
  const float* Wn2  = (const float*)d_in[10];
  const float* bn2  = (const float*)d_in[11];
  const float* W_ee = (const float*)d_in[12];
  const float* b_ee = (const float*)d_in[13];
  const float* We1  = (const float*)d_in[14];
  const float* be1  = (const float*)d_in[15];
  const float* We2  = (const float*)d_in[16];
  const float* be2  = (const float*)d_in[17];
  const float* Wm1  = (const float*)d_in[18];
  const float* bm1  = (const float*)d_in[19];
  const float* Wm2  = (const float*)d_in[20];
  const float* bm2  = (const float*)d_in[21];
  const float* Wl0  = (const float*)d_in[22];
  const float* bl0  = (const float*)d_in[23];
  const float* Ws0  = (const float*)d_in[24];
  const float* bs0  = (const float*)d_in[25];
  const float* Wsi  = (const float*)d_in[26];
  const float* bsi  = (const float*)d_in[27];
  const float* Wp1  = (const float*)d_in[28];
  const float* bp1  = (const float*)d_in[29];
  const float* Wp2  = (const float*)d_in[30];
  const float* bp2  = (const float*)d_in[31];
  const float* Wp3  = (const float*)d_in[32];
  const float* bp3  = (const float*)d_in[33];
  const float* Wp4  = (const float*)d_in[34];
  const float* bp4  = (const float*)d_in[35];
  const float* Wout = (const float*)d_in[36];
  const float* bout = (const float*)d_in[37];

  float* wsf    = (float*)d_ws;
  float* seq_ln = wsf + WS_SEQ;
  float* nodev  = wsf + WS_NODE;
  int*   nbr    = (int*)(wsf + WS_NBR);
  float* csee   = wsf + WS_CSEE;
  float* fin2   = wsf + WS_FIN;
  unsigned* pkws = (unsigned*)(wsf + WS_PK);
  float* out = (float*)d_out;

  kernABP<<<2*LL + 1, 256, 0, stream>>>(msa, state, W_en, b_en, Wn1, bn1, Wn2, bn2,
                                        xyz, W_ee, We1, We2, Wm1, Wm2,
                                        seq_ln, nodev, nbr, csee, pkws);
  kernC<<<2*LL, 256, 0, stream>>>(pair, xyz, idx, W_ee, b_ee, csee,
                                  be1, be2, Wm1, bm1, bm2,
                                  nodev, nbr, pkws, fin2);
  kernD<<<LL, 512, 0, stream>>>(seq_ln, xyz, rmask, Wl0, bl0, nodev, fin2,
                                Ws0, bs0, Wsi, bsi, Wp1, bp1, Wp2, bp2,
                                Wp3, bp3, Wp4, bp4, Wout, bout, out);
}

// Round 17
// 72.174 us; speedup vs baseline: 2.3590x; 1.0247x over previous
//
#include <hip/hip_runtime.h>
#include <hip/hip_bf16.h>

#define LL 768
#define TOPK 128

// workspace layout (floats)
#define WS_SEQ   0                         // 768*256
#define WS_NODE  (WS_SEQ + LL*256)         // 768*32
#define WS_NBR   (WS_NODE + LL*32)         // 768*128 ints
#define WS_CSEE  (WS_NBR + LL*TOPK)        // 32
#define WS_FIN   (WS_CSEE + 32)            // 768*2*44
#define WS_NIM   (WS_FIN + LL*2*44)        // 768*64
#define WS_NODEB (WS_NIM + LL*64)          // 768*16 (u32)
#define WS_PK    (WS_NODEB + LL*16)        // 34 frags x 256 dwords

typedef __attribute__((ext_vector_type(8))) short  bf16x8_t;
typedef __attribute__((ext_vector_type(4))) float  f32x4_t;
typedef __attribute__((ext_vector_type(4))) unsigned u32x4_t;

// bf16 pair pack/unpack (RNE)
__device__ __forceinline__ unsigned bfpack(float a, float b) {
  unsigned ua = __float_as_uint(a);
  ua = (ua + 0x7fffu + ((ua >> 16) & 1u)) >> 16;
  unsigned ub = __float_as_uint(b);
  ub = (ub + 0x7fffu + ((ub >> 16) & 1u)) & 0xffff0000u;
  return ua | ub;
}
__device__ __forceinline__ float bflo(unsigned v) { return __uint_as_float(v << 16); }
__device__ __forceinline__ float bfhi(unsigned v) { return __uint_as_float(v & 0xffff0000u); }

__device__ __forceinline__ float block_sum_256(float v, float* red, int t) {
#pragma unroll
  for (int o = 32; o > 0; o >>= 1) v += __shfl_xor(v, o, 64);
  __syncthreads();
  if ((t & 63) == 0) red[t >> 6] = v;
  __syncthreads();
  return red[0] + red[1] + red[2] + red[3];
}

// ---------------- Kernel ABP: A (0..767), B (768..1535), P (1536) ----------
__global__ __launch_bounds__(256) void kernABP(
    const float* __restrict__ msa, const float* __restrict__ state,
    const float* __restrict__ W_en, const float* __restrict__ b_en,
    const float* __restrict__ Wn1, const float* __restrict__ bn1,
    const float* __restrict__ Wn2, const float* __restrict__ bn2,
    const float* __restrict__ xyz, const float* __restrict__ W_ee,
    const float* __restrict__ We1, const float* __restrict__ We2,
    const float* __restrict__ Wm1, const float* __restrict__ bm1,
    const float* __restrict__ Wm2,
    float* __restrict__ seq_ln, float* __restrict__ nodeo,
    int* __restrict__ nbr, float* __restrict__ colsum_ee,
    float* __restrict__ nim, unsigned* __restrict__ nodeb,
    unsigned* __restrict__ pkws)
{
  const int bid = blockIdx.x, t = threadIdx.x;
  __shared__ float x[256];
  __shared__ float red[4];
  __shared__ float sn[16], n0[32], tn[32], hh[64], n1v[32], nfin[32];
  __shared__ float partA[8][33];
  __shared__ float partN[4][65];
  __shared__ unsigned hist[256];
  __shared__ int selBin, below;
  __shared__ unsigned wcL[4], wcE[4];

  if (bid < LL) {
    // ================= A =================
    const int i = bid;
    float v = msa[i*256 + t];
    float mean = block_sum_256(v, red, t) * (1.f/256.f);
    float d = v - mean;
    float var = block_sum_256(d*d, red, t) * (1.f/256.f);
    float xn = d / sqrtf(var + 1e-5f);
    x[t] = xn;
    seq_ln[i*256 + t] = xn;

    if (t < 16) {
      float m2 = 0.f;
      for (int k = 0; k < 16; ++k) m2 += state[i*16 + k];
      m2 *= (1.f/16.f);
      float v2 = 0.f;
      for (int k = 0; k < 16; ++k) { float dd = state[i*16 + k] - m2; v2 += dd*dd; }
      v2 *= (1.f/16.f);
      sn[t] = (state[i*16 + t] - m2) / sqrtf(v2 + 1e-5f);
    }
    __syncthreads();

    {
      const int g = t >> 5, c = t & 31;
      float p = 0.f;
      for (int k = g*32; k < g*32 + 32; ++k) p = fmaf(x[k], W_en[k*32 + c], p);
      if (g == 7)
        for (int k = 0; k < 16; ++k) p = fmaf(sn[k], W_en[(256+k)*32 + c], p);
      partA[g][c] = p;
    }
    __syncthreads();
    if (t < 32) {
      float a = b_en[t];
#pragma unroll
      for (int g = 0; g < 8; ++g) a += partA[g][t];
      n0[t] = a;
    }
    __syncthreads();
    if (t < 32) {
      float m = 0.f;
      for (int k = 0; k < 32; ++k) m += n0[k];
      m *= (1.f/32.f);
      float vv = 0.f;
      for (int k = 0; k < 32; ++k) { float dd = n0[k] - m; vv += dd*dd; }
      vv *= (1.f/32.f);
      tn[t] = (n0[t] - m) / sqrtf(vv + 1e-5f);
    }
    __syncthreads();
    if (t < 64) {
      float a = bn1[t];
      for (int k = 0; k < 32; ++k) a = fmaf(tn[k], Wn1[k*64 + t], a);
      hh[t] = fmaxf(a, 0.f);
    }
    __syncthreads();
    if (t < 32) {
      float a = n0[t] + bn2[t];
      for (int k = 0; k < 64; ++k) a = fmaf(hh[k], Wn2[k*32 + t], a);
      n1v[t] = a;
    }
    __syncthreads();
    if (t < 32) {
      float m = 0.f;
      for (int k = 0; k < 32; ++k) m += n1v[k];
      m *= (1.f/32.f);
      float vv = 0.f;
      for (int k = 0; k < 32; ++k) { float dd = n1v[k] - m; vv += dd*dd; }
      vv *= (1.f/32.f);
      const float nv = (n1v[t] - m) / sqrtf(vv + 1e-5f);
      nodeo[i*32 + t] = nv;
      nfin[t] = nv;
    }
    __syncthreads();
    if (t < 16) nodeb[i*16 + t] = bfpack(nfin[2*t], nfin[2*t+1]);
    {  // nim = bm1 + node_ln @ Wm1[0:32] (per-residue hoist of m1's ni-term)
      const int c = t & 63, g = t >> 6;
      float p = 0.f;
      for (int k = g*8; k < g*8 + 8; ++k) p = fmaf(nfin[k], Wm1[k*64 + c], p);
      partN[g][c] = p;
    }
    __syncthreads();
    if (t < 64)
      nim[i*64 + t] = bm1[t] + partN[0][t] + partN[1][t] + partN[2][t] + partN[3][t];
    return;
  }

  if (bid < 2*LL) {
    // ================= B: radix select =================
    const int i = bid - LL;
    const int lane = t & 63, wv = t >> 6;

    const float cix = xyz[i*9+3], ciy = xyz[i*9+4], ciz = xyz[i*9+5];
    unsigned key[3];
#pragma unroll
    for (int r = 0; r < 3; ++r) {
      const int j = r*256 + t;
      float dx = __fadd_rn(cix, -xyz[j*9+3]);
      float dy = __fadd_rn(ciy, -xyz[j*9+4]);
      float dz = __fadd_rn(ciz, -xyz[j*9+5]);
      float Dv = sqrtf(__fadd_rn(__fadd_rn(__fadd_rn(__fmul_rn(dx,dx),
                         __fmul_rn(dy,dy)), __fmul_rn(dz,dz)), 1e-8f));
      key[r] = __float_as_uint(Dv);
    }

    unsigned prefix = 0;
    int rank = 127, cntLess = 0;
#pragma unroll
    for (int pass = 0; pass < 4; ++pass) {
      const int shift = 24 - pass*8;
      const unsigned hiMask = (pass == 0) ? 0u : (0xFFFFFFFFu << (shift + 8));
      hist[t] = 0;
      __syncthreads();
#pragma unroll
      for (int r = 0; r < 3; ++r)
        if ((key[r] & hiMask) == (prefix & hiMask))
          atomicAdd(&hist[(key[r] >> shift) & 0xffu], 1u);
      __syncthreads();
      if (t < 64) {
        unsigned s0 = hist[t*4], s1 = hist[t*4+1], s2 = hist[t*4+2], s3 = hist[t*4+3];
        int tot = (int)(s0 + s1 + s2 + s3);
        int inc = tot;
#pragma unroll
        for (int o = 1; o < 64; o <<= 1) {
          int v = __shfl_up(inc, o);
          if (t >= o) inc += v;
        }
        int excl = inc - tot;
        if (rank >= excl && rank < inc) {
          int c = excl, bsel = t*4;
          if (rank >= c + (int)s0) { c += (int)s0; bsel = t*4+1;
            if (rank >= c + (int)s1) { c += (int)s1; bsel = t*4+2;
              if (rank >= c + (int)s2) { c += (int)s2; bsel = t*4+3; } } }
          selBin = bsel; below = c;
        }
      }
      __syncthreads();
      prefix |= ((unsigned)selBin) << shift;
      rank -= below;
      cntLess += below;
      __syncthreads();
    }
    const unsigned thr = prefix;

    const unsigned long long lmask = (1ull << lane) - 1ull;
    unsigned baseLt = 0, baseEq = (unsigned)cntLess;
#pragma unroll
    for (int r = 0; r < 3; ++r) {
      const int j = r*256 + t;
      const bool pl = key[r] < thr;
      const bool pe = key[r] == thr;
      unsigned long long balL = __ballot(pl);
      unsigned long long balE = __ballot(pe);
      unsigned preL = (unsigned)__popcll(balL & lmask);
      unsigned preE = (unsigned)__popcll(balE & lmask);
      if (lane == 0) { wcL[wv] = (unsigned)__popcll(balL); wcE[wv] = (unsigned)__popcll(balE); }
      __syncthreads();
      unsigned wbL = 0, wbE = 0, totL = 0, totE = 0;
#pragma unroll
      for (int w = 0; w < 4; ++w) {
        if (w < wv) { wbL += wcL[w]; wbE += wcE[w]; }
        totL += wcL[w]; totE += wcE[w];
      }
      if (pl) nbr[i*TOPK + baseLt + wbL + preL] = j;
      if (pe) {
        unsigned pos = baseEq + wbE + preE;
        if (pos < TOPK) nbr[i*TOPK + pos] = j;
      }
      baseLt += totL; baseEq += totE;
      __syncthreads();
    }
    return;
  }

  // ================= P: colsum + MFMA B-fragment weight packing ============
  {
    const int c = t & 31, sg = t >> 5;
    float s = 0.f;
    for (int k = sg*16; k < sg*16 + 16; ++k) s += W_ee[k*32 + c];
    partA[sg][c] = s;
    __syncthreads();
    if (t < 32) {
      float tot = 0.f;
#pragma unroll
      for (int g = 0; g < 8; ++g) tot += partA[g][t];
      colsum_ee[t] = tot;
    }

    // 34 B-frags: lane l holds W[kb+(l>>4)*8 + 2d .. +2d+1][ct*16 + (l&15)]
    const int lane6 = t & 63;
    for (int f = t >> 6; f < 34; f += 4) {
      const float* W; int N, krow0, ct;
      if (f < 4)       { W = We1;  N = 64; krow0 = 0;                    ct = f;        }
      else if (f < 8)  { W = We2;  N = 32; krow0 = ((f-4)>>1)*32;        ct = (f-4)&1;  }
      else if (f < 12) { W = Wm1;  N = 64; krow0 = 32;                   ct = f-8;      }
      else if (f < 16) { W = Wm1;  N = 64; krow0 = 64;                   ct = f-12;     }
      else if (f < 22) { W = Wm2;  N = 40; krow0 = ((f-16)/3)*32;        ct = (f-16)%3; }
      else if (f < 30) { W = W_ee; N = 32; krow0 = ((f-22)>>1)*32;       ct = (f-22)&1; }
      else             { W = W_ee; N = 32; krow0 = 128 + ((f-30)>>1)*32; ct = (f-30)&1; }
      const int cc = ct*16 + (lane6 & 15);
      const int kb = krow0 + ((lane6 >> 4) << 3);
#pragma unroll
      for (int d = 0; d < 4; ++d) {
        const int k = kb + 2*d;
        const float lo = (cc < N) ? W[k*N + cc]     : 0.f;
        const float hi = (cc < N) ? W[(k+1)*N + cc] : 0.f;
        pkws[f*256 + lane6*4 + d] = bfpack(lo, hi);
      }
    }
  }
}

// ---------------- Kernel C: 64 edges/block, MFMA chain, 5 blocks/CU --------
__global__ __launch_bounds__(256, 5) void kernC(
    const float* __restrict__ pair, const float* __restrict__ xyz,
    const int* __restrict__ idx,
    const float* __restrict__ W_ee, const float* __restrict__ b_ee,
    const float* __restrict__ colsum_ee,
    const float* __restrict__ be1, const float* __restrict__ be2,
    const int* __restrict__ nbr, const float* __restrict__ nim,
    const unsigned* __restrict__ nodeb, const float* __restrict__ bm2,
    const unsigned* __restrict__ pkws, float* __restrict__ fin2)
{
  const int i = blockIdx.x >> 1, part = blockIdx.x & 1;
  const int t = threadIdx.x, lane = t & 63;
  const int wv = __builtin_amdgcn_readfirstlane(t >> 6);   // uniform 0..3
  __shared__ unsigned Ab[64][17];      // e0 -> ed -> e2 -> ed2 (bf16 pairs)
  __shared__ unsigned U[64*65];        // pairB[64][65]; Bb[64][33] reuses
  __shared__ unsigned nd[64][17];      // node rows (bf16 pairs)
  __shared__ int   jl[64];
  __shared__ float Dvv[64], xsepv[64];
  __shared__ float relv[64][3];
  __shared__ float nimS[64];
  __shared__ float pmv[64], prsv[64];
  __shared__ float mA[64], sgA[64];
  __shared__ float P2[4][44];

  // ---- phase 0: stage nd (pre-packed), nimS, jl, relv, Dv, xsep ----
  if (t >= 128 && t < 192) nimS[t-128] = nim[i*64 + (t-128)];
  if (t < 128) {
    const int pp = t >> 1, hh2 = t & 1;
    const int jj = nbr[i*TOPK + part*64 + pp];
    const u32x4_t* src = (const u32x4_t*)(nodeb + jj*16 + hh2*8);
    u32x4_t a0 = src[0], a1 = src[1];
    unsigned* dst = &nd[pp][hh2*8];
    dst[0]=a0.x; dst[1]=a0.y; dst[2]=a0.z; dst[3]=a0.w;
    dst[4]=a1.x; dst[5]=a1.y; dst[6]=a1.z; dst[7]=a1.w;
    if (hh2 == 0) {
      jl[pp] = jj;
      const float cix = xyz[i*9+3], ciy = xyz[i*9+4], ciz = xyz[i*9+5];
      const float cjx = xyz[jj*9+3], cjy = xyz[jj*9+4], cjz = xyz[jj*9+5];
      relv[pp][0] = cjx - cix;
      relv[pp][1] = cjy - ciy;
      relv[pp][2] = cjz - ciz;
      const float dx = __fadd_rn(cix, -cjx), dy = __fadd_rn(ciy, -cjy),
                  dz = __fadd_rn(ciz, -cjz);
      Dvv[pp] = sqrtf(__fadd_rn(__fadd_rn(__fadd_rn(__fmul_rn(dx,dx),
                        __fmul_rn(dy,dy)), __fmul_rn(dz,dz)), 1e-8f));
      const float offv = (float)(idx[jj] - idx[i]);
      const float sg = (offv > 0.f) ? 1.f : ((offv < 0.f) ? -1.f : 0.f);
      xsepv[pp] = sg * logf(fabsf(offv) + 1.f);
    }
  }
  __syncthreads();

  // ---- C1 staging: 64 pair rows -> bf16 LDS (single pass) ----
  unsigned (*pairB)[65] = (unsigned (*)[65])U;
  {
    const int r = t >> 2, qq = t & 3;
    const float* prow = pair + ((size_t)i*LL + jl[r])*128 + qq*32;
    float s = 0.f, ss = 0.f;
#pragma unroll
    for (int n = 0; n < 8; ++n) {
      float4 v = ((const float4*)prow)[n];
      s  += (v.x + v.y) + (v.z + v.w);
      ss += v.x*v.x + v.y*v.y + v.z*v.z + v.w*v.w;
      pairB[r][qq*16 + n*2]     = bfpack(v.x, v.y);
      pairB[r][qq*16 + n*2 + 1] = bfpack(v.z, v.w);
    }
    s  += __shfl_xor(s, 1);  s  += __shfl_xor(s, 2);
    ss += __shfl_xor(ss, 1); ss += __shfl_xor(ss, 2);
    if (qq == 0) {
      const float pm = s * (1.f/128.f);
      const float pv = ss * (1.f/128.f) - pm*pm;
      pmv[r] = pm; prsv[r] = 1.f / sqrtf(pv + 1e-5f);
    }
  }
  __syncthreads();

  const f32x4_t fz = {0.f, 0.f, 0.f, 0.f};

  // ---- C1 MFMA: wave wv owns m-tile wv (16 edges), both col-tiles ----
  {
    const int col = lane & 15, rg = lane >> 4;
    const int eM = wv*16;
    f32x4_t accP[2] = {fz, fz}, accR[2] = {fz, fz};
#pragma unroll
    for (int ks = 0; ks < 4; ++ks) {   // pair part: K=128
      u32x4_t av;
      const unsigned* rp = &pairB[eM + col][ks*16 + rg*4];
      av.x = rp[0]; av.y = rp[1]; av.z = rp[2]; av.w = rp[3];
      const bf16x8_t af = __builtin_bit_cast(bf16x8_t, av);
#pragma unroll
      for (int ct = 0; ct < 2; ++ct) {
        const u32x4_t bv = ((const u32x4_t*)(pkws + (22 + ks*2 + ct)*256))[lane];
        accP[ct] = __builtin_amdgcn_mfma_f32_16x16x32_bf16(
            af, __builtin_bit_cast(bf16x8_t, bv), accP[ct], 0, 0, 0);
      }
    }
    const float Dv = Dvv[eM + col];
#pragma unroll
    for (int ks = 0; ks < 2; ++ks) {   // RBF part: K=64, A in-register
      u32x4_t av;
#pragma unroll
      for (int d = 0; d < 4; ++d) {
        const int k = ks*32 + rg*8 + 2*d;
        const float mu0 = 2.f + (float)k     * (20.f/63.f);
        const float mu1 = 2.f + (float)(k+1) * (20.f/63.f);
        const float u0 = (Dv - mu0) / 0.3125f;
        const float u1 = (Dv - mu1) / 0.3125f;
        ((unsigned*)&av)[d] = bfpack(expf(-(u0*u0)), expf(-(u1*u1)));
      }
      const bf16x8_t af = __builtin_bit_cast(bf16x8_t, av);
#pragma unroll
      for (int ct = 0; ct < 2; ++ct) {
        const u32x4_t bv = ((const u32x4_t*)(pkws + (30 + ks*2 + ct)*256))[lane];
        accR[ct] = __builtin_amdgcn_mfma_f32_16x16x32_bf16(
            af, __builtin_bit_cast(bf16x8_t, bv), accR[ct], 0, 0, 0);
      }
    }
#pragma unroll
    for (int ct = 0; ct < 2; ++ct) {
      const int ch = ct*16 + col;
      const float cs = colsum_ee[ch];
      const float w3 = W_ee[192*32 + ch];
      const float bb = b_ee[ch];
#pragma unroll
      for (int j = 0; j < 4; ++j) {
        const int e = eM + rg*4 + j;
        const float prs = prsv[e], pm = pmv[e];
        float v = fmaf(prs, accP[ct][j],
                   fmaf(-prs*pm, cs,
                     fmaf(xsepv[e], w3, bb + accR[ct][j])));
        const float p = __shfl_xor(v, 1);
        if (!(lane & 1)) Ab[e][ct*8 + (col >> 1)] = bfpack(v, p);
      }
    }
  }
  __syncthreads();

  // ---- MFMA MLP chain: wave wv owns edges [16wv, 16wv+16); NO barriers ----
  unsigned (*Bb)[33] = (unsigned (*)[33])U;
  {
    const int e0b = 16 * wv;
    const int row = lane & 15;    // A M-row / D N-col
    const int kg  = lane >> 4;    // k-group
    const int r0  = kg * 4;       // D M-row base

    // LN(Ab) per-wave: 4 lanes per edge (16 edges)
    {
      const int eL = e0b + row;
      float av[8];
#pragma unroll
      for (int kk = 0; kk < 4; ++kk) {
        const unsigned v = Ab[eL][kg*4 + kk];
        av[2*kk] = bflo(v); av[2*kk+1] = bfhi(v);
      }
      float s = 0.f;
#pragma unroll
      for (int c = 0; c < 8; ++c) s += av[c];
      s += __shfl_xor(s, 16); s += __shfl_xor(s, 32);
      const float mm = s * (1.f/32.f);
      float vv = 0.f;
#pragma unroll
      for (int c = 0; c < 8; ++c) { const float dd = av[c] - mm; vv += dd*dd; }
      vv += __shfl_xor(vv, 16); vv += __shfl_xor(vv, 32);
      vv *= (1.f/32.f);
      const float sg = sqrtf(vv + 1e-5f);
      const float rs = 1.f / sg;
#pragma unroll
      for (int kk = 0; kk < 4; ++kk)
        Ab[eL][kg*4 + kk] = bfpack((av[2*kk]-mm)*rs, (av[2*kk+1]-mm)*rs);
      if (kg == 0) { mA[eL] = mm; sgA[eL] = sg; }
    }

    // ---- h = relu(ed @ We1 + be1): MFMA, K=32, N=64 ----
    {
      u32x4_t av4;
      const unsigned* rp = &Ab[e0b + row][0];
      av4.x = rp[kg*4]; av4.y = rp[kg*4+1]; av4.z = rp[kg*4+2]; av4.w = rp[kg*4+3];
      const bf16x8_t af = __builtin_bit_cast(bf16x8_t, av4);
      f32x4_t acc[4];
#pragma unroll
      for (int ct = 0; ct < 4; ++ct) {
        const u32x4_t bv = ((const u32x4_t*)(pkws + (0 + ct)*256))[lane];
        acc[ct] = __builtin_amdgcn_mfma_f32_16x16x32_bf16(
            af, __builtin_bit_cast(bf16x8_t, bv), fz, 0, 0, 0);
      }
#pragma unroll
      for (int ct = 0; ct < 4; ++ct) {
        const int ch = ct*16 + row;
#pragma unroll
        for (int j = 0; j < 4; ++j) {
          float v = fmaxf(acc[ct][j] + be1[ch], 0.f);
          const float p = __shfl_xor(v, 1);
          if (!(lane & 1))
            Bb[e0b + r0 + j][ct*8 + (row >> 1)] = bfpack(v, p);
        }
      }
    }

    // ---- e2 = e0raw + h @ We2 + be2: MFMA, K=64, N=32 ----
    {
      f32x4_t acc[2] = {fz, fz};
#pragma unroll
      for (int ks = 0; ks < 2; ++ks) {
        u32x4_t av4;
        const unsigned* rp = &Bb[e0b + row][0];
        const int kd = ks*16 + kg*4;
        av4.x = rp[kd]; av4.y = rp[kd+1]; av4.z = rp[kd+2]; av4.w = rp[kd+3];
        const bf16x8_t af = __builtin_bit_cast(bf16x8_t, av4);
#pragma unroll
        for (int ct = 0; ct < 2; ++ct) {
          const u32x4_t bv = ((const u32x4_t*)(pkws + (4 + ks*2 + ct)*256))[lane];
          acc[ct] = __builtin_amdgcn_mfma_f32_16x16x32_bf16(
              af, __builtin_bit_cast(bf16x8_t, bv), acc[ct], 0, 0, 0);
        }
      }
#pragma unroll
      for (int ct = 0; ct < 2; ++ct) {
        const int ch = ct*16 + row;
        const int dw = ct*8 + (row >> 1);
#pragma unroll
        for (int j = 0; j < 4; ++j) {
          const int e = e0b + r0 + j;
          const unsigned old = Ab[e][dw];
          const float e0v = (lane & 1) ? bfhi(old) : bflo(old);
          float v = acc[ct][j] + fmaf(e0v, sgA[e], mA[e]) + be2[ch];
          const float p = __shfl_xor(v, 1);
          if (!(lane & 1)) Ab[e][dw] = bfpack(v, p);
        }
      }
    }

    // LN(e2) per-wave
    {
      const int eL = e0b + row;
      float av[8];
#pragma unroll
      for (int kk = 0; kk < 4; ++kk) {
        const unsigned v = Ab[eL][kg*4 + kk];
        av[2*kk] = bflo(v); av[2*kk+1] = bfhi(v);
      }
      float s = 0.f;
#pragma unroll
      for (int c = 0; c < 8; ++c) s += av[c];
      s += __shfl_xor(s, 16); s += __shfl_xor(s, 32);
      const float mm = s * (1.f/32.f);
      float vv = 0.f;
#pragma unroll
      for (int c = 0; c < 8; ++c) { const float dd = av[c] - mm; vv += dd*dd; }
      vv += __shfl_xor(vv, 16); vv += __shfl_xor(vv, 32);
      vv *= (1.f/32.f);
      const float rs = 1.f / sqrtf(vv + 1e-5f);
#pragma unroll
      for (int kk = 0; kk < 4; ++kk)
        Ab[eL][kg*4 + kk] = bfpack((av[2*kk]-mm)*rs, (av[2*kk+1]-mm)*rs);
    }

    // ---- m1 = relu(nim + nd@Wm1[32:64] + ed2@Wm1[64:96]) ----
    {
      u32x4_t aN, aE;
      const unsigned* rn = &nd[e0b + row][0];
      aN.x = rn[kg*4]; aN.y = rn[kg*4+1]; aN.z = rn[kg*4+2]; aN.w = rn[kg*4+3];
      const unsigned* ra = &Ab[e0b + row][0];
      aE.x = ra[kg*4]; aE.y = ra[kg*4+1]; aE.z = ra[kg*4+2]; aE.w = ra[kg*4+3];
      const bf16x8_t afN = __builtin_bit_cast(bf16x8_t, aN);
      const bf16x8_t afE = __builtin_bit_cast(bf16x8_t, aE);
      f32x4_t acc[4];
#pragma unroll
      for (int ct = 0; ct < 4; ++ct) {
        const u32x4_t bN = ((const u32x4_t*)(pkws + (8 + ct)*256))[lane];
        const u32x4_t bE = ((const u32x4_t*)(pkws + (12 + ct)*256))[lane];
        acc[ct] = __builtin_amdgcn_mfma_f32_16x16x32_bf16(
            afN, __builtin_bit_cast(bf16x8_t, bN), fz, 0, 0, 0);
        acc[ct] = __builtin_amdgcn_mfma_f32_16x16x32_bf16(
            afE, __builtin_bit_cast(bf16x8_t, bE), acc[ct], 0, 0, 0);
      }
#pragma unroll
      for (int ct = 0; ct < 4; ++ct) {
        const int ch = ct*16 + row;
        const float tb = nimS[ch];
#pragma unroll
        for (int j = 0; j < 4; ++j) {
          float v = fmaxf(acc[ct][j] + tb, 0.f);
          const float p = __shfl_xor(v, 1);
          if (!(lane & 1))
            Bb[e0b + r0 + j][ct*8 + (row >> 1)] = bfpack(v, p);
        }
      }
    }

    // ---- m2: MFMA K=64, N=48 (40 valid) + expand + wave reduce ----
    {
      f32x4_t acc[3] = {fz, fz, fz};
#pragma unroll
      for (int ks = 0; ks < 2; ++ks) {
        u32x4_t av4;
        const unsigned* rp = &Bb[e0b + row][0];
        const int kd = ks*16 + kg*4;
        av4.x = rp[kd]; av4.y = rp[kd+1]; av4.z = rp[kd+2]; av4.w = rp[kd+3];
        const bf16x8_t af = __builtin_bit_cast(bf16x8_t, av4);
#pragma unroll
        for (int ct = 0; ct < 3; ++ct) {
          const u32x4_t bv = ((const u32x4_t*)(pkws + (16 + ks*3 + ct)*256))[lane];
          acc[ct] = __builtin_amdgcn_mfma_f32_16x16x32_bf16(
              af, __builtin_bit_cast(bf16x8_t, bv), acc[ct], 0, 0, 0);
        }
      }
      float plain[3] = {0.f, 0.f, 0.f};
      float rel3[3]  = {0.f, 0.f, 0.f};
#pragma unroll
      for (int ct = 0; ct < 3; ++ct) {
        const int o = ct*16 + row;
        if (ct == 2 && row >= 8) continue;   // o >= 40
#pragma unroll
        for (int j = 0; j < 4; ++j) {
          const int e = e0b + r0 + j;
          const float v = acc[ct][j] + bm2[o];
          if (ct == 2 && row < 2) {
            rel3[0] = fmaf(v, relv[e][0], rel3[0]);
            rel3[1] = fmaf(v, relv[e][1], rel3[1]);
            rel3[2] = fmaf(v, relv[e][2], rel3[2]);
          } else {
            plain[ct] += v;
          }
        }
      }
#pragma unroll
      for (int d = 0; d < 3; ++d) {
        plain[d] += __shfl_xor(plain[d], 16); plain[d] += __shfl_xor(plain[d], 32);
        rel3[d]  += __shfl_xor(rel3[d], 16);  rel3[d]  += __shfl_xor(rel3[d], 32);
      }
      if (lane < 16) {
        P2[wv][lane]      = plain[0];
        P2[wv][16 + lane] = plain[1];
        if (lane < 2) {
#pragma unroll
          for (int d = 0; d < 3; ++d) P2[wv][32 + lane*3 + d] = rel3[d];
        } else if (lane < 8) {
          P2[wv][38 + lane - 2] = plain[2];
        }
      }
    }
  }
  __syncthreads();
  if (t < 44)
    fin2[(size_t)(i*2 + part)*44 + t] = P2[0][t] + P2[1][t] + P2[2][t] + P2[3][t];
}

// ---------------- Kernel D: epilogue (state_out/frame) + si MLP -> alpha ----
__global__ __launch_bounds__(512) void kernD(
    const float* __restrict__ seq_ln, const float* __restrict__ xyz,
    const unsigned char* __restrict__ rmask,
    const float* __restrict__ Wl0, const float* __restrict__ bl0,
    const float* __restrict__ node, const float* __restrict__ fin2,
    const float* __restrict__ Ws0, const float* __restrict__ bs0,
    const float* __restrict__ Wsi, const float* __restrict__ bsi,
    const float* __restrict__ Wp1, const float* __restrict__ bp1,
    const float* __restrict__ Wp2, const float* __restrict__ bp2,
    const float* __restrict__ Wp3, const float* __restrict__ bp3,
    const float* __restrict__ Wp4, const float* __restrict__ bp4,
    const float* __restrict__ Wout, const float* __restrict__ bout,
    float* __restrict__ out)
{
  const int i = blockIdx.x, t = threadIdx.x;
  const int c = t & 127, g = t >> 7;
  __shared__ float fin[44], niD[32], sout_s[16], stn[16];
  __shared__ float x0[256], act[128], resid[128], part[4][129];

  if (t < 44) fin[t] = fin2[(size_t)(i*2)*44 + t] + fin2[(size_t)(i*2+1)*44 + t];
  if (t >= 64 && t < 96) niD[t-64] = node[i*32 + (t-64)];
  if (t >= 256) x0[t-256] = seq_ln[i*256 + (t-256)];
  else if (t >= 128) x0[t] = seq_ln[i*256 + t];
  __syncthreads();

  if (t < 16) {  // state_out = [node_i, m_l0] @ Wl0 + bl0
    float a = bl0[t];
#pragma unroll
    for (int k = 0; k < 32; ++k) a = fmaf(niD[k], Wl0[k*16 + t], a);
#pragma unroll
    for (int k = 0; k < 32; ++k) a = fmaf(fin[k] * (1.f/128.f), Wl0[(32+k)*16 + t], a);
    sout_s[t] = a;
    out[LL*9 + i*16 + t] = a;
  }
  if (t == 32) {  // frame update
    float ve[6], wa[6];
#pragma unroll
    for (int qq = 0; qq < 6; ++qq) ve[qq] = fin[32 + qq] * (1.f/128.f);
#pragma unroll
    for (int qq = 0; qq < 6; ++qq) wa[qq] = fin[38 + qq] * (1.f/128.f);
    float l1[9];
#pragma unroll
    for (int a = 0; a < 3; ++a)
#pragma unroll
      for (int d = 0; d < 3; ++d) l1[a*3 + d] = xyz[i*9 + a*3 + d] - xyz[i*9 + 3 + d];
    float T[3], Rv[3];
#pragma unroll
    for (int d = 0; d < 3; ++d) {
      float va0 = wa[0]*l1[d] + wa[1]*l1[3 + d] + wa[2]*l1[6 + d];
      float va1 = wa[3]*l1[d] + wa[4]*l1[3 + d] + wa[5]*l1[6 + d];
      T[d]  = (ve[d] + va0) / 10.f;
      Rv[d] = (ve[3 + d] + va1) / 100.f;
    }
    float qn = sqrtf(1.f + Rv[0]*Rv[0] + Rv[1]*Rv[1] + Rv[2]*Rv[2]);
    float qA = 1.f/qn, qB = Rv[0]/qn, qC = Rv[1]/qn, qD = Rv[2]/qn;
    float Rm[9];
    Rm[0] = qA*qA + qB*qB - qC*qC - qD*qD;
    Rm[1] = 2.f*qB*qC - 2.f*qA*qD;
    Rm[2] = 2.f*qB*qD + 2.f*qA*qC;
    Rm[3] = 2.f*qB*qC + 2.f*qA*qD;
    Rm[4] = qA*qA - qB*qB + qC*qC - qD*qD;
    Rm[5] = 2.f*qC*qD - 2.f*qA*qB;
    Rm[6] = 2.f*qB*qD - 2.f*qA*qC;
    Rm[7] = 2.f*qC*qD + 2.f*qA*qB;
    Rm[8] = qA*qA - qB*qB - qC*qC + qD*qD;
    if (rmask[i]) {
      Rm[0] = 1.f; Rm[1] = 0.f; Rm[2] = 0.f;
      Rm[3] = 0.f; Rm[4] = 1.f; Rm[5] = 0.f;
      Rm[6] = 0.f; Rm[7] = 0.f; Rm[8] = 1.f;
    }
#pragma unroll
    for (int a = 0; a < 3; ++a)
#pragma unroll
      for (int di = 0; di < 3; ++di) {
        float xn = Rm[di*3+0]*l1[a*3+0] + Rm[di*3+1]*l1[a*3+1] + Rm[di*3+2]*l1[a*3+2]
                 + xyz[i*9 + 3 + di] + T[di];
        out[i*9 + a*3 + di] = xn;
      }
  }
  __syncthreads();

  if (t < 16) {
    float m = 0.f;
    for (int k = 0; k < 16; ++k) m += sout_s[k];
    m *= (1.f/16.f);
    float v = 0.f;
    for (int k = 0; k < 16; ++k) { float dd = sout_s[k] - m; v += dd*dd; }
    v *= (1.f/16.f);
    stn[t] = (sout_s[t] - m) / sqrtf(v + 1e-5f);
  }
  __syncthreads();

  // L0: si = x0 @ Ws0 + stn @ Wsi + bs0 + bsi
  {
    float p = 0.f;
    for (int k = g*64; k < g*64 + 64; ++k) p = fmaf(x0[k], Ws0[k*128 + c], p);
    if (g == 0)
      for (int k = 0; k < 16; ++k) p = fmaf(stn[k], Wsi[k*128 + c], p);
    part[g][c] = p;
  }
  __syncthreads();
  if (t < 128) {
    const float si = part[0][t] + part[1][t] + part[2][t] + part[3][t]
                   + bs0[t] + bsi[t];
    resid[t] = si;
    act[t] = fmaxf(si, 0.f);
  }
  __syncthreads();

  {
    float p = 0.f;
    for (int k = g*32; k < g*32 + 32; ++k) p = fmaf(act[k], Wp1[k*128 + c], p);
    part[g][c] = p;
  }
  __syncthreads();
  if (t < 128)
    act[t] = fmaxf(part[0][t] + part[1][t] + part[2][t] + part[3][t] + bp1[t], 0.f);
  __syncthreads();

  {
    float p = 0.f;
    for (int k = g*32; k < g*32 + 32; ++k) p = fmaf(act[k], Wp2[k*128 + c], p);
    part[g][c] = p;
  }
  __syncthreads();
  if (t < 128) {
    const float si = resid[t] + part[0][t] + part[1][t] + part[2][t] + part[3][t] + bp2[t];
    resid[t] = si;
    act[t] = fmaxf(si, 0.f);
  }
  __syncthreads();

  {
    float p = 0.f;
    for (int k = g*32; k < g*32 + 32; ++k) p = fmaf(act[k], Wp3[k*128 + c], p);
    part[g][c] = p;
  }
  __syncthreads();
  if (t < 128)
    act[t] = fmaxf(part[0][t] + part[1][t] + part[2][t] + part[3][t] + bp3[t], 0.f);
  __syncthreads();

  {
    float p = 0.f;
    for (int k = g*32; k < g*32 + 32; ++k) p = fmaf(act[k], Wp4[k*128 + c], p);
    part[g][c] = p;
  }
  __syncthreads();
  if (t < 128)
    act[t] = fmaxf(resid[t] + part[0][t] + part[1][t] + part[2][t] + part[3][t] + bp4[t], 0.f);
  __syncthreads();

  if (t < 20) {
    float a = bout[t];
    for (int k = 0; k < 128; ++k) a = fmaf(act[k], Wout[k*20 + t], a);
    out[19200 + i*20 + t] = a;
  }
}

extern "C" void kernel_launch(void* const* d_in, const int* in_sizes, int n_in,
                              void* d_out, int out_size, void* d_ws, size_t ws_size,
                              hipStream_t stream)
{
  (void)in_sizes; (void)n_in; (void)out_size; (void)ws_size;
  const float* msa   = (const float*)d_in[0];
  const float* pair  = (const float*)d_in[1];
  const float* xyz   = (const float*)d_in[2];
  const float* state = (const float*)d_in[3];
  const int*   idx   = (const int*)d_in[4];
  const unsigned char* rmask = (const unsigned char*)d_in[5];
  const float* W_en = (const float*)d_in[6];
  const float* b_en = (const float*)d_in[7];
  const float* Wn1  = (const float*)d_in[8];
  const float* bn1  = (const float*)d_in[9];
  const float* Wn2  = (const float*)d_in[10];
  const float* bn2  = (const float*)d_in[11];
  const float* W_ee = (const float*)d_in[12];
  const float* b_ee = (const float*)d_in[13];
  const float* We1  = (const float*)d_in[14];
  const float* be1  = (const float*)d_in[15];
  const float* We2  = (const float*)d_in[16];
  const float* be2  = (const float*)d_in[17];
  const float* Wm1  = (const float*)d_in[18];
  const float* bm1  = (const float*)d_in[19];
  const float* Wm2  = (const float*)d_in[20];
  const float* bm2  = (const float*)d_in[21];
  const float* Wl0  = (const float*)d_in[22];
  const float* bl0  = (const float*)d_in[23];
  const float* Ws0  = (const float*)d_in[24];
  const float* bs0  = (const float*)d_in[25];
  const float* Wsi  = (const float*)d_in[26];
  const float* bsi  = (const float*)d_in[27];
  const float* Wp1  = (const float*)d_in[28];
  const float* bp1  = (const float*)d_in[29];
  const float* Wp2  = (const float*)d_in[30];
  const float* bp2  = (const float*)d_in[31];
  const float* Wp3  = (const float*)d_in[32];
  const float* bp3  = (const float*)d_in[33];
  const float* Wp4  = (const float*)d_in[34];
  const float* bp4  = (const float*)d_in[35];
  const float* Wout = (const float*)d_in[36];
  const float* bout = (const float*)d_in[37];

  float* wsf    = (float*)d_ws;
  float* seq_ln = wsf + WS_SEQ;
  float* nodev  = wsf + WS_NODE;
  int*   nbr    = (int*)(wsf + WS_NBR);
  float* csee   = wsf + WS_CSEE;
  float* fin2   = wsf + WS_FIN;
  float* nim    = wsf + WS_NIM;
  unsigned* nodeb = (unsigned*)(wsf + WS_NODEB);
  unsigned* pkws  = (unsigned*)(wsf + WS_PK);
  float* out = (float*)d_out;

  kernABP<<<2*LL + 1, 256, 0, stream>>>(msa, state, W_en, b_en, Wn1, bn1, Wn2, bn2,
                                        xyz, W_ee, We1, We2, Wm1, bm1, Wm2,
                                        seq_ln, nodev, nbr, csee, nim, nodeb, pkws);
  kernC<<<2*LL, 256, 0, stream>>>(pair, xyz, idx, W_ee, b_ee, csee,
                                  be1, be2, nbr, nim, nodeb, bm2, pkws, fin2);
  kernD<<<LL, 512, 0, stream>>>(seq_ln, xyz, rmask, Wl0, bl0, nodev, fin2,
                                Ws0, bs0, Wsi, bsi, Wp1, bp1, Wp2, bp2,
                                Wp3, bp3, Wp4, bp4, Wout, bout, out);
}

// Round 18
// 71.180 us; speedup vs baseline: 2.3920x; 1.0140x over previous
//
#include <hip/hip_runtime.h>
#include <hip/hip_bf16.h>

#define LL 768
#define TOPK 128

// workspace layout (floats)
#define WS_SEQ   0                         // 768*256
#define WS_NODE  (WS_SEQ + LL*256)         // 768*32
#define WS_NBR   (WS_NODE + LL*32)         // 768*128 ints
#define WS_CSEE  (WS_NBR + LL*TOPK)        // 32
#define WS_FIN   (WS_CSEE + 32)            // 768*2*44
#define WS_NIM   (WS_FIN + LL*2*44)        // 768*64
#define WS_NODEB (WS_NIM + LL*64)          // 768*16 (u32)
#define WS_PK    (WS_NODEB + LL*16)        // 34 frags x 256 dwords

typedef __attribute__((ext_vector_type(8))) short  bf16x8_t;
typedef __attribute__((ext_vector_type(4))) float  f32x4_t;
typedef __attribute__((ext_vector_type(4))) unsigned u32x4_t;

// bf16 pair pack/unpack (RNE)
__device__ __forceinline__ unsigned bfpack(float a, float b) {
  unsigned ua = __float_as_uint(a);
  ua = (ua + 0x7fffu + ((ua >> 16) & 1u)) >> 16;
  unsigned ub = __float_as_uint(b);
  ub = (ub + 0x7fffu + ((ub >> 16) & 1u)) & 0xffff0000u;
  return ua | ub;
}
__device__ __forceinline__ float bflo(unsigned v) { return __uint_as_float(v << 16); }
__device__ __forceinline__ float bfhi(unsigned v) { return __uint_as_float(v & 0xffff0000u); }

__device__ __forceinline__ float block_sum_256(float v, float* red, int t) {
#pragma unroll
  for (int o = 32; o > 0; o >>= 1) v += __shfl_xor(v, o, 64);
  __syncthreads();
  if ((t & 63) == 0) red[t >> 6] = v;
  __syncthreads();
  return red[0] + red[1] + red[2] + red[3];
}

// ---------------- Kernel ABP: A (0..767), B (768..1535), P (1536) ----------
__global__ __launch_bounds__(256) void kernABP(
    const float* __restrict__ msa, const float* __restrict__ state,
    const float* __restrict__ W_en, const float* __restrict__ b_en,
    const float* __restrict__ Wn1, const float* __restrict__ bn1,
    const float* __restrict__ Wn2, const float* __restrict__ bn2,
    const float* __restrict__ xyz, const float* __restrict__ W_ee,
    const float* __restrict__ We1, const float* __restrict__ We2,
    const float* __restrict__ Wm1, const float* __restrict__ bm1,
    const float* __restrict__ Wm2,
    float* __restrict__ seq_ln, float* __restrict__ nodeo,
    int* __restrict__ nbr, float* __restrict__ colsum_ee,
    float* __restrict__ nim, unsigned* __restrict__ nodeb,
    unsigned* __restrict__ pkws)
{
  const int bid = blockIdx.x, t = threadIdx.x;
  __shared__ float x[256];
  __shared__ float red[4];
  __shared__ float sn[16], n0[32], tn[32], hh[64], n1v[32], nfin[32];
  __shared__ float partA[8][33];
  __shared__ float partN[4][65];
  __shared__ unsigned hist[256];
  __shared__ int selBin, below;
  __shared__ unsigned wcL[4], wcE[4];

  if (bid < LL) {
    // ================= A =================
    const int i = bid;
    float v = msa[i*256 + t];
    float mean = block_sum_256(v, red, t) * (1.f/256.f);
    float d = v - mean;
    float var = block_sum_256(d*d, red, t) * (1.f/256.f);
    float xn = d / sqrtf(var + 1e-5f);
    x[t] = xn;
    seq_ln[i*256 + t] = xn;

    if (t < 16) {
      float m2 = 0.f;
      for (int k = 0; k < 16; ++k) m2 += state[i*16 + k];
      m2 *= (1.f/16.f);
      float v2 = 0.f;
      for (int k = 0; k < 16; ++k) { float dd = state[i*16 + k] - m2; v2 += dd*dd; }
      v2 *= (1.f/16.f);
      sn[t] = (state[i*16 + t] - m2) / sqrtf(v2 + 1e-5f);
    }
    __syncthreads();

    {
      const int g = t >> 5, c = t & 31;
      float p = 0.f;
      for (int k = g*32; k < g*32 + 32; ++k) p = fmaf(x[k], W_en[k*32 + c], p);
      if (g == 7)
        for (int k = 0; k < 16; ++k) p = fmaf(sn[k], W_en[(256+k)*32 + c], p);
      partA[g][c] = p;
    }
    __syncthreads();
    if (t < 32) {
      float a = b_en[t];
#pragma unroll
      for (int g = 0; g < 8; ++g) a += partA[g][t];
      n0[t] = a;
    }
    __syncthreads();
    if (t < 32) {
      float m = 0.f;
      for (int k = 0; k < 32; ++k) m += n0[k];
      m *= (1.f/32.f);
      float vv = 0.f;
      for (int k = 0; k < 32; ++k) { float dd = n0[k] - m; vv += dd*dd; }
      vv *= (1.f/32.f);
      tn[t] = (n0[t] - m) / sqrtf(vv + 1e-5f);
    }
    __syncthreads();
    if (t < 64) {
      float a = bn1[t];
      for (int k = 0; k < 32; ++k) a = fmaf(tn[k], Wn1[k*64 + t], a);
      hh[t] = fmaxf(a, 0.f);
    }
    __syncthreads();
    if (t < 32) {
      float a = n0[t] + bn2[t];
      for (int k = 0; k < 64; ++k) a = fmaf(hh[k], Wn2[k*32 + t], a);
      n1v[t] = a;
    }
    __syncthreads();
    if (t < 32) {
      float m = 0.f;
      for (int k = 0; k < 32; ++k) m += n1v[k];
      m *= (1.f/32.f);
      float vv = 0.f;
      for (int k = 0; k < 32; ++k) { float dd = n1v[k] - m; vv += dd*dd; }
      vv *= (1.f/32.f);
      const float nv = (n1v[t] - m) / sqrtf(vv + 1e-5f);
      nodeo[i*32 + t] = nv;
      nfin[t] = nv;
    }
    __syncthreads();
    if (t < 16) nodeb[i*16 + t] = bfpack(nfin[2*t], nfin[2*t+1]);
    {  // nim = bm1 + node_ln @ Wm1[0:32]
      const int c = t & 63, g = t >> 6;
      float p = 0.f;
      for (int k = g*8; k < g*8 + 8; ++k) p = fmaf(nfin[k], Wm1[k*64 + c], p);
      partN[g][c] = p;
    }
    __syncthreads();
    if (t < 64)
      nim[i*64 + t] = bm1[t] + partN[0][t] + partN[1][t] + partN[2][t] + partN[3][t];
    return;
  }

  if (bid < 2*LL) {
    // ================= B: radix select =================
    const int i = bid - LL;
    const int lane = t & 63, wv = t >> 6;

    const float cix = xyz[i*9+3], ciy = xyz[i*9+4], ciz = xyz[i*9+5];
    unsigned key[3];
#pragma unroll
    for (int r = 0; r < 3; ++r) {
      const int j = r*256 + t;
      float dx = __fadd_rn(cix, -xyz[j*9+3]);
      float dy = __fadd_rn(ciy, -xyz[j*9+4]);
      float dz = __fadd_rn(ciz, -xyz[j*9+5]);
      float Dv = sqrtf(__fadd_rn(__fadd_rn(__fadd_rn(__fmul_rn(dx,dx),
                         __fmul_rn(dy,dy)), __fmul_rn(dz,dz)), 1e-8f));
      key[r] = __float_as_uint(Dv);
    }

    unsigned prefix = 0;
    int rank = 127, cntLess = 0;
#pragma unroll
    for (int pass = 0; pass < 4; ++pass) {
      const int shift = 24 - pass*8;
      const unsigned hiMask = (pass == 0) ? 0u : (0xFFFFFFFFu << (shift + 8));
      hist[t] = 0;
      __syncthreads();
#pragma unroll
      for (int r = 0; r < 3; ++r)
        if ((key[r] & hiMask) == (prefix & hiMask))
          atomicAdd(&hist[(key[r] >> shift) & 0xffu], 1u);
      __syncthreads();
      if (t < 64) {
        unsigned s0 = hist[t*4], s1 = hist[t*4+1], s2 = hist[t*4+2], s3 = hist[t*4+3];
        int tot = (int)(s0 + s1 + s2 + s3);
        int inc = tot;
#pragma unroll
        for (int o = 1; o < 64; o <<= 1) {
          int v = __shfl_up(inc, o);
          if (t >= o) inc += v;
        }
        int excl = inc - tot;
        if (rank >= excl && rank < inc) {
          int c = excl, bsel = t*4;
          if (rank >= c + (int)s0) { c += (int)s0; bsel = t*4+1;
            if (rank >= c + (int)s1) { c += (int)s1; bsel = t*4+2;
              if (rank >= c + (int)s2) { c += (int)s2; bsel = t*4+3; } } }
          selBin = bsel; below = c;
        }
      }
      __syncthreads();
      prefix |= ((unsigned)selBin) << shift;
      rank -= below;
      cntLess += below;
      __syncthreads();
    }
    const unsigned thr = prefix;

    const unsigned long long lmask = (1ull << lane) - 1ull;
    unsigned baseLt = 0, baseEq = (unsigned)cntLess;
#pragma unroll
    for (int r = 0; r < 3; ++r) {
      const int j = r*256 + t;
      const bool pl = key[r] < thr;
      const bool pe = key[r] == thr;
      unsigned long long balL = __ballot(pl);
      unsigned long long balE = __ballot(pe);
      unsigned preL = (unsigned)__popcll(balL & lmask);
      unsigned preE = (unsigned)__popcll(balE & lmask);
      if (lane == 0) { wcL[wv] = (unsigned)__popcll(balL); wcE[wv] = (unsigned)__popcll(balE); }
      __syncthreads();
      unsigned wbL = 0, wbE = 0, totL = 0, totE = 0;
#pragma unroll
      for (int w = 0; w < 4; ++w) {
        if (w < wv) { wbL += wcL[w]; wbE += wcE[w]; }
        totL += wcL[w]; totE += wcE[w];
      }
      if (pl) nbr[i*TOPK + baseLt + wbL + preL] = j;
      if (pe) {
        unsigned pos = baseEq + wbE + preE;
        if (pos < TOPK) nbr[i*TOPK + pos] = j;
      }
      baseLt += totL; baseEq += totE;
      __syncthreads();
    }
    return;
  }

  // ================= P: colsum + MFMA B-fragment weight packing ============
  {
    const int c = t & 31, sg = t >> 5;
    float s = 0.f;
    for (int k = sg*16; k < sg*16 + 16; ++k) s += W_ee[k*32 + c];
    partA[sg][c] = s;
    __syncthreads();
    if (t < 32) {
      float tot = 0.f;
#pragma unroll
      for (int g = 0; g < 8; ++g) tot += partA[g][t];
      colsum_ee[t] = tot;
    }

    // 34 B-frags: lane l holds W[kb+(l>>4)*8 + 2d .. +2d+1][ct*16 + (l&15)]
    const int lane6 = t & 63;
    for (int f = t >> 6; f < 34; f += 4) {
      const float* W; int N, krow0, ct;
      if (f < 4)       { W = We1;  N = 64; krow0 = 0;                    ct = f;        }
      else if (f < 8)  { W = We2;  N = 32; krow0 = ((f-4)>>1)*32;        ct = (f-4)&1;  }
      else if (f < 12) { W = Wm1;  N = 64; krow0 = 32;                   ct = f-8;      }
      else if (f < 16) { W = Wm1;  N = 64; krow0 = 64;                   ct = f-12;     }
      else if (f < 22) { W = Wm2;  N = 40; krow0 = ((f-16)/3)*32;        ct = (f-16)%3; }
      else if (f < 30) { W = W_ee; N = 32; krow0 = ((f-22)>>1)*32;       ct = (f-22)&1; }
      else             { W = W_ee; N = 32; krow0 = 128 + ((f-30)>>1)*32; ct = (f-30)&1; }
      const int cc = ct*16 + (lane6 & 15);
      const int kb = krow0 + ((lane6 >> 4) << 3);
#pragma unroll
      for (int d = 0; d < 4; ++d) {
        const int k = kb + 2*d;
        const float lo = (cc < N) ? W[k*N + cc]     : 0.f;
        const float hi = (cc < N) ? W[(k+1)*N + cc] : 0.f;
        pkws[f*256 + lane6*4 + d] = bfpack(lo, hi);
      }
    }
  }
}

// ---------------- Kernel C: 64 edges/block, MFMA chain, 5 blocks/CU --------
// Pair gather issued at kernel entry (no LDS dependency) and overlapped with
// nd/nim/geometry staging; single barrier before the MFMA chain.
__global__ __launch_bounds__(256, 5) void kernC(
    const float* __restrict__ pair, const float* __restrict__ xyz,
    const int* __restrict__ idx,
    const float* __restrict__ W_ee, const float* __restrict__ b_ee,
    const float* __restrict__ colsum_ee,
    const float* __restrict__ be1, const float* __restrict__ be2,
    const int* __restrict__ nbr, const float* __restrict__ nim,
    const unsigned* __restrict__ nodeb, const float* __restrict__ bm2,
    const unsigned* __restrict__ pkws, float* __restrict__ fin2)
{
  const int i = blockIdx.x >> 1, part = blockIdx.x & 1;
  const int t = threadIdx.x, lane = t & 63;
  const int wv = __builtin_amdgcn_readfirstlane(t >> 6);   // uniform 0..3
  __shared__ unsigned Ab[64][17];      // e0 -> ed -> e2 -> ed2 (bf16 pairs)
  __shared__ unsigned U[64*65];        // pairB[64][65]; Bb[64][33] reuses
  __shared__ unsigned nd[64][17];      // node rows (bf16 pairs)
  __shared__ float Dvv[64], xsepv[64];
  __shared__ float relv[64][3];
  __shared__ float nimS[64];
  __shared__ float pmv[64], prsv[64];
  __shared__ float mA[64], sgA[64];
  __shared__ float P2[4][44];

  // ---- fused phase 0: issue pair gather FIRST (overlaps everything) ----
  const int rS = t >> 2, qS = t & 3;
  const int jjS = nbr[i*TOPK + part*64 + rS];   // L2-hot, 4-lane broadcast
  const float* prow = pair + ((size_t)i*LL + jjS)*128 + qS*32;
  float4 pv[8];
#pragma unroll
  for (int n = 0; n < 8; ++n) pv[n] = ((const float4*)prow)[n];

  if (t >= 128 && t < 192) nimS[t-128] = nim[i*64 + (t-128)];
  if (t < 128) {
    const int pp = t >> 1, hh2 = t & 1;
    const int jj = nbr[i*TOPK + part*64 + pp];
    const u32x4_t* src = (const u32x4_t*)(nodeb + jj*16 + hh2*8);
    u32x4_t a0 = src[0], a1 = src[1];
    unsigned* dst = &nd[pp][hh2*8];
    dst[0]=a0.x; dst[1]=a0.y; dst[2]=a0.z; dst[3]=a0.w;
    dst[4]=a1.x; dst[5]=a1.y; dst[6]=a1.z; dst[7]=a1.w;
    if (hh2 == 0) {
      const float cix = xyz[i*9+3], ciy = xyz[i*9+4], ciz = xyz[i*9+5];
      const float cjx = xyz[jj*9+3], cjy = xyz[jj*9+4], cjz = xyz[jj*9+5];
      relv[pp][0] = cjx - cix;
      relv[pp][1] = cjy - ciy;
      relv[pp][2] = cjz - ciz;
      const float dx = __fadd_rn(cix, -cjx), dy = __fadd_rn(ciy, -cjy),
                  dz = __fadd_rn(ciz, -cjz);
      Dvv[pp] = sqrtf(__fadd_rn(__fadd_rn(__fadd_rn(__fmul_rn(dx,dx),
                        __fmul_rn(dy,dy)), __fmul_rn(dz,dz)), 1e-8f));
      const float offv = (float)(idx[jj] - idx[i]);
      const float sg = (offv > 0.f) ? 1.f : ((offv < 0.f) ? -1.f : 0.f);
      xsepv[pp] = sg * logf(fabsf(offv) + 1.f);
    }
  }

  // pair stats + bf16 pack into LDS (consumes pv registers)
  unsigned (*pairB)[65] = (unsigned (*)[65])U;
  {
    float s = 0.f, ss = 0.f;
#pragma unroll
    for (int n = 0; n < 8; ++n) {
      const float4 v = pv[n];
      s  += (v.x + v.y) + (v.z + v.w);
      ss += v.x*v.x + v.y*v.y + v.z*v.z + v.w*v.w;
      pairB[rS][qS*16 + n*2]     = bfpack(v.x, v.y);
      pairB[rS][qS*16 + n*2 + 1] = bfpack(v.z, v.w);
    }
    s  += __shfl_xor(s, 1);  s  += __shfl_xor(s, 2);
    ss += __shfl_xor(ss, 1); ss += __shfl_xor(ss, 2);
    if (qS == 0) {
      const float pm = s * (1.f/128.f);
      const float pvv = ss * (1.f/128.f) - pm*pm;
      pmv[rS] = pm; prsv[rS] = 1.f / sqrtf(pvv + 1e-5f);
    }
  }
  __syncthreads();

  const f32x4_t fz = {0.f, 0.f, 0.f, 0.f};

  // ---- C1 MFMA: wave wv owns m-tile wv (16 edges), both col-tiles ----
  {
    const int col = lane & 15, rg = lane >> 4;
    const int eM = wv*16;
    f32x4_t accP[2] = {fz, fz}, accR[2] = {fz, fz};
#pragma unroll
    for (int ks = 0; ks < 4; ++ks) {   // pair part: K=128
      u32x4_t av;
      const unsigned* rp = &pairB[eM + col][ks*16 + rg*4];
      av.x = rp[0]; av.y = rp[1]; av.z = rp[2]; av.w = rp[3];
      const bf16x8_t af = __builtin_bit_cast(bf16x8_t, av);
#pragma unroll
      for (int ct = 0; ct < 2; ++ct) {
        const u32x4_t bv = ((const u32x4_t*)(pkws + (22 + ks*2 + ct)*256))[lane];
        accP[ct] = __builtin_amdgcn_mfma_f32_16x16x32_bf16(
            af, __builtin_bit_cast(bf16x8_t, bv), accP[ct], 0, 0, 0);
      }
    }
    const float Dv = Dvv[eM + col];
#pragma unroll
    for (int ks = 0; ks < 2; ++ks) {   // RBF part: K=64, A in-register
      u32x4_t av;
#pragma unroll
      for (int d = 0; d < 4; ++d) {
        const int k = ks*32 + rg*8 + 2*d;
        const float mu0 = 2.f + (float)k     * (20.f/63.f);
        const float mu1 = 2.f + (float)(k+1) * (20.f/63.f);
        const float u0 = (Dv - mu0) / 0.3125f;
        const float u1 = (Dv - mu1) / 0.3125f;
        ((unsigned*)&av)[d] = bfpack(expf(-(u0*u0)), expf(-(u1*u1)));
      }
      const bf16x8_t af = __builtin_bit_cast(bf16x8_t, av);
#pragma unroll
      for (int ct = 0; ct < 2; ++ct) {
        const u32x4_t bv = ((const u32x4_t*)(pkws + (30 + ks*2 + ct)*256))[lane];
        accR[ct] = __builtin_amdgcn_mfma_f32_16x16x32_bf16(
            af, __builtin_bit_cast(bf16x8_t, bv), accR[ct], 0, 0, 0);
      }
    }
#pragma unroll
    for (int ct = 0; ct < 2; ++ct) {
      const int ch = ct*16 + col;
      const float cs = colsum_ee[ch];
      const float w3 = W_ee[192*32 + ch];
      const float bb = b_ee[ch];
#pragma unroll
      for (int j = 0; j < 4; ++j) {
        const int e = eM + rg*4 + j;
        const float prs = prsv[e], pm = pmv[e];
        float v = fmaf(prs, accP[ct][j],
                   fmaf(-prs*pm, cs,
                     fmaf(xsepv[e], w3, bb + accR[ct][j])));
        const float p = __shfl_xor(v, 1);
        if (!(lane & 1)) Ab[e][ct*8 + (col >> 1)] = bfpack(v, p);
      }
    }
  }
  __syncthreads();

  // ---- MFMA MLP chain: wave wv owns edges [16wv, 16wv+16); NO barriers ----
  unsigned (*Bb)[33] = (unsigned (*)[33])U;
  {
    const int e0b = 16 * wv;
    const int row = lane & 15;    // A M-row / D N-col
    const int kg  = lane >> 4;    // k-group
    const int r0  = kg * 4;       // D M-row base

    // LN(Ab) per-wave: 4 lanes per edge (16 edges)
    {
      const int eL = e0b + row;
      float av[8];
#pragma unroll
      for (int kk = 0; kk < 4; ++kk) {
        const unsigned v = Ab[eL][kg*4 + kk];
        av[2*kk] = bflo(v); av[2*kk+1] = bfhi(v);
      }
      float s = 0.f;
#pragma unroll
      for (int c = 0; c < 8; ++c) s += av[c];
      s += __shfl_xor(s, 16); s += __shfl_xor(s, 32);
      const float mm = s * (1.f/32.f);
      float vv = 0.f;
#pragma unroll
      for (int c = 0; c < 8; ++c) { const float dd = av[c] - mm; vv += dd*dd; }
      vv += __shfl_xor(vv, 16); vv += __shfl_xor(vv, 32);
      vv *= (1.f/32.f);
      const float sg = sqrtf(vv + 1e-5f);
      const float rs = 1.f / sg;
#pragma unroll
      for (int kk = 0; kk < 4; ++kk)
        Ab[eL][kg*4 + kk] = bfpack((av[2*kk]-mm)*rs, (av[2*kk+1]-mm)*rs);
      if (kg == 0) { mA[eL] = mm; sgA[eL] = sg; }
    }

    // ---- h = relu(ed @ We1 + be1): MFMA, K=32, N=64 ----
    {
      u32x4_t av4;
      const unsigned* rp = &Ab[e0b + row][0];
      av4.x = rp[kg*4]; av4.y = rp[kg*4+1]; av4.z = rp[kg*4+2]; av4.w = rp[kg*4+3];
      const bf16x8_t af = __builtin_bit_cast(bf16x8_t, av4);
      f32x4_t acc[4];
#pragma unroll
      for (int ct = 0; ct < 4; ++ct) {
        const u32x4_t bv = ((const u32x4_t*)(pkws + (0 + ct)*256))[lane];
        acc[ct] = __builtin_amdgcn_mfma_f32_16x16x32_bf16(
            af, __builtin_bit_cast(bf16x8_t, bv), fz, 0, 0, 0);
      }
#pragma unroll
      for (int ct = 0; ct < 4; ++ct) {
        const int ch = ct*16 + row;
#pragma unroll
        for (int j = 0; j < 4; ++j) {
          float v = fmaxf(acc[ct][j] + be1[ch], 0.f);
          const float p = __shfl_xor(v, 1);
          if (!(lane & 1))
            Bb[e0b + r0 + j][ct*8 + (row >> 1)] = bfpack(v, p);
        }
      }
    }

    // ---- e2 = e0raw + h @ We2 + be2: MFMA, K=64, N=32 ----
    {
      f32x4_t acc[2] = {fz, fz};
#pragma unroll
      for (int ks = 0; ks < 2; ++ks) {
        u32x4_t av4;
        const unsigned* rp = &Bb[e0b + row][0];
        const int kd = ks*16 + kg*4;
        av4.x = rp[kd]; av4.y = rp[kd+1]; av4.z = rp[kd+2]; av4.w = rp[kd+3];
        const bf16x8_t af = __builtin_bit_cast(bf16x8_t, av4);
#pragma unroll
        for (int ct = 0; ct < 2; ++ct) {
          const u32x4_t bv = ((const u32x4_t*)(pkws + (4 + ks*2 + ct)*256))[lane];
          acc[ct] = __builtin_amdgcn_mfma_f32_16x16x32_bf16(
              af, __builtin_bit_cast(bf16x8_t, bv), acc[ct], 0, 0, 0);
        }
      }
#pragma unroll
      for (int ct = 0; ct < 2; ++ct) {
        const int ch = ct*16 + row;
        const int dw = ct*8 + (row >> 1);
#pragma unroll
        for (int j = 0; j < 4; ++j) {
          const int e = e0b + r0 + j;
          const unsigned old = Ab[e][dw];
          const float e0v = (lane & 1) ? bfhi(old) : bflo(old);
          float v = acc[ct][j] + fmaf(e0v, sgA[e], mA[e]) + be2[ch];
          const float p = __shfl_xor(v, 1);
          if (!(lane & 1)) Ab[e][dw] = bfpack(v, p);
        }
      }
    }

    // LN(e2) per-wave
    {
      const int eL = e0b + row;
      float av[8];
#pragma unroll
      for (int kk = 0; kk < 4; ++kk) {
        const unsigned v = Ab[eL][kg*4 + kk];
        av[2*kk] = bflo(v); av[2*kk+1] = bfhi(v);
      }
      float s = 0.f;
#pragma unroll
      for (int c = 0; c < 8; ++c) s += av[c];
      s += __shfl_xor(s, 16); s += __shfl_xor(s, 32);
      const float mm = s * (1.f/32.f);
      float vv = 0.f;
#pragma unroll
      for (int c = 0; c < 8; ++c) { const float dd = av[c] - mm; vv += dd*dd; }
      vv += __shfl_xor(vv, 16); vv += __shfl_xor(vv, 32);
      vv *= (1.f/32.f);
      const float rs = 1.f / sqrtf(vv + 1e-5f);
#pragma unroll
      for (int kk = 0; kk < 4; ++kk)
        Ab[eL][kg*4 + kk] = bfpack((av[2*kk]-mm)*rs, (av[2*kk+1]-mm)*rs);
    }

    // ---- m1 = relu(nim + nd@Wm1[32:64] + ed2@Wm1[64:96]) ----
    {
      u32x4_t aN, aE;
      const unsigned* rn = &nd[e0b + row][0];
      aN.x = rn[kg*4]; aN.y = rn[kg*4+1]; aN.z = rn[kg*4+2]; aN.w = rn[kg*4+3];
      const unsigned* ra = &Ab[e0b + row][0];
      aE.x = ra[kg*4]; aE.y = ra[kg*4+1]; aE.z = ra[kg*4+2]; aE.w = ra[kg*4+3];
      const bf16x8_t afN = __builtin_bit_cast(bf16x8_t, aN);
      const bf16x8_t afE = __builtin_bit_cast(bf16x8_t, aE);
      f32x4_t acc[4];
#pragma unroll
      for (int ct = 0; ct < 4; ++ct) {
        const u32x4_t bN = ((const u32x4_t*)(pkws + (8 + ct)*256))[lane];
        const u32x4_t bE = ((const u32x4_t*)(pkws + (12 + ct)*256))[lane];
        acc[ct] = __builtin_amdgcn_mfma_f32_16x16x32_bf16(
            afN, __builtin_bit_cast(bf16x8_t, bN), fz, 0, 0, 0);
        acc[ct] = __builtin_amdgcn_mfma_f32_16x16x32_bf16(
            afE, __builtin_bit_cast(bf16x8_t, bE), acc[ct], 0, 0, 0);
      }
#pragma unroll
      for (int ct = 0; ct < 4; ++ct) {
        const int ch = ct*16 + row;
        const float tb = nimS[ch];
#pragma unroll
        for (int j = 0; j < 4; ++j) {
          float v = fmaxf(acc[ct][j] + tb, 0.f);
          const float p = __shfl_xor(v, 1);
          if (!(lane & 1))
            Bb[e0b + r0 + j][ct*8 + (row >> 1)] = bfpack(v, p);
        }
      }
    }

    // ---- m2: MFMA K=64, N=48 (40 valid) + expand + wave reduce ----
    {
      f32x4_t acc[3] = {fz, fz, fz};
#pragma unroll
      for (int ks = 0; ks < 2; ++ks) {
        u32x4_t av4;
        const unsigned* rp = &Bb[e0b + row][0];
        const int kd = ks*16 + kg*4;
        av4.x = rp[kd]; av4.y = rp[kd+1]; av4.z = rp[kd+2]; av4.w = rp[kd+3];
        const bf16x8_t af = __builtin_bit_cast(bf16x8_t, av4);
#pragma unroll
        for (int ct = 0; ct < 3; ++ct) {
          const u32x4_t bv = ((const u32x4_t*)(pkws + (16 + ks*3 + ct)*256))[lane];
          acc[ct] = __builtin_amdgcn_mfma_f32_16x16x32_bf16(
              af, __builtin_bit_cast(bf16x8_t, bv), acc[ct], 0, 0, 0);
        }
      }
      float plain[3] = {0.f, 0.f, 0.f};
      float rel3[3]  = {0.f, 0.f, 0.f};
#pragma unroll
      for (int ct = 0; ct < 3; ++ct) {
        const int o = ct*16 + row;
        if (ct == 2 && row >= 8) continue;   // o >= 40
#pragma unroll
        for (int j = 0; j < 4; ++j) {
          const int e = e0b + r0 + j;
          const float v = acc[ct][j] + bm2[o];
          if (ct == 2 && row < 2) {
            rel3[0] = fmaf(v, relv[e][0], rel3[0]);
            rel3[1] = fmaf(v, relv[e][1], rel3[1]);
            rel3[2] = fmaf(v, relv[e][2], rel3[2]);
          } else {
            plain[ct] += v;
          }
        }
      }
#pragma unroll
      for (int d = 0; d < 3; ++d) {
        plain[d] += __shfl_xor(plain[d], 16); plain[d] += __shfl_xor(plain[d], 32);
        rel3[d]  += __shfl_xor(rel3[d], 16);  rel3[d]  += __shfl_xor(rel3[d], 32);
      }
      if (lane < 16) {
        P2[wv][lane]      = plain[0];
        P2[wv][16 + lane] = plain[1];
        if (lane < 2) {
#pragma unroll
          for (int d = 0; d < 3; ++d) P2[wv][32 + lane*3 + d] = rel3[d];
        } else if (lane < 8) {
          P2[wv][38 + lane - 2] = plain[2];
        }
      }
    }
  }
  __syncthreads();
  if (t < 44)
    fin2[(size_t)(i*2 + part)*44 + t] = P2[0][t] + P2[1][t] + P2[2][t] + P2[3][t];
}

// ---------------- Kernel D: epilogue (state_out/frame) + si MLP -> alpha ----
__global__ __launch_bounds__(512) void kernD(
    const float* __restrict__ seq_ln, const float* __restrict__ xyz,
    const unsigned char* __restrict__ rmask,
    const float* __restrict__ Wl0, const float* __restrict__ bl0,
    const float* __restrict__ node, const float* __restrict__ fin2,
    const float* __restrict__ Ws0, const float* __restrict__ bs0,
    const float* __restrict__ Wsi, const float* __restrict__ bsi,
    const float* __restrict__ Wp1, const float* __restrict__ bp1,
    const float* __restrict__ Wp2, const float* __restrict__ bp2,
    const float* __restrict__ Wp3, const float* __restrict__ bp3,
    const float* __restrict__ Wp4, const float* __restrict__ bp4,
    const float* __restrict__ Wout, const float* __restrict__ bout,
    float* __restrict__ out)
{
  const int i = blockIdx.x, t = threadIdx.x;
  const int c = t & 127, g = t >> 7;
  __shared__ float fin[44], niD[32], sout_s[16], stn[16];
  __shared__ float x0[256], act[128], resid[128], part[4][129];

  if (t < 44) fin[t] = fin2[(size_t)(i*2)*44 + t] + fin2[(size_t)(i*2+1)*44 + t];
  if (t >= 64 && t < 96) niD[t-64] = node[i*32 + (t-64)];
  if (t >= 256) x0[t-256] = seq_ln[i*256 + (t-256)];
  else if (t >= 128) x0[t] = seq_ln[i*256 + t];
  __syncthreads();

  if (t < 16) {  // state_out = [node_i, m_l0] @ Wl0 + bl0
    float a = bl0[t];
#pragma unroll
    for (int k = 0; k < 32; ++k) a = fmaf(niD[k], Wl0[k*16 + t], a);
#pragma unroll
    for (int k = 0; k < 32; ++k) a = fmaf(fin[k] * (1.f/128.f), Wl0[(32+k)*16 + t], a);
    sout_s[t] = a;
    out[LL*9 + i*16 + t] = a;
  }
  if (t == 32) {  // frame update
    float ve[6], wa[6];
#pragma unroll
    for (int qq = 0; qq < 6; ++qq) ve[qq] = fin[32 + qq] * (1.f/128.f);
#pragma unroll
    for (int qq = 0; qq < 6; ++qq) wa[qq] = fin[38 + qq] * (1.f/128.f);
    float l1[9];
#pragma unroll
    for (int a = 0; a < 3; ++a)
#pragma unroll
      for (int d = 0; d < 3; ++d) l1[a*3 + d] = xyz[i*9 + a*3 + d] - xyz[i*9 + 3 + d];
    float T[3], Rv[3];
#pragma unroll
    for (int d = 0; d < 3; ++d) {
      float va0 = wa[0]*l1[d] + wa[1]*l1[3 + d] + wa[2]*l1[6 + d];
      float va1 = wa[3]*l1[d] + wa[4]*l1[3 + d] + wa[5]*l1[6 + d];
      T[d]  = (ve[d] + va0) / 10.f;
      Rv[d] = (ve[3 + d] + va1) / 100.f;
    }
    float qn = sqrtf(1.f + Rv[0]*Rv[0] + Rv[1]*Rv[1] + Rv[2]*Rv[2]);
    float qA = 1.f/qn, qB = Rv[0]/qn, qC = Rv[1]/qn, qD = Rv[2]/qn;
    float Rm[9];
    Rm[0] = qA*qA + qB*qB - qC*qC - qD*qD;
    Rm[1] = 2.f*qB*qC - 2.f*qA*qD;
    Rm[2] = 2.f*qB*qD + 2.f*qA*qC;
    Rm[3] = 2.f*qB*qC + 2.f*qA*qD;
    Rm[4] = qA*qA - qB*qB + qC*qC - qD*qD;
    Rm[5] = 2.f*qC*qD - 2.f*qA*qB;
    Rm[6] = 2.f*qB*qD - 2.f*qA*qC;
    Rm[7] = 2.f*qC*qD + 2.f*qA*qB;
    Rm[8] = qA*qA - qB*qB - qC*qC + qD*qD;
    if (rmask[i]) {
      Rm[0] = 1.f; Rm[1] = 0.f; Rm[2] = 0.f;
      Rm[3] = 0.f; Rm[4] = 1.f; Rm[5] = 0.f;
      Rm[6] = 0.f; Rm[7] = 0.f; Rm[8] = 1.f;
    }
#pragma unroll
    for (int a = 0; a < 3; ++a)
#pragma unroll
      for (int di = 0; di < 3; ++di) {
        float xn = Rm[di*3+0]*l1[a*3+0] + Rm[di*3+1]*l1[a*3+1] + Rm[di*3+2]*l1[a*3+2]
                 + xyz[i*9 + 3 + di] + T[di];
        out[i*9 + a*3 + di] = xn;
      }
  }
  __syncthreads();

  if (t < 16) {
    float m = 0.f;
    for (int k = 0; k < 16; ++k) m += sout_s[k];
    m *= (1.f/16.f);
    float v = 0.f;
    for (int k = 0; k < 16; ++k) { float dd = sout_s[k] - m; v += dd*dd; }
    v *= (1.f/16.f);
    stn[t] = (sout_s[t] - m) / sqrtf(v + 1e-5f);
  }
  __syncthreads();

  // L0: si = x0 @ Ws0 + stn @ Wsi + bs0 + bsi
  {
    float p = 0.f;
    for (int k = g*64; k < g*64 + 64; ++k) p = fmaf(x0[k], Ws0[k*128 + c], p);
    if (g == 0)
      for (int k = 0; k < 16; ++k) p = fmaf(stn[k], Wsi[k*128 + c], p);
    part[g][c] = p;
  }
  __syncthreads();
  if (t < 128) {
    const float si = part[0][t] + part[1][t] + part[2][t] + part[3][t]
                   + bs0[t] + bsi[t];
    resid[t] = si;
    act[t] = fmaxf(si, 0.f);
  }
  __syncthreads();

  {
    float p = 0.f;
    for (int k = g*32; k < g*32 + 32; ++k) p = fmaf(act[k], Wp1[k*128 + c], p);
    part[g][c] = p;
  }
  __syncthreads();
  if (t < 128)
    act[t] = fmaxf(part[0][t] + part[1][t] + part[2][t] + part[3][t] + bp1[t], 0.f);
  __syncthreads();

  {
    float p = 0.f;
    for (int k = g*32; k < g*32 + 32; ++k) p = fmaf(act[k], Wp2[k*128 + c], p);
    part[g][c] = p;
  }
  __syncthreads();
  if (t < 128) {
    const float si = resid[t] + part[0][t] + part[1][t] + part[2][t] + part[3][t] + bp2[t];
    resid[t] = si;
    act[t] = fmaxf(si, 0.f);
  }
  __syncthreads();

  {
    float p = 0.f;
    for (int k = g*32; k < g*32 + 32; ++k) p = fmaf(act[k], Wp3[k*128 + c], p);
    part[g][c] = p;
  }
  __syncthreads();
  if (t < 128)
    act[t] = fmaxf(part[0][t] + part[1][t] + part[2][t] + part[3][t] + bp3[t], 0.f);
  __syncthreads();

  {
    float p = 0.f;
    for (int k = g*32; k < g*32 + 32; ++k) p = fmaf(act[k], Wp4[k*128 + c], p);
    part[g][c] = p;
  }
  __syncthreads();
  if (t < 128)
    act[t] = fmaxf(resid[t] + part[0][t] + part[1][t] + part[2][t] + part[3][t] + bp4[t], 0.f);
  __syncthreads();

  if (t < 20) {
    float a = bout[t];
    for (int k = 0; k < 128; ++k) a = fmaf(act[k], Wout[k*20 + t], a);
    out[19200 + i*20 + t] = a;
  }
}

extern "C" void kernel_launch(void* const* d_in, const int* in_sizes, int n_in,
                              void* d_out, int out_size, void* d_ws, size_t ws_size,
                              hipStream_t stream)
{
  (void)in_sizes; (void)n_in; (void)out_size; (void)ws_size;
  const float* msa   = (const float*)d_in[0];
  const float* pair  = (const float*)d_in[1];
  const float* xyz   = (const float*)d_in[2];
  const float* state = (const float*)d_in[3];
  const int*   idx   = (const int*)d_in[4];
  const unsigned char* rmask = (const unsigned char*)d_in[5];
  const float* W_en = (const float*)d_in[6];
  const float* b_en = (const float*)d_in[7];
  const float* Wn1  = (const float*)d_in[8];
  const float* bn1  = (const float*)d_in[9];
  const float* Wn2  = (const float*)d_in[10];
  const float* bn2  = (const float*)d_in[11];
  const float* W_ee = (const float*)d_in[12];
  const float* b_ee = (const float*)d_in[13];
  const float* We1  = (const float*)d_in[14];
  const float* be1  = (const float*)d_in[15];
  const float* We2  = (const float*)d_in[16];
  const float* be2  = (const float*)d_in[17];
  const float* Wm1  = (const float*)d_in[18];
  const float* bm1  = (const float*)d_in[19];
  const float* Wm2  = (const float*)d_in[20];
  const float* bm2  = (const float*)d_in[21];
  const float* Wl0  = (const float*)d_in[22];
  const float* bl0  = (const float*)d_in[23];
  const float* Ws0  = (const float*)d_in[24];
  const float* bs0  = (const float*)d_in[25];
  const float* Wsi  = (const float*)d_in[26];
  const float* bsi  = (const float*)d_in[27];
  const float* Wp1  = (const float*)d_in[28];
  const float* bp1  = (const float*)d_in[29];
  const float* Wp2  = (const float*)d_in[30];
  const float* bp2  = (const float*)d_in[31];
  const float* Wp3  = (const float*)d_in[32];
  const float* bp3  = (const float*)d_in[33];
  const float* Wp4  = (const float*)d_in[34];
  const float* bp4  = (const float*)d_in[35];
  const float* Wout = (const float*)d_in[36];
  const float* bout = (const float*)d_in[37];

  float* wsf    = (float*)d_ws;
  float* seq_ln = wsf + WS_SEQ;
  float* nodev  = wsf + WS_NODE;
  int*   nbr    = (int*)(wsf + WS_NBR);
  float* csee   = wsf + WS_CSEE;
  float* fin2   = wsf + WS_FIN;
  float* nim    = wsf + WS_NIM;
  unsigned* nodeb = (unsigned*)(wsf + WS_NODEB);
  unsigned* pkws  = (unsigned*)(wsf + WS_PK);
  float* out = (float*)d_out;

  kernABP<<<2*LL + 1, 256, 0, stream>>>(msa, state, W_en, b_en, Wn1, bn1, Wn2, bn2,
                                        xyz, W_ee, We1, We2, Wm1, bm1, Wm2,
                                        seq_ln, nodev, nbr, csee, nim, nodeb, pkws);
  kernC<<<2*LL, 256, 0, stream>>>(pair, xyz, idx, W_ee, b_ee, csee,
                                  be1, be2, nbr, nim, nodeb, bm2, pkws, fin2);
  kernD<<<LL, 512, 0, stream>>>(seq_ln, xyz, rmask, Wl0, bl0, nodev, fin2,
                                Ws0, bs0, Wsi, bsi, Wp1, bp1, Wp2, bp2,
                                Wp3, bp3, Wp4, bp4, Wout, bout, out);
}